// Round 20
// baseline (1319.571 us; speedup 1.0000x reference)
//
#include <hip/hip_runtime.h>
#include <hip/hip_bf16.h>
#include <math.h>

// Problem constants
#define B_  16
#define T_  1023
#define C_  384
#define H_  6
#define DH_ 64
#define L_  6
#define V_  256
#define FF_ 1536
#define M_  (B_*T_)      // 16368 rows
#define MP_ 16384        // padded rows (128-multiple)
#define EPS_ 1e-5f

typedef __attribute__((ext_vector_type(8))) short bf16x8;
typedef __attribute__((ext_vector_type(4))) short short4v;
typedef __attribute__((ext_vector_type(4))) float f32x4;

__device__ inline short f2bf(float x) {   // RNE float->bf16
    union { float f; unsigned u; } c; c.f = x;
    unsigned r = (c.u + 0x7fffu + ((c.u >> 16) & 1u)) >> 16;
    return (short)r;
}

#define GLDS16(g, l) __builtin_amdgcn_global_load_lds(                         \
    (const __attribute__((address_space(1))) void*)(g),                        \
    (__attribute__((address_space(3))) void*)(l), 16, 0, 0)

// hardware transpose read: 4 bf16 per lane (rule #18: waitcnt+sched_barrier after)
#define TRRD(dst, va, IMM) asm volatile("ds_read_b64_tr_b16 %0, %1 offset:" IMM \
    : "=v"(dst) : "v"(va))

// ---------------- embedding: h = tok_emb[x] + pos_emb (fp32) ----------------
__global__ void embed_kernel(const int* __restrict__ x, const float* __restrict__ tok,
                             const float* __restrict__ pos, float* __restrict__ h) {
    int i = blockIdx.x * 256 + threadIdx.x;
    if (i >= M_ * C_) return;
    int bt = i / C_;
    int c  = i - bt * C_;
    int t  = bt % T_;
    h[i] = tok[x[bt] * C_ + c] + pos[t * C_ + c];
}

// ---------------- weight transpose+convert: src fp32 [K][N] -> dst bf16 [N][K] ----
__global__ __launch_bounds__(256) void wconv_kernel(
    const float* __restrict__ Wq, const float* __restrict__ Wk,
    const float* __restrict__ Wv, const float* __restrict__ Wo,
    const float* __restrict__ W1, const float* __restrict__ W2,
    const float* __restrict__ Wf,
    short* __restrict__ qkvt, short* __restrict__ wot, short* __restrict__ w1t,
    short* __restrict__ w2t, short* __restrict__ wft) {
    __shared__ float tile[32][33];
    int t = blockIdx.x;
    const float* src; short* dst; int K, N, tl;
    if (t < 10368) {
        int l = t / 1728, r = t - l * 1728;
        if (r < 432) {                 // Wq/Wk/Wv -> fused qkv^T rows
            int which = r / 144; tl = r - which * 144;
            src = (which == 0 ? Wq : which == 1 ? Wk : Wv) + (size_t)l * 384 * 384;
            dst = qkvt + (size_t)l * 1152 * 384 + (size_t)which * 384 * 384;
            K = 384; N = 384;
        } else if (r < 576) {
            tl = r - 432;
            src = Wo + (size_t)l * 384 * 384; dst = wot + (size_t)l * 384 * 384;
            K = 384; N = 384;
        } else if (r < 1152) {
            tl = r - 576;
            src = W1 + (size_t)l * 384 * 1536; dst = w1t + (size_t)l * 1536 * 384;
            K = 384; N = 1536;
        } else {
            tl = r - 1152;
            src = W2 + (size_t)l * 1536 * 384; dst = w2t + (size_t)l * 384 * 1536;
            K = 1536; N = 384;
        }
    } else {
        tl = t - 10368; src = Wf; dst = wft; K = 384; N = 256;
    }
    int ntx = N >> 5;
    int k0 = (tl / ntx) << 5, n0 = (tl % ntx) << 5;
    int rr = threadIdx.x >> 5, cc = threadIdx.x & 31;
#pragma unroll
    for (int p = 0; p < 4; ++p)
        tile[rr + 8 * p][cc] = src[(size_t)(k0 + rr + 8 * p) * N + n0 + cc];
    __syncthreads();
#pragma unroll
    for (int p = 0; p < 4; ++p)
        dst[(size_t)(n0 + rr + 8 * p) * K + k0 + cc] = f2bf(tile[cc][rr + 8 * p]);
}

// ---------------- LayerNorm: fp32 in -> bf16 out, 4 rows per block ----------------
__global__ __launch_bounds__(256) void ln_kernel(const float* __restrict__ in,
                                                 const float* __restrict__ g,
                                                 const float* __restrict__ b,
                                                 short* __restrict__ out) {
    int wave = threadIdx.x >> 6, lane = threadIdx.x & 63;
    int row  = blockIdx.x * 4 + wave;       // M_ = 4092*4 exactly
    const float* rp = in + (size_t)row * C_;
    float v[6];
    float s = 0.f, s2 = 0.f;
#pragma unroll
    for (int i = 0; i < 6; ++i) {
        v[i] = rp[i * 64 + lane];
        s  += v[i];
        s2 += v[i] * v[i];
    }
#pragma unroll
    for (int o = 32; o > 0; o >>= 1) {
        s  += __shfl_xor(s,  o, 64);
        s2 += __shfl_xor(s2, o, 64);
    }
    float mu  = s * (1.0f / C_);
    float var = s2 * (1.0f / C_) - mu * mu;
    float rs  = rsqrtf(var + EPS_);
    short* op = out + (size_t)row * C_;
#pragma unroll
    for (int i = 0; i < 6; ++i) {
        int c = i * 64 + lane;
        op[c] = f2bf((v[i] - mu) * rs * g[c] + b[c]);
    }
}

// ---------------- bf16 MFMA GEMM (final projection only) ----------------
template<int MODE, bool RELU, bool HB>
__global__ __launch_bounds__(256) void mm_kernel(const short* __restrict__ A,
                                                 const short* __restrict__ Bt,
                                                 const float* __restrict__ bias,
                                                 short* __restrict__ outb,
                                                 float* __restrict__ outf,
                                                 int N, int K) {
    __shared__ short Al[2][8][128][8];   // [dbuf][k-octet][row][8] = 32 KB
    __shared__ short Bl[2][8][128][8];   // 32 KB
    int tid  = threadIdx.x;
    int wave = tid >> 6, lane = tid & 63;
    int kg4 = lane >> 4, r16 = lane & 15;
    int wr = (wave >> 1) * 64, wc = (wave & 1) * 64;
    int row0 = blockIdx.x * 128, col0 = blockIdx.y * 128;

    const short* ga = A  + (size_t)(row0 + (tid & 127)) * K + ((tid >> 7) << 5);
    const short* gb = Bt + (size_t)(col0 + (tid & 127)) * K + ((tid >> 7) << 5);
    short* alds = &Al[0][0][0][0];
    short* blds = &Bl[0][0][0][0];
    int ldst = ((tid >> 7) << 2) * 1024 + (tid & 127) * 8;   // shorts

    f32x4 acc[4][4];
#pragma unroll
    for (int i = 0; i < 4; ++i)
#pragma unroll
        for (int j = 0; j < 4; ++j) { acc[i][j][0]=0.f; acc[i][j][1]=0.f; acc[i][j][2]=0.f; acc[i][j][3]=0.f; }

#define MM_STAGE(BUF)                                                          \
    {                                                                          \
        short* la = alds + (BUF) * 8192 + ldst;                                \
        short* lb = blds + (BUF) * 8192 + ldst;                                \
        GLDS16(ga,      la);        GLDS16(ga + 8,  la + 1024);                \
        GLDS16(ga + 16, la + 2048); GLDS16(ga + 24, la + 3072);                \
        GLDS16(gb,      lb);        GLDS16(gb + 8,  lb + 1024);                \
        GLDS16(gb + 16, lb + 2048); GLDS16(gb + 24, lb + 3072);                \
        ga += 64; gb += 64;                                                    \
    }

#define MM_COMPUTE(BUF)                                                        \
    {                                                                          \
        _Pragma("unroll")                                                      \
        for (int p = 0; p < 2; ++p) {                                          \
            const short* ab = alds + (BUF) * 8192 + (4 * p + kg4) * 1024;      \
            const short* bb = blds + (BUF) * 8192 + (4 * p + kg4) * 1024;      \
            bf16x8 av[4], bv[4];                                               \
            _Pragma("unroll")                                                  \
            for (int i = 0; i < 4; ++i) av[i] = *(const bf16x8*)(ab + (wr + 16*i + r16) * 8); \
            _Pragma("unroll")                                                  \
            for (int j = 0; j < 4; ++j) bv[j] = *(const bf16x8*)(bb + (wc + 16*j + r16) * 8); \
            _Pragma("unroll")                                                  \
            for (int i = 0; i < 4; ++i)                                        \
                _Pragma("unroll")                                              \
                for (int j = 0; j < 4; ++j)                                    \
                    acc[i][j] = __builtin_amdgcn_mfma_f32_16x16x32_bf16(av[i], bv[j], acc[i][j], 0, 0, 0); \
        }                                                                      \
    }

    int NT = K >> 6;
    MM_STAGE(0);
    MM_STAGE(1);
    asm volatile("s_waitcnt vmcnt(8)" ::: "memory");
    __builtin_amdgcn_s_barrier();
    asm volatile("" ::: "memory");

    for (int t = 0; t < NT - 1; ++t) {
        MM_COMPUTE(t & 1);
        __builtin_amdgcn_s_barrier();
        asm volatile("" ::: "memory");
        if (t + 2 < NT) {
            MM_STAGE(t & 1);
            asm volatile("s_waitcnt vmcnt(8)" ::: "memory");
        } else {
            asm volatile("s_waitcnt vmcnt(0)" ::: "memory");
        }
        __builtin_amdgcn_s_barrier();
        asm volatile("" ::: "memory");
    }
    MM_COMPUTE((NT - 1) & 1);
#undef MM_STAGE
#undef MM_COMPUTE

#pragma unroll
    for (int j = 0; j < 4; ++j) {
        int col = col0 + wc + 16 * j + r16;
        float bj = HB ? bias[col] : 0.f;
#pragma unroll
        for (int i = 0; i < 4; ++i) {
#pragma unroll
            for (int rg = 0; rg < 4; ++rg) {
                int row = row0 + wr + 16 * i + 4 * kg4 + rg;
                float v = acc[i][j][rg] + bj;
                if (RELU) v = fmaxf(v, 0.f);
                if (MODE == 0) {
                    outb[(size_t)row * N + col] = f2bf(v);
                } else if (MODE == 1) {
                    outf[(size_t)row * N + col] += v;
                } else {
                    if (row < M_) outf[(size_t)row * N + col] = v;
                }
            }
        }
    }
}

// ---------------- QKV GEMM (ffn-FF1 style): big = z @ qkvt^T ----------------
__global__ __launch_bounds__(512) void qkv_kernel(const short* __restrict__ z,
                                                  const short* __restrict__ wt,
                                                  short* __restrict__ outb) {
    __shared__ short Zl[48 * 64 * 8];   // 48 KB
    int tid  = threadIdx.x;
    int wave = tid >> 6, lane = tid & 63;
    int g = lane >> 4, r16 = lane & 15;
    int r0 = blockIdx.x * 64;

    {
        const short* gz = z + (size_t)(r0 + lane) * C_ + wave * 8;
        short* lz = Zl + (wave * 64 + lane) * 8;
#pragma unroll
        for (int ro = 0; ro < 6; ++ro) { GLDS16(gz, lz); gz += 64; lz += 4096; }
    }

    const short* wbase = wt + (size_t)(16 * wave + r16) * C_ + 8 * g;
    bf16x8 wf[12];
#pragma unroll
    for (int ks = 0; ks < 12; ++ks) wf[ks] = *(const bf16x8*)(wbase + ks * 32);

    asm volatile("s_waitcnt vmcnt(0)" ::: "memory");
    __builtin_amdgcn_s_barrier();
    asm volatile("" ::: "memory");

    for (int c = 0; c < 9; ++c) {
        f32x4 acc[4];
#pragma unroll
        for (int mj = 0; mj < 4; ++mj) { acc[mj][0]=0.f; acc[mj][1]=0.f; acc[mj][2]=0.f; acc[mj][3]=0.f; }
#pragma unroll
        for (int ks = 0; ks < 12; ++ks) {
#pragma unroll
            for (int mj = 0; mj < 4; ++mj) {
                bf16x8 bz = *(const bf16x8*)(Zl + ((4 * ks + g) * 64 + 16 * mj + r16) * 8);
                acc[mj] = __builtin_amdgcn_mfma_f32_16x16x32_bf16(wf[ks], bz, acc[mj], 0, 0, 0);
            }
        }
        if (c + 1 < 9) {
#pragma unroll
            for (int ks = 0; ks < 12; ++ks)
                wf[ks] = *(const bf16x8*)(wbase + (size_t)(c + 1) * 128 * C_ + ks * 32);
        }
#pragma unroll
        for (int mj = 0; mj < 4; ++mj) {
            short4v ov;
#pragma unroll
            for (int rg = 0; rg < 4; ++rg) ov[rg] = f2bf(acc[mj][rg]);
            *(short4v*)(outb + (size_t)(r0 + 16 * mj + r16) * 1152
                        + 128 * c + 16 * wave + 4 * g) = ov;
        }
    }
}

// ---------------- Wo GEMM + residual + fused LN2 -> z (ffn-FF2 style) ---------
__global__ __launch_bounds__(512) void wo_kernel(const short* __restrict__ ob,
                                                 const short* __restrict__ wt,
                                                 const float* __restrict__ bo,
                                                 float* __restrict__ h,
                                                 const float* __restrict__ lng,
                                                 const float* __restrict__ lnb,
                                                 short* __restrict__ zout) {
    __shared__ short Ol[48 * 64 * 8];   // 48 KB (reused as LN scratch at end)
    int tid  = threadIdx.x;
    int wave = tid >> 6, lane = tid & 63;
    int g = lane >> 4, r16 = lane & 15;
    int r0 = blockIdx.x * 64;

    {
        const short* go = ob + (size_t)(r0 + lane) * C_ + wave * 8;
        short* lo = Ol + (wave * 64 + lane) * 8;
#pragma unroll
        for (int ro = 0; ro < 6; ++ro) { GLDS16(go, lo); go += 64; lo += 4096; }
    }

    const short* wbase = wt + (size_t)(48 * wave + r16) * C_ + 8 * g;
    bf16x8 wf[12];
#pragma unroll
    for (int ks2 = 0; ks2 < 4; ++ks2)
#pragma unroll
        for (int j = 0; j < 3; ++j)
            wf[ks2 * 3 + j] = *(const bf16x8*)(wbase + (size_t)(16 * j) * C_ + 32 * ks2);

    asm volatile("s_waitcnt vmcnt(0)" ::: "memory");
    __builtin_amdgcn_s_barrier();
    asm volatile("" ::: "memory");

    f32x4 acc[4][3];
#pragma unroll
    for (int mi = 0; mi < 4; ++mi)
#pragma unroll
        for (int j = 0; j < 3; ++j) { acc[mi][j][0]=0.f; acc[mi][j][1]=0.f; acc[mi][j][2]=0.f; acc[mi][j][3]=0.f; }

    for (int kc = 0; kc < 3; ++kc) {
#pragma unroll
        for (int ks2 = 0; ks2 < 4; ++ks2) {
            bf16x8 pa[4];
#pragma unroll
            for (int mi = 0; mi < 4; ++mi)
                pa[mi] = *(const bf16x8*)(Ol + ((16 * kc + 4 * ks2 + g) * 64 + 16 * mi + r16) * 8);
#pragma unroll
            for (int j = 0; j < 3; ++j)
#pragma unroll
                for (int mi = 0; mi < 4; ++mi)
                    acc[mi][j] = __builtin_amdgcn_mfma_f32_16x16x32_bf16(pa[mi], wf[ks2 * 3 + j], acc[mi][j], 0, 0, 0);
        }
        if (kc + 1 < 3) {
#pragma unroll
            for (int ks2 = 0; ks2 < 4; ++ks2)
#pragma unroll
                for (int j = 0; j < 3; ++j)
                    wf[ks2 * 3 + j] = *(const bf16x8*)(wbase + (size_t)(16 * j) * C_
                                                       + 128 * (kc + 1) + 32 * ks2);
        }
    }
    __syncthreads();               // Ol reads done; reuse as LN scratch

    // ---- epilogue: h_new = h_old + acc + bo (stored); fused LN -> zout ----
    float rsum[4][4], rsq[4][4];
#pragma unroll
    for (int mi = 0; mi < 4; ++mi)
#pragma unroll
        for (int rg = 0; rg < 4; ++rg) { rsum[mi][rg] = 0.f; rsq[mi][rg] = 0.f; }

#pragma unroll
    for (int j = 0; j < 3; ++j) {
        int col = 48 * wave + 16 * j + r16;
        float bj = bo[col];
#pragma unroll
        for (int mi = 0; mi < 4; ++mi) {
#pragma unroll
            for (int rg = 0; rg < 4; ++rg) {
                int row = r0 + 16 * mi + 4 * g + rg;
                float hv = h[(size_t)row * C_ + col] + acc[mi][j][rg] + bj;
                h[(size_t)row * C_ + col] = hv;
                acc[mi][j][rg] = hv;
                rsum[mi][rg] += hv;
                rsq[mi][rg]  += hv * hv;
            }
        }
    }
#pragma unroll
    for (int o = 1; o < 16; o <<= 1) {
#pragma unroll
        for (int mi = 0; mi < 4; ++mi)
#pragma unroll
            for (int rg = 0; rg < 4; ++rg) {
                rsum[mi][rg] += __shfl_xor(rsum[mi][rg], o, 64);
                rsq[mi][rg]  += __shfl_xor(rsq[mi][rg],  o, 64);
            }
    }
    float* St = (float*)Ol;             // [64 rows][16] floats = 4 KB
    if (r16 == 0) {
#pragma unroll
        for (int mi = 0; mi < 4; ++mi)
#pragma unroll
            for (int rg = 0; rg < 4; ++rg) {
                int rr = 16 * mi + 4 * g + rg;
                St[rr * 16 + 2 * wave]     = rsum[mi][rg];
                St[rr * 16 + 2 * wave + 1] = rsq[mi][rg];
            }
    }
    __syncthreads();
    if (tid < 64) {
        float s = 0.f, s2 = 0.f;
#pragma unroll
        for (int w = 0; w < 8; ++w) { s += St[tid * 16 + 2 * w]; s2 += St[tid * 16 + 2 * w + 1]; }
        float mu  = s * (1.0f / C_);
        float var = s2 * (1.0f / C_) - mu * mu;
        St[tid * 16]     = mu;
        St[tid * 16 + 1] = rsqrtf(var + EPS_);
    }
    __syncthreads();
#pragma unroll
    for (int j = 0; j < 3; ++j) {
        int col = 48 * wave + 16 * j + r16;
        float gam = lng[col], bet = lnb[col];
#pragma unroll
        for (int mi = 0; mi < 4; ++mi) {
#pragma unroll
            for (int rg = 0; rg < 4; ++rg) {
                int rr = 16 * mi + 4 * g + rg;
                float mu = St[rr * 16], rs = St[rr * 16 + 1];
                zout[(size_t)(r0 + rr) * C_ + col] = f2bf((acc[mi][j][rg] - mu) * rs * gam + bet);
            }
        }
    }
}

// ---------------- fused FFN v8: 256-wide chunks, 2 ff-col groups per wave ----
// Block = 64 rows, 512 threads, grid 256. Each bz LDS fragment reused for 2
// W1 fragments (jj=0,1): FF1 z-LDS-reads halve, barriers halve (6 chunks),
// 96 MFMA per barrier window. Pl doubled to 32 KB (32 ff-octets per chunk).
__global__ __launch_bounds__(512) void ffn_kernel(const short* __restrict__ z,
                                                  const short* __restrict__ w1t,
                                                  const short* __restrict__ w2t,
                                                  const float* __restrict__ b1,
                                                  const float* __restrict__ b2,
                                                  float* __restrict__ h) {
    __shared__ short Zl[48 * 64 * 8];   // 48 KB: [koct][row][8]
    __shared__ short Pl[32 * 64 * 8];   // 32 KB: [ffoct][row][8] (256-wide chunk)
    int tid  = threadIdx.x;
    int wave = tid >> 6, lane = tid & 63;
    int g = lane >> 4, r16 = lane & 15;
    int r0 = blockIdx.x * 64;

    {
        const short* gz = z + (size_t)(r0 + lane) * C_ + wave * 8;
        short* lz = Zl + (wave * 64 + lane) * 8;
#pragma unroll
        for (int ro = 0; ro < 6; ++ro) {
            GLDS16(gz, lz);
            gz += 64;
            lz += 8 * 64 * 8;
        }
    }

    // wave owns ff cols 256c + 32*wave + 16*jj + (4g+rg); rows 16mj+r16
    const short* w1base = w1t + (size_t)(32 * wave + r16) * C_ + 8 * g;
    const short* w2base = w2t + (size_t)(48 * wave + r16) * FF_ + 8 * g;

    asm volatile("s_waitcnt vmcnt(0)" ::: "memory");
    __builtin_amdgcn_s_barrier();
    asm volatile("" ::: "memory");

    f32x4 acc2[4][3];              // out rows 4x16, cols 48*wave..+47
#pragma unroll
    for (int mi = 0; mi < 4; ++mi)
#pragma unroll
        for (int j = 0; j < 3; ++j) { acc2[mi][j][0]=0.f; acc2[mi][j][1]=0.f; acc2[mi][j][2]=0.f; acc2[mi][j][3]=0.f; }

    for (int c = 0; c < 6; ++c) {
        // ---- W1 fragments for this chunk: 2 col-groups x 12 k-slices ----
        bf16x8 w1f[2][12];
#pragma unroll
        for (int jj = 0; jj < 2; ++jj)
#pragma unroll
            for (int ks = 0; ks < 12; ++ks)
                w1f[jj][ks] = *(const bf16x8*)(w1base + (size_t)(256 * c + 16 * jj) * C_ + 32 * ks);

        // ---- FF1: per ks load 4 bz, feed both jj groups (8 MFMA / 4 reads) ----
        f32x4 acc1[2][4];
#pragma unroll
        for (int jj = 0; jj < 2; ++jj)
#pragma unroll
            for (int mj = 0; mj < 4; ++mj) { acc1[jj][mj][0]=0.f; acc1[jj][mj][1]=0.f; acc1[jj][mj][2]=0.f; acc1[jj][mj][3]=0.f; }
#pragma unroll
        for (int ks = 0; ks < 12; ++ks) {
            bf16x8 bz[4];
#pragma unroll
            for (int mj = 0; mj < 4; ++mj)
                bz[mj] = *(const bf16x8*)(Zl + ((4 * ks + g) * 64 + 16 * mj + r16) * 8);
#pragma unroll
            for (int jj = 0; jj < 2; ++jj)
#pragma unroll
                for (int mj = 0; mj < 4; ++mj)
                    acc1[jj][mj] = __builtin_amdgcn_mfma_f32_16x16x32_bf16(w1f[jj][ks], bz[mj], acc1[jj][mj], 0, 0, 0);
        }
        // bias + relu + pack + store P (ffcol = 256c+32w+16jj+4g+rg, row = 16mj+r16)
#pragma unroll
        for (int jj = 0; jj < 2; ++jj) {
            f32x4 b1v = *(const f32x4*)(b1 + 256 * c + 32 * wave + 16 * jj + 4 * g);
            int oct = 4 * wave + 2 * jj + (g >> 1);
#pragma unroll
            for (int mj = 0; mj < 4; ++mj) {
                short4v pv;
#pragma unroll
                for (int rg = 0; rg < 4; ++rg)
                    pv[rg] = f2bf(fmaxf(acc1[jj][mj][rg] + b1v[rg], 0.f));
                *(short4v*)(Pl + (oct * 64 + 16 * mj + r16) * 8 + (g & 1) * 4) = pv;
            }
        }
        __syncthreads();

        // ---- FF2: acc2 += P @ W2chunk (256-wide: ks2 = 0..7) ----
#pragma unroll
        for (int ks2 = 0; ks2 < 8; ++ks2) {
            bf16x8 pa[4];
#pragma unroll
            for (int mi = 0; mi < 4; ++mi)
                pa[mi] = *(const bf16x8*)(Pl + ((4 * ks2 + g) * 64 + 16 * mi + r16) * 8);
#pragma unroll
            for (int j = 0; j < 3; ++j) {
                bf16x8 w2v = *(const bf16x8*)(w2base + (size_t)(16 * j) * FF_
                                              + 256 * c + 32 * ks2);
#pragma unroll
                for (int mi = 0; mi < 4; ++mi)
                    acc2[mi][j] = __builtin_amdgcn_mfma_f32_16x16x32_bf16(pa[mi], w2v, acc2[mi][j], 0, 0, 0);
            }
        }
        __syncthreads();
    }

    // ---- epilogue: h += acc2 + b2 ----
#pragma unroll
    for (int j = 0; j < 3; ++j) {
        int col = 48 * wave + 16 * j + r16;
        float bj = b2[col];
#pragma unroll
        for (int mi = 0; mi < 4; ++mi) {
#pragma unroll
            for (int rg = 0; rg < 4; ++rg) {
                int row = r0 + 16 * mi + 4 * g + rg;
                h[(size_t)row * C_ + col] += acc2[mi][j][rg] + bj;
            }
        }
    }
}

// ---------------- MFMA flash attention v3: paired q-tiles ----------------
__device__ __forceinline__ void attn_step(int kt, int qg, int g, int r16,
                                          const char* Kb, unsigned ka, unsigned va,
                                          short (*Pw)[40],
                                          bf16x8 qf0, bf16x8 qf1,
                                          f32x4* o_acc, float& m, float& l) {
    f32x4 s0, s1;
    s0[0]=0.f;s0[1]=0.f;s0[2]=0.f;s0[3]=0.f;
    s1[0]=0.f;s1[1]=0.f;s1[2]=0.f;s1[3]=0.f;
    bf16x8 a00 = *(const bf16x8*)(Kb + ka);
    bf16x8 a01 = *(const bf16x8*)(Kb + (ka ^ 64u));
    bf16x8 a10 = *(const bf16x8*)(Kb + ka + 2048u);
    bf16x8 a11 = *(const bf16x8*)(Kb + ((ka + 2048u) ^ 64u));
    s0 = __builtin_amdgcn_mfma_f32_16x16x32_bf16(a00, qf0, s0, 0, 0, 0);
    s0 = __builtin_amdgcn_mfma_f32_16x16x32_bf16(a01, qf1, s0, 0, 0, 0);
    s1 = __builtin_amdgcn_mfma_f32_16x16x32_bf16(a10, qf0, s1, 0, 0, 0);
    s1 = __builtin_amdgcn_mfma_f32_16x16x32_bf16(a11, qf1, s1, 0, 0, 0);

    int kb0 = kt * 32 + 4 * g;
    float sv[8];
#pragma unroll
    for (int r = 0; r < 4; ++r) {
        sv[r]     = (kb0 + r      <= qg) ? s0[r] * 0.125f : -3e38f;
        sv[4 + r] = (kb0 + 16 + r <= qg) ? s1[r] * 0.125f : -3e38f;
    }
    float pmax = sv[0];
#pragma unroll
    for (int i = 1; i < 8; ++i) pmax = fmaxf(pmax, sv[i]);
    pmax = fmaxf(pmax, __shfl_xor(pmax, 16, 64));
    pmax = fmaxf(pmax, __shfl_xor(pmax, 32, 64));
    float mn   = fmaxf(m, pmax);
    float corr = __expf(m - mn);
    float rs = 0.f;
    short pb[8];
#pragma unroll
    for (int i = 0; i < 8; ++i) {
        float p = __expf(sv[i] - mn);
        rs += p;
        pb[i] = f2bf(p);
    }
    rs += __shfl_xor(rs, 16, 64);
    rs += __shfl_xor(rs, 32, 64);
    l = l * corr + rs;
    m = mn;

    short4v t0w, t1w;
    t0w[0]=pb[0]; t0w[1]=pb[1]; t0w[2]=pb[2]; t0w[3]=pb[3];
    t1w[0]=pb[4]; t1w[1]=pb[5]; t1w[2]=pb[6]; t1w[3]=pb[7];
    *(short4v*)&Pw[r16][4 * g]      = t0w;
    *(short4v*)&Pw[r16][16 + 4 * g] = t1w;

    short4v v0, v1, v2, v3, v4, v5, v6, v7;
    TRRD(v0, va, "0");    TRRD(v1, va, "512");
    TRRD(v2, va, "128");  TRRD(v3, va, "640");
    TRRD(v4, va, "256");  TRRD(v5, va, "768");
    TRRD(v6, va, "384");  TRRD(v7, va, "896");

    bf16x8 pB = *(const bf16x8*)&Pw[r16][8 * g];
#pragma unroll
    for (int d = 0; d < 4; ++d) {
        o_acc[d][0] *= corr; o_acc[d][1] *= corr;
        o_acc[d][2] *= corr; o_acc[d][3] *= corr;
    }
    asm volatile("s_waitcnt lgkmcnt(0)" ::: "memory");
    __builtin_amdgcn_sched_barrier(0);

    bf16x8 av0, av1, av2, av3;
#pragma unroll
    for (int i = 0; i < 4; ++i) {
        av0[i] = v0[i]; av0[i + 4] = v1[i];
        av1[i] = v2[i]; av1[i + 4] = v3[i];
        av2[i] = v4[i]; av2[i + 4] = v5[i];
        av3[i] = v6[i]; av3[i + 4] = v7[i];
    }
    o_acc[0] = __builtin_amdgcn_mfma_f32_16x16x32_bf16(av0, pB, o_acc[0], 0, 0, 0);
    o_acc[1] = __builtin_amdgcn_mfma_f32_16x16x32_bf16(av1, pB, o_acc[1], 0, 0, 0);
    o_acc[2] = __builtin_amdgcn_mfma_f32_16x16x32_bf16(av2, pB, o_acc[2], 0, 0, 0);
    o_acc[3] = __builtin_amdgcn_mfma_f32_16x16x32_bf16(av3, pB, o_acc[3], 0, 0, 0);
}

__global__ __launch_bounds__(256) void attn_kernel(const short* __restrict__ qkv,
                                                   short* __restrict__ o) {
    __shared__ short Kl[32 * 64];
    __shared__ short Vl[32 * 64];
    __shared__ short P_lds[4][16][40];

    int tid  = threadIdx.x;
    int wave = tid >> 6;
    int lane = tid & 63;
    int g    = lane >> 4;
    int r16  = lane & 15;

    int qtA = blockIdx.x;
    int qtB = 15 - qtA;
    int bh = blockIdx.y;
    int b  = bh / H_, hh = bh - b * H_;
    size_t rbase = (size_t)b * T_;
    int qoff = hh * 64;

    int q0A = qtA * 64, q0B = qtB * 64;
    int qgA = q0A + wave * 16 + r16;
    int qgB = q0B + wave * 16 + r16;

    const short* qrA = qkv + (rbase + qgA) * 1152 + qoff;
    const short* qrB = qkv + (rbase + qgB) * 1152 + qoff;
    bf16x8 qfA0 = *(const bf16x8*)(qrA + 8 * g);
    bf16x8 qfA1 = *(const bf16x8*)(qrA + 32 + 8 * g);
    bf16x8 qfB0 = *(const bf16x8*)(qrB + 8 * g);
    bf16x8 qfB1 = *(const bf16x8*)(qrB + 32 + 8 * g);

    int kkey = tid >> 3;
    int koct = (tid & 7) ^ (kkey & 7);
    const short* gk = qkv + (rbase + kkey) * 1152 + qoff + 384 + koct * 8;
    int vkey = 4 * (tid >> 5) + ((tid >> 1) & 3);
    int voct = 2 * ((tid >> 3) & 3) + (tid & 1);
    const short* gv = qkv + (rbase + vkey) * 1152 + qoff + 768 + voct * 8;
    short* lk = Kl + tid * 8;
    short* lv = Vl + tid * 8;

    f32x4 oA[4], oB[4];
#pragma unroll
    for (int d = 0; d < 4; ++d) {
        oA[d][0]=0.f; oA[d][1]=0.f; oA[d][2]=0.f; oA[d][3]=0.f;
        oB[d][0]=0.f; oB[d][1]=0.f; oB[d][2]=0.f; oB[d][3]=0.f;
    }
    float mA = -3e38f, lA = 0.f, mB = -3e38f, lB = 0.f;

    const char* Kb = (const char*)Kl;
    unsigned ka = (unsigned)(r16 * 128 + ((g ^ (r16 & 7)) << 4));
    unsigned va = (unsigned)(size_t)(__attribute__((address_space(3))) short*)Vl
                + 1024u * (unsigned)g + 8u * (unsigned)r16;

    int ktA_hi = (q0A + wave * 16 + 15) >> 5;
    int ktB_hi = (q0B + wave * 16 + 15) >> 5;
    int nkt = 2 * (qtB + 1);

    for (int kt = 0; kt < nkt; ++kt) {
        __syncthreads();
        GLDS16(gk, lk);
        GLDS16(gv, lv);
        gk += 32 * 1152; gv += 32 * 1152;
        __syncthreads();

        if (kt <= ktB_hi)
            attn_step(kt, qgB, g, r16, Kb, ka, va, P_lds[wave], qfB0, qfB1, oB, mB, lB);
        if (kt <= ktA_hi)
            attn_step(kt, qgA, g, r16, Kb, ka, va, P_lds[wave], qfA0, qfA1, oA, mA, lA);
    }

    {
        float inv = (lA > 0.f) ? 1.f / lA : 0.f;
        short* orow = o + (rbase + qgA) * C_ + qoff;
#pragma unroll
        for (int d = 0; d < 4; ++d) {
            short4v ov;
#pragma unroll
            for (int r = 0; r < 4; ++r) ov[r] = f2bf(oA[d][r] * inv);
            *(short4v*)(orow + 16 * d + 4 * g) = ov;
        }
    }
    if (qgB < T_) {
        float inv = (lB > 0.f) ? 1.f / lB : 0.f;
        short* orow = o + (rbase + qgB) * C_ + qoff;
#pragma unroll
        for (int d = 0; d < 4; ++d) {
            short4v ov;
#pragma unroll
            for (int r = 0; r < 4; ++r) ov[r] = f2bf(oB[d][r] * inv);
            *(short4v*)(orow + 16 * d + 4 * g) = ov;
        }
    }
}

// ---------------- per-row NLL: 4 rows per 256-thread block ----------------
__global__ __launch_bounds__(256) void nll_kernel(const float* __restrict__ logits,
                                                  const int* __restrict__ tgt,
                                                  float* __restrict__ nll) {
    int wave = threadIdx.x >> 6, lane = threadIdx.x & 63;
    int row  = blockIdx.x * 4 + wave;       // M_ = 4092*4 exactly
    const float* rp = logits + (size_t)row * V_;
    float v[4];
    float mx = -INFINITY;
#pragma unroll
    for (int i = 0; i < 4; ++i) {
        v[i] = rp[i * 64 + lane];
        mx = fmaxf(mx, v[i]);
    }
#pragma unroll
    for (int o = 32; o > 0; o >>= 1) mx = fmaxf(mx, __shfl_xor(mx, o, 64));
    float s = 0.f;
#pragma unroll
    for (int i = 0; i < 4; ++i) s += expf(v[i] - mx);
#pragma unroll
    for (int o = 32; o > 0; o >>= 1) s += __shfl_xor(s, o, 64);
    if (lane == 0) {
        float lse = mx + logf(s);
        nll[row] = lse - rp[tgt[row]];
    }
}

// ---------------- final deterministic mean reduce ----------------
__global__ __launch_bounds__(256) void loss_kernel(const float* __restrict__ nll,
                                                   float* __restrict__ loss) {
    __shared__ float sm[256];
    float s = 0.f;
    for (int i = threadIdx.x; i < M_; i += 256) s += nll[i];
    sm[threadIdx.x] = s;
    __syncthreads();
    for (int o = 128; o > 0; o >>= 1) {
        if (threadIdx.x < o) sm[threadIdx.x] += sm[threadIdx.x + o];
        __syncthreads();
    }
    if (threadIdx.x == 0) *loss = sm[0] * (1.0f / M_);
}

// ---------------- host launcher ----------------
extern "C" void kernel_launch(void* const* d_in, const int* in_sizes, int n_in,
                              void* d_out, int out_size, void* d_ws, size_t ws_size,
                              hipStream_t stream) {
    const int*   x       = (const int*)d_in[0];
    const int*   targets = (const int*)d_in[1];
    const float* tok_emb = (const float*)d_in[2];
    const float* pos_emb = (const float*)d_in[3];
    const float* Wq      = (const float*)d_in[4];
    const float* Wk      = (const float*)d_in[5];
    const float* Wv      = (const float*)d_in[6];
    const float* Wo      = (const float*)d_in[7];
    const float* bo      = (const float*)d_in[8];
    const float* ln1_g   = (const float*)d_in[9];
    const float* ln1_b   = (const float*)d_in[10];
    const float* ln2_g   = (const float*)d_in[11];
    const float* ln2_b   = (const float*)d_in[12];
    const float* W1      = (const float*)d_in[13];
    const float* b1      = (const float*)d_in[14];
    const float* W2      = (const float*)d_in[15];
    const float* b2      = (const float*)d_in[16];
    const float* lnf_g   = (const float*)d_in[17];
    const float* lnf_b   = (const float*)d_in[18];
    const float* Wf      = (const float*)d_in[19];
    const float* bf      = (const float*)d_in[20];

    float* logits = (float*)d_out;
    float* loss   = logits + (size_t)M_ * V_;

    float* h    = (float*)d_ws;                          // [MP_][C_] fp32
    short* z    = (short*)(h + (size_t)MP_ * C_);        // [MP_][C_] bf16
    short* big  = z + (size_t)MP_ * C_;                  // [MP_][FF_] bf16 (qkv)
    short* ob   = big + (size_t)MP_ * FF_;               // [MP_][C_] bf16
    short* qkvt = ob + (size_t)MP_ * C_;                 // [L][1152][384]
    short* wot  = qkvt + (size_t)L_ * 1152 * 384;        // [L][384][384]
    short* w1t  = wot + (size_t)L_ * 384 * 384;          // [L][1536][384]
    short* w2t  = w1t + (size_t)L_ * 1536 * 384;         // [L][384][1536]
    short* wft  = w2t + (size_t)L_ * 1536 * 384;         // [256][384]
    float* nll  = (float*)(wft + (size_t)256 * 384);     // [M_]

    wconv_kernel<<<10464, 256, 0, stream>>>(Wq, Wk, Wv, Wo, W1, W2, Wf,
                                            qkvt, wot, w1t, w2t, wft);
    embed_kernel<<<(M_ * C_ + 255) / 256, 256, 0, stream>>>(x, tok_emb, pos_emb, h);

    for (int l = 0; l < L_; ++l) {
        ln_kernel<<<M_ / 4, 256, 0, stream>>>(h, ln1_g + l * C_, ln1_b + l * C_, z);
        qkv_kernel<<<MP_ / 64, 512, 0, stream>>>(z, qkvt + (size_t)l * 1152 * 384, big);
        attn_kernel<<<dim3(8, B_ * H_), 256, 0, stream>>>(big, ob);
        wo_kernel<<<MP_ / 64, 512, 0, stream>>>(
            ob, wot + (size_t)l * 384 * 384, bo + l * C_, h,
            ln2_g + l * C_, ln2_b + l * C_, z);
        ffn_kernel<<<MP_ / 64, 512, 0, stream>>>(
            z, w1t + (size_t)l * 1536 * 384, w2t + (size_t)l * 384 * 1536,
            b1 + l * FF_, b2 + l * C_, h);
    }

    ln_kernel<<<M_ / 4, 256, 0, stream>>>(h, lnf_g, lnf_b, z);
    mm_kernel<2, false, true><<<dim3(128, 2), 256, 0, stream>>>(
        z, wft, bf, nullptr, logits, 256, 384);

    nll_kernel<<<M_ / 4, 256, 0, stream>>>(logits, targets, nll);
    loss_kernel<<<1, 256, 0, stream>>>(nll, loss);
}

// Round 21
// 1275.314 us; speedup vs baseline: 1.0347x; 1.0347x over previous
//
#include <hip/hip_runtime.h>
#include <hip/hip_bf16.h>
#include <math.h>

// Problem constants
#define B_  16
#define T_  1023
#define C_  384
#define H_  6
#define DH_ 64
#define L_  6
#define V_  256
#define FF_ 1536
#define M_  (B_*T_)      // 16368 rows
#define MP_ 16384        // padded rows (128-multiple)
#define EPS_ 1e-5f

typedef __attribute__((ext_vector_type(8))) short bf16x8;
typedef __attribute__((ext_vector_type(4))) short short4v;
typedef __attribute__((ext_vector_type(4))) float f32x4;

__device__ inline short f2bf(float x) {   // RNE float->bf16
    union { float f; unsigned u; } c; c.f = x;
    unsigned r = (c.u + 0x7fffu + ((c.u >> 16) & 1u)) >> 16;
    return (short)r;
}

#define GLDS16(g, l) __builtin_amdgcn_global_load_lds(                         \
    (const __attribute__((address_space(1))) void*)(g),                        \
    (__attribute__((address_space(3))) void*)(l), 16, 0, 0)

// hardware transpose read: 4 bf16 per lane (rule #18: waitcnt+sched_barrier after)
#define TRRD(dst, va, IMM) asm volatile("ds_read_b64_tr_b16 %0, %1 offset:" IMM \
    : "=v"(dst) : "v"(va))

// ---------------- embedding: h = tok_emb[x] + pos_emb (fp32) ----------------
__global__ void embed_kernel(const int* __restrict__ x, const float* __restrict__ tok,
                             const float* __restrict__ pos, float* __restrict__ h) {
    int i = blockIdx.x * 256 + threadIdx.x;
    if (i >= M_ * C_) return;
    int bt = i / C_;
    int c  = i - bt * C_;
    int t  = bt % T_;
    h[i] = tok[x[bt] * C_ + c] + pos[t * C_ + c];
}

// ---------------- weight transpose+convert: src fp32 [K][N] -> dst bf16 [N][K] ----
__global__ __launch_bounds__(256) void wconv_kernel(
    const float* __restrict__ Wq, const float* __restrict__ Wk,
    const float* __restrict__ Wv, const float* __restrict__ Wo,
    const float* __restrict__ W1, const float* __restrict__ W2,
    const float* __restrict__ Wf,
    short* __restrict__ qkvt, short* __restrict__ wot, short* __restrict__ w1t,
    short* __restrict__ w2t, short* __restrict__ wft) {
    __shared__ float tile[32][33];
    int t = blockIdx.x;
    const float* src; short* dst; int K, N, tl;
    if (t < 10368) {
        int l = t / 1728, r = t - l * 1728;
        if (r < 432) {                 // Wq/Wk/Wv -> fused qkv^T rows
            int which = r / 144; tl = r - which * 144;
            src = (which == 0 ? Wq : which == 1 ? Wk : Wv) + (size_t)l * 384 * 384;
            dst = qkvt + (size_t)l * 1152 * 384 + (size_t)which * 384 * 384;
            K = 384; N = 384;
        } else if (r < 576) {
            tl = r - 432;
            src = Wo + (size_t)l * 384 * 384; dst = wot + (size_t)l * 384 * 384;
            K = 384; N = 384;
        } else if (r < 1152) {
            tl = r - 576;
            src = W1 + (size_t)l * 384 * 1536; dst = w1t + (size_t)l * 1536 * 384;
            K = 384; N = 1536;
        } else {
            tl = r - 1152;
            src = W2 + (size_t)l * 1536 * 384; dst = w2t + (size_t)l * 384 * 1536;
            K = 1536; N = 384;
        }
    } else {
        tl = t - 10368; src = Wf; dst = wft; K = 384; N = 256;
    }
    int ntx = N >> 5;
    int k0 = (tl / ntx) << 5, n0 = (tl % ntx) << 5;
    int rr = threadIdx.x >> 5, cc = threadIdx.x & 31;
#pragma unroll
    for (int p = 0; p < 4; ++p)
        tile[rr + 8 * p][cc] = src[(size_t)(k0 + rr + 8 * p) * N + n0 + cc];
    __syncthreads();
#pragma unroll
    for (int p = 0; p < 4; ++p)
        dst[(size_t)(n0 + rr + 8 * p) * K + k0 + cc] = f2bf(tile[cc][rr + 8 * p]);
}

// ---------------- LayerNorm: fp32 in -> bf16 out, 4 rows per block ----------------
__global__ __launch_bounds__(256) void ln_kernel(const float* __restrict__ in,
                                                 const float* __restrict__ g,
                                                 const float* __restrict__ b,
                                                 short* __restrict__ out) {
    int wave = threadIdx.x >> 6, lane = threadIdx.x & 63;
    int row  = blockIdx.x * 4 + wave;       // M_ = 4092*4 exactly
    const float* rp = in + (size_t)row * C_;
    float v[6];
    float s = 0.f, s2 = 0.f;
#pragma unroll
    for (int i = 0; i < 6; ++i) {
        v[i] = rp[i * 64 + lane];
        s  += v[i];
        s2 += v[i] * v[i];
    }
#pragma unroll
    for (int o = 32; o > 0; o >>= 1) {
        s  += __shfl_xor(s,  o, 64);
        s2 += __shfl_xor(s2, o, 64);
    }
    float mu  = s * (1.0f / C_);
    float var = s2 * (1.0f / C_) - mu * mu;
    float rs  = rsqrtf(var + EPS_);
    short* op = out + (size_t)row * C_;
#pragma unroll
    for (int i = 0; i < 6; ++i) {
        int c = i * 64 + lane;
        op[c] = f2bf((v[i] - mu) * rs * g[c] + b[c]);
    }
}

// ---------------- bf16 MFMA GEMM (final projection only) ----------------
template<int MODE, bool RELU, bool HB>
__global__ __launch_bounds__(256) void mm_kernel(const short* __restrict__ A,
                                                 const short* __restrict__ Bt,
                                                 const float* __restrict__ bias,
                                                 short* __restrict__ outb,
                                                 float* __restrict__ outf,
                                                 int N, int K) {
    __shared__ short Al[2][8][128][8];   // [dbuf][k-octet][row][8] = 32 KB
    __shared__ short Bl[2][8][128][8];   // 32 KB
    int tid  = threadIdx.x;
    int wave = tid >> 6, lane = tid & 63;
    int kg4 = lane >> 4, r16 = lane & 15;
    int wr = (wave >> 1) * 64, wc = (wave & 1) * 64;
    int row0 = blockIdx.x * 128, col0 = blockIdx.y * 128;

    const short* ga = A  + (size_t)(row0 + (tid & 127)) * K + ((tid >> 7) << 5);
    const short* gb = Bt + (size_t)(col0 + (tid & 127)) * K + ((tid >> 7) << 5);
    short* alds = &Al[0][0][0][0];
    short* blds = &Bl[0][0][0][0];
    int ldst = ((tid >> 7) << 2) * 1024 + (tid & 127) * 8;   // shorts

    f32x4 acc[4][4];
#pragma unroll
    for (int i = 0; i < 4; ++i)
#pragma unroll
        for (int j = 0; j < 4; ++j) { acc[i][j][0]=0.f; acc[i][j][1]=0.f; acc[i][j][2]=0.f; acc[i][j][3]=0.f; }

#define MM_STAGE(BUF)                                                          \
    {                                                                          \
        short* la = alds + (BUF) * 8192 + ldst;                                \
        short* lb = blds + (BUF) * 8192 + ldst;                                \
        GLDS16(ga,      la);        GLDS16(ga + 8,  la + 1024);                \
        GLDS16(ga + 16, la + 2048); GLDS16(ga + 24, la + 3072);                \
        GLDS16(gb,      lb);        GLDS16(gb + 8,  lb + 1024);                \
        GLDS16(gb + 16, lb + 2048); GLDS16(gb + 24, lb + 3072);                \
        ga += 64; gb += 64;                                                    \
    }

#define MM_COMPUTE(BUF)                                                        \
    {                                                                          \
        _Pragma("unroll")                                                      \
        for (int p = 0; p < 2; ++p) {                                          \
            const short* ab = alds + (BUF) * 8192 + (4 * p + kg4) * 1024;      \
            const short* bb = blds + (BUF) * 8192 + (4 * p + kg4) * 1024;      \
            bf16x8 av[4], bv[4];                                               \
            _Pragma("unroll")                                                  \
            for (int i = 0; i < 4; ++i) av[i] = *(const bf16x8*)(ab + (wr + 16*i + r16) * 8); \
            _Pragma("unroll")                                                  \
            for (int j = 0; j < 4; ++j) bv[j] = *(const bf16x8*)(bb + (wc + 16*j + r16) * 8); \
            _Pragma("unroll")                                                  \
            for (int i = 0; i < 4; ++i)                                        \
                _Pragma("unroll")                                              \
                for (int j = 0; j < 4; ++j)                                    \
                    acc[i][j] = __builtin_amdgcn_mfma_f32_16x16x32_bf16(av[i], bv[j], acc[i][j], 0, 0, 0); \
        }                                                                      \
    }

    int NT = K >> 6;
    MM_STAGE(0);
    MM_STAGE(1);
    asm volatile("s_waitcnt vmcnt(8)" ::: "memory");
    __builtin_amdgcn_s_barrier();
    asm volatile("" ::: "memory");

    for (int t = 0; t < NT - 1; ++t) {
        MM_COMPUTE(t & 1);
        __builtin_amdgcn_s_barrier();
        asm volatile("" ::: "memory");
        if (t + 2 < NT) {
            MM_STAGE(t & 1);
            asm volatile("s_waitcnt vmcnt(8)" ::: "memory");
        } else {
            asm volatile("s_waitcnt vmcnt(0)" ::: "memory");
        }
        __builtin_amdgcn_s_barrier();
        asm volatile("" ::: "memory");
    }
    MM_COMPUTE((NT - 1) & 1);
#undef MM_STAGE
#undef MM_COMPUTE

#pragma unroll
    for (int j = 0; j < 4; ++j) {
        int col = col0 + wc + 16 * j + r16;
        float bj = HB ? bias[col] : 0.f;
#pragma unroll
        for (int i = 0; i < 4; ++i) {
#pragma unroll
            for (int rg = 0; rg < 4; ++rg) {
                int row = row0 + wr + 16 * i + 4 * kg4 + rg;
                float v = acc[i][j][rg] + bj;
                if (RELU) v = fmaxf(v, 0.f);
                if (MODE == 0) {
                    outb[(size_t)row * N + col] = f2bf(v);
                } else if (MODE == 1) {
                    outf[(size_t)row * N + col] += v;
                } else {
                    if (row < M_) outf[(size_t)row * N + col] = v;
                }
            }
        }
    }
}

// ---------------- QKV GEMM (ffn-FF1 style): big = z @ qkvt^T ----------------
__global__ __launch_bounds__(512) void qkv_kernel(const short* __restrict__ z,
                                                  const short* __restrict__ wt,
                                                  short* __restrict__ outb) {
    __shared__ short Zl[48 * 64 * 8];   // 48 KB
    int tid  = threadIdx.x;
    int wave = tid >> 6, lane = tid & 63;
    int g = lane >> 4, r16 = lane & 15;
    int r0 = blockIdx.x * 64;

    {
        const short* gz = z + (size_t)(r0 + lane) * C_ + wave * 8;
        short* lz = Zl + (wave * 64 + lane) * 8;
#pragma unroll
        for (int ro = 0; ro < 6; ++ro) { GLDS16(gz, lz); gz += 64; lz += 4096; }
    }

    const short* wbase = wt + (size_t)(16 * wave + r16) * C_ + 8 * g;
    bf16x8 wf[12];
#pragma unroll
    for (int ks = 0; ks < 12; ++ks) wf[ks] = *(const bf16x8*)(wbase + ks * 32);

    asm volatile("s_waitcnt vmcnt(0)" ::: "memory");
    __builtin_amdgcn_s_barrier();
    asm volatile("" ::: "memory");

    for (int c = 0; c < 9; ++c) {
        f32x4 acc[4];
#pragma unroll
        for (int mj = 0; mj < 4; ++mj) { acc[mj][0]=0.f; acc[mj][1]=0.f; acc[mj][2]=0.f; acc[mj][3]=0.f; }
#pragma unroll
        for (int ks = 0; ks < 12; ++ks) {
#pragma unroll
            for (int mj = 0; mj < 4; ++mj) {
                bf16x8 bz = *(const bf16x8*)(Zl + ((4 * ks + g) * 64 + 16 * mj + r16) * 8);
                acc[mj] = __builtin_amdgcn_mfma_f32_16x16x32_bf16(wf[ks], bz, acc[mj], 0, 0, 0);
            }
        }
        if (c + 1 < 9) {
#pragma unroll
            for (int ks = 0; ks < 12; ++ks)
                wf[ks] = *(const bf16x8*)(wbase + (size_t)(c + 1) * 128 * C_ + ks * 32);
        }
#pragma unroll
        for (int mj = 0; mj < 4; ++mj) {
            short4v ov;
#pragma unroll
            for (int rg = 0; rg < 4; ++rg) ov[rg] = f2bf(acc[mj][rg]);
            *(short4v*)(outb + (size_t)(r0 + 16 * mj + r16) * 1152
                        + 128 * c + 16 * wave + 4 * g) = ov;
        }
    }
}

// ---------------- Wo GEMM + residual + fused LN2 -> z (ffn-FF2 style) ---------
__global__ __launch_bounds__(512) void wo_kernel(const short* __restrict__ ob,
                                                 const short* __restrict__ wt,
                                                 const float* __restrict__ bo,
                                                 float* __restrict__ h,
                                                 const float* __restrict__ lng,
                                                 const float* __restrict__ lnb,
                                                 short* __restrict__ zout) {
    __shared__ short Ol[48 * 64 * 8];   // 48 KB (reused as LN scratch at end)
    int tid  = threadIdx.x;
    int wave = tid >> 6, lane = tid & 63;
    int g = lane >> 4, r16 = lane & 15;
    int r0 = blockIdx.x * 64;

    {
        const short* go = ob + (size_t)(r0 + lane) * C_ + wave * 8;
        short* lo = Ol + (wave * 64 + lane) * 8;
#pragma unroll
        for (int ro = 0; ro < 6; ++ro) { GLDS16(go, lo); go += 64; lo += 4096; }
    }

    const short* wbase = wt + (size_t)(48 * wave + r16) * C_ + 8 * g;
    bf16x8 wf[12];
#pragma unroll
    for (int ks2 = 0; ks2 < 4; ++ks2)
#pragma unroll
        for (int j = 0; j < 3; ++j)
            wf[ks2 * 3 + j] = *(const bf16x8*)(wbase + (size_t)(16 * j) * C_ + 32 * ks2);

    asm volatile("s_waitcnt vmcnt(0)" ::: "memory");
    __builtin_amdgcn_s_barrier();
    asm volatile("" ::: "memory");

    f32x4 acc[4][3];
#pragma unroll
    for (int mi = 0; mi < 4; ++mi)
#pragma unroll
        for (int j = 0; j < 3; ++j) { acc[mi][j][0]=0.f; acc[mi][j][1]=0.f; acc[mi][j][2]=0.f; acc[mi][j][3]=0.f; }

    for (int kc = 0; kc < 3; ++kc) {
#pragma unroll
        for (int ks2 = 0; ks2 < 4; ++ks2) {
            bf16x8 pa[4];
#pragma unroll
            for (int mi = 0; mi < 4; ++mi)
                pa[mi] = *(const bf16x8*)(Ol + ((16 * kc + 4 * ks2 + g) * 64 + 16 * mi + r16) * 8);
#pragma unroll
            for (int j = 0; j < 3; ++j)
#pragma unroll
                for (int mi = 0; mi < 4; ++mi)
                    acc[mi][j] = __builtin_amdgcn_mfma_f32_16x16x32_bf16(pa[mi], wf[ks2 * 3 + j], acc[mi][j], 0, 0, 0);
        }
        if (kc + 1 < 3) {
#pragma unroll
            for (int ks2 = 0; ks2 < 4; ++ks2)
#pragma unroll
                for (int j = 0; j < 3; ++j)
                    wf[ks2 * 3 + j] = *(const bf16x8*)(wbase + (size_t)(16 * j) * C_
                                                       + 128 * (kc + 1) + 32 * ks2);
        }
    }
    __syncthreads();               // Ol reads done; reuse as LN scratch

    // ---- epilogue: h_new = h_old + acc + bo (stored); fused LN -> zout ----
    float rsum[4][4], rsq[4][4];
#pragma unroll
    for (int mi = 0; mi < 4; ++mi)
#pragma unroll
        for (int rg = 0; rg < 4; ++rg) { rsum[mi][rg] = 0.f; rsq[mi][rg] = 0.f; }

#pragma unroll
    for (int j = 0; j < 3; ++j) {
        int col = 48 * wave + 16 * j + r16;
        float bj = bo[col];
#pragma unroll
        for (int mi = 0; mi < 4; ++mi) {
#pragma unroll
            for (int rg = 0; rg < 4; ++rg) {
                int row = r0 + 16 * mi + 4 * g + rg;
                float hv = h[(size_t)row * C_ + col] + acc[mi][j][rg] + bj;
                h[(size_t)row * C_ + col] = hv;
                acc[mi][j][rg] = hv;
                rsum[mi][rg] += hv;
                rsq[mi][rg]  += hv * hv;
            }
        }
    }
#pragma unroll
    for (int o = 1; o < 16; o <<= 1) {
#pragma unroll
        for (int mi = 0; mi < 4; ++mi)
#pragma unroll
            for (int rg = 0; rg < 4; ++rg) {
                rsum[mi][rg] += __shfl_xor(rsum[mi][rg], o, 64);
                rsq[mi][rg]  += __shfl_xor(rsq[mi][rg],  o, 64);
            }
    }
    float* St = (float*)Ol;             // [64 rows][16] floats = 4 KB
    if (r16 == 0) {
#pragma unroll
        for (int mi = 0; mi < 4; ++mi)
#pragma unroll
            for (int rg = 0; rg < 4; ++rg) {
                int rr = 16 * mi + 4 * g + rg;
                St[rr * 16 + 2 * wave]     = rsum[mi][rg];
                St[rr * 16 + 2 * wave + 1] = rsq[mi][rg];
            }
    }
    __syncthreads();
    if (tid < 64) {
        float s = 0.f, s2 = 0.f;
#pragma unroll
        for (int w = 0; w < 8; ++w) { s += St[tid * 16 + 2 * w]; s2 += St[tid * 16 + 2 * w + 1]; }
        float mu  = s * (1.0f / C_);
        float var = s2 * (1.0f / C_) - mu * mu;
        St[tid * 16]     = mu;
        St[tid * 16 + 1] = rsqrtf(var + EPS_);
    }
    __syncthreads();
#pragma unroll
    for (int j = 0; j < 3; ++j) {
        int col = 48 * wave + 16 * j + r16;
        float gam = lng[col], bet = lnb[col];
#pragma unroll
        for (int mi = 0; mi < 4; ++mi) {
#pragma unroll
            for (int rg = 0; rg < 4; ++rg) {
                int rr = 16 * mi + 4 * g + rg;
                float mu = St[rr * 16], rs = St[rr * 16 + 1];
                zout[(size_t)(r0 + rr) * C_ + col] = f2bf((acc[mi][j][rg] - mu) * rs * gam + bet);
            }
        }
    }
}

// ---------------- fused FFN v2 (round-11/19 best): h += relu(z@W1+b1)@W2 + b2 ----
__global__ __launch_bounds__(512) void ffn_kernel(const short* __restrict__ z,
                                                  const short* __restrict__ w1t,
                                                  const short* __restrict__ w2t,
                                                  const float* __restrict__ b1,
                                                  const float* __restrict__ b2,
                                                  float* __restrict__ h) {
    __shared__ short Zl[48 * 64 * 8];   // 48 KB: [koct][row][8]
    __shared__ short Pl[16 * 64 * 8];   // 16 KB: [ffoct][row][8]
    int tid  = threadIdx.x;
    int wave = tid >> 6, lane = tid & 63;
    int g = lane >> 4, r16 = lane & 15;
    int r0 = blockIdx.x * 64;

    {
        const short* gz = z + (size_t)(r0 + lane) * C_ + wave * 8;
        short* lz = Zl + (wave * 64 + lane) * 8;
#pragma unroll
        for (int ro = 0; ro < 6; ++ro) {
            GLDS16(gz, lz);
            gz += 64;
            lz += 8 * 64 * 8;
        }
    }

    const short* w1base = w1t + (size_t)(16 * wave + r16) * C_ + 8 * g;
    const short* w2base = w2t + (size_t)(48 * wave + r16) * FF_ + 8 * g;

    bf16x8 w1f[12];
#pragma unroll
    for (int ks = 0; ks < 12; ++ks)
        w1f[ks] = *(const bf16x8*)(w1base + ks * 32);

    asm volatile("s_waitcnt vmcnt(0)" ::: "memory");
    __builtin_amdgcn_s_barrier();
    asm volatile("" ::: "memory");

    f32x4 acc2[4][3];
#pragma unroll
    for (int mi = 0; mi < 4; ++mi)
#pragma unroll
        for (int j = 0; j < 3; ++j) { acc2[mi][j][0]=0.f; acc2[mi][j][1]=0.f; acc2[mi][j][2]=0.f; acc2[mi][j][3]=0.f; }

    for (int c = 0; c < 12; ++c) {
        bf16x8 w2f[12];
#pragma unroll
        for (int ks2 = 0; ks2 < 4; ++ks2)
#pragma unroll
            for (int j = 0; j < 3; ++j)
                w2f[ks2 * 3 + j] = *(const bf16x8*)(w2base + (size_t)(16 * j) * FF_
                                                    + 128 * c + 32 * ks2);

        f32x4 acc1[4];
#pragma unroll
        for (int mj = 0; mj < 4; ++mj) { acc1[mj][0]=0.f; acc1[mj][1]=0.f; acc1[mj][2]=0.f; acc1[mj][3]=0.f; }
#pragma unroll
        for (int ks = 0; ks < 12; ++ks) {
#pragma unroll
            for (int mj = 0; mj < 4; ++mj) {
                bf16x8 bz = *(const bf16x8*)(Zl + ((4 * ks + g) * 64 + 16 * mj + r16) * 8);
                acc1[mj] = __builtin_amdgcn_mfma_f32_16x16x32_bf16(w1f[ks], bz, acc1[mj], 0, 0, 0);
            }
        }
        f32x4 b1v = *(const f32x4*)(b1 + 128 * c + 16 * wave + 4 * g);
        int oct = 2 * wave + (g >> 1);
#pragma unroll
        for (int mj = 0; mj < 4; ++mj) {
            short4v pv;
#pragma unroll
            for (int rg = 0; rg < 4; ++rg)
                pv[rg] = f2bf(fmaxf(acc1[mj][rg] + b1v[rg], 0.f));
            *(short4v*)(Pl + (oct * 64 + 16 * mj + r16) * 8 + (g & 1) * 4) = pv;
        }
        __syncthreads();

        if (c + 1 < 12) {
#pragma unroll
            for (int ks = 0; ks < 12; ++ks)
                w1f[ks] = *(const bf16x8*)(w1base + (size_t)(c + 1) * 128 * C_ + ks * 32);
        }

#pragma unroll
        for (int ks2 = 0; ks2 < 4; ++ks2) {
            bf16x8 pa[4];
#pragma unroll
            for (int mi = 0; mi < 4; ++mi)
                pa[mi] = *(const bf16x8*)(Pl + ((4 * ks2 + g) * 64 + 16 * mi + r16) * 8);
#pragma unroll
            for (int j = 0; j < 3; ++j) {
#pragma unroll
                for (int mi = 0; mi < 4; ++mi)
                    acc2[mi][j] = __builtin_amdgcn_mfma_f32_16x16x32_bf16(pa[mi], w2f[ks2 * 3 + j], acc2[mi][j], 0, 0, 0);
            }
        }
        __syncthreads();
    }

#pragma unroll
    for (int j = 0; j < 3; ++j) {
        int col = 48 * wave + 16 * j + r16;
        float bj = b2[col];
#pragma unroll
        for (int mi = 0; mi < 4; ++mi) {
#pragma unroll
            for (int rg = 0; rg < 4; ++rg) {
                int row = r0 + 16 * mi + 4 * g + rg;
                h[(size_t)row * C_ + col] += acc2[mi][j][rg] + bj;
            }
        }
    }
}

// ---------------- MFMA flash attention v3: paired q-tiles ----------------
__device__ __forceinline__ void attn_step(int kt, int qg, int g, int r16,
                                          const char* Kb, unsigned ka, unsigned va,
                                          short (*Pw)[40],
                                          bf16x8 qf0, bf16x8 qf1,
                                          f32x4* o_acc, float& m, float& l) {
    f32x4 s0, s1;
    s0[0]=0.f;s0[1]=0.f;s0[2]=0.f;s0[3]=0.f;
    s1[0]=0.f;s1[1]=0.f;s1[2]=0.f;s1[3]=0.f;
    bf16x8 a00 = *(const bf16x8*)(Kb + ka);
    bf16x8 a01 = *(const bf16x8*)(Kb + (ka ^ 64u));
    bf16x8 a10 = *(const bf16x8*)(Kb + ka + 2048u);
    bf16x8 a11 = *(const bf16x8*)(Kb + ((ka + 2048u) ^ 64u));
    s0 = __builtin_amdgcn_mfma_f32_16x16x32_bf16(a00, qf0, s0, 0, 0, 0);
    s0 = __builtin_amdgcn_mfma_f32_16x16x32_bf16(a01, qf1, s0, 0, 0, 0);
    s1 = __builtin_amdgcn_mfma_f32_16x16x32_bf16(a10, qf0, s1, 0, 0, 0);
    s1 = __builtin_amdgcn_mfma_f32_16x16x32_bf16(a11, qf1, s1, 0, 0, 0);

    int kb0 = kt * 32 + 4 * g;
    float sv[8];
#pragma unroll
    for (int r = 0; r < 4; ++r) {
        sv[r]     = (kb0 + r      <= qg) ? s0[r] * 0.125f : -3e38f;
        sv[4 + r] = (kb0 + 16 + r <= qg) ? s1[r] * 0.125f : -3e38f;
    }
    float pmax = sv[0];
#pragma unroll
    for (int i = 1; i < 8; ++i) pmax = fmaxf(pmax, sv[i]);
    pmax = fmaxf(pmax, __shfl_xor(pmax, 16, 64));
    pmax = fmaxf(pmax, __shfl_xor(pmax, 32, 64));
    float mn   = fmaxf(m, pmax);
    float corr = __expf(m - mn);
    float rs = 0.f;
    short pb[8];
#pragma unroll
    for (int i = 0; i < 8; ++i) {
        float p = __expf(sv[i] - mn);
        rs += p;
        pb[i] = f2bf(p);
    }
    rs += __shfl_xor(rs, 16, 64);
    rs += __shfl_xor(rs, 32, 64);
    l = l * corr + rs;
    m = mn;

    short4v t0w, t1w;
    t0w[0]=pb[0]; t0w[1]=pb[1]; t0w[2]=pb[2]; t0w[3]=pb[3];
    t1w[0]=pb[4]; t1w[1]=pb[5]; t1w[2]=pb[6]; t1w[3]=pb[7];
    *(short4v*)&Pw[r16][4 * g]      = t0w;
    *(short4v*)&Pw[r16][16 + 4 * g] = t1w;

    short4v v0, v1, v2, v3, v4, v5, v6, v7;
    TRRD(v0, va, "0");    TRRD(v1, va, "512");
    TRRD(v2, va, "128");  TRRD(v3, va, "640");
    TRRD(v4, va, "256");  TRRD(v5, va, "768");
    TRRD(v6, va, "384");  TRRD(v7, va, "896");

    bf16x8 pB = *(const bf16x8*)&Pw[r16][8 * g];
#pragma unroll
    for (int d = 0; d < 4; ++d) {
        o_acc[d][0] *= corr; o_acc[d][1] *= corr;
        o_acc[d][2] *= corr; o_acc[d][3] *= corr;
    }
    asm volatile("s_waitcnt lgkmcnt(0)" ::: "memory");
    __builtin_amdgcn_sched_barrier(0);

    bf16x8 av0, av1, av2, av3;
#pragma unroll
    for (int i = 0; i < 4; ++i) {
        av0[i] = v0[i]; av0[i + 4] = v1[i];
        av1[i] = v2[i]; av1[i + 4] = v3[i];
        av2[i] = v4[i]; av2[i + 4] = v5[i];
        av3[i] = v6[i]; av3[i + 4] = v7[i];
    }
    o_acc[0] = __builtin_amdgcn_mfma_f32_16x16x32_bf16(av0, pB, o_acc[0], 0, 0, 0);
    o_acc[1] = __builtin_amdgcn_mfma_f32_16x16x32_bf16(av1, pB, o_acc[1], 0, 0, 0);
    o_acc[2] = __builtin_amdgcn_mfma_f32_16x16x32_bf16(av2, pB, o_acc[2], 0, 0, 0);
    o_acc[3] = __builtin_amdgcn_mfma_f32_16x16x32_bf16(av3, pB, o_acc[3], 0, 0, 0);
}

__global__ __launch_bounds__(256) void attn_kernel(const short* __restrict__ qkv,
                                                   short* __restrict__ o) {
    __shared__ short Kl[32 * 64];
    __shared__ short Vl[32 * 64];
    __shared__ short P_lds[4][16][40];

    int tid  = threadIdx.x;
    int wave = tid >> 6;
    int lane = tid & 63;
    int g    = lane >> 4;
    int r16  = lane & 15;

    int qtA = blockIdx.x;
    int qtB = 15 - qtA;
    int bh = blockIdx.y;
    int b  = bh / H_, hh = bh - b * H_;
    size_t rbase = (size_t)b * T_;
    int qoff = hh * 64;

    int q0A = qtA * 64, q0B = qtB * 64;
    int qgA = q0A + wave * 16 + r16;
    int qgB = q0B + wave * 16 + r16;

    const short* qrA = qkv + (rbase + qgA) * 1152 + qoff;
    const short* qrB = qkv + (rbase + qgB) * 1152 + qoff;
    bf16x8 qfA0 = *(const bf16x8*)(qrA + 8 * g);
    bf16x8 qfA1 = *(const bf16x8*)(qrA + 32 + 8 * g);
    bf16x8 qfB0 = *(const bf16x8*)(qrB + 8 * g);
    bf16x8 qfB1 = *(const bf16x8*)(qrB + 32 + 8 * g);

    int kkey = tid >> 3;
    int koct = (tid & 7) ^ (kkey & 7);
    const short* gk = qkv + (rbase + kkey) * 1152 + qoff + 384 + koct * 8;
    int vkey = 4 * (tid >> 5) + ((tid >> 1) & 3);
    int voct = 2 * ((tid >> 3) & 3) + (tid & 1);
    const short* gv = qkv + (rbase + vkey) * 1152 + qoff + 768 + voct * 8;
    short* lk = Kl + tid * 8;
    short* lv = Vl + tid * 8;

    f32x4 oA[4], oB[4];
#pragma unroll
    for (int d = 0; d < 4; ++d) {
        oA[d][0]=0.f; oA[d][1]=0.f; oA[d][2]=0.f; oA[d][3]=0.f;
        oB[d][0]=0.f; oB[d][1]=0.f; oB[d][2]=0.f; oB[d][3]=0.f;
    }
    float mA = -3e38f, lA = 0.f, mB = -3e38f, lB = 0.f;

    const char* Kb = (const char*)Kl;
    unsigned ka = (unsigned)(r16 * 128 + ((g ^ (r16 & 7)) << 4));
    unsigned va = (unsigned)(size_t)(__attribute__((address_space(3))) short*)Vl
                + 1024u * (unsigned)g + 8u * (unsigned)r16;

    int ktA_hi = (q0A + wave * 16 + 15) >> 5;
    int ktB_hi = (q0B + wave * 16 + 15) >> 5;
    int nkt = 2 * (qtB + 1);

    for (int kt = 0; kt < nkt; ++kt) {
        __syncthreads();
        GLDS16(gk, lk);
        GLDS16(gv, lv);
        gk += 32 * 1152; gv += 32 * 1152;
        __syncthreads();

        if (kt <= ktB_hi)
            attn_step(kt, qgB, g, r16, Kb, ka, va, P_lds[wave], qfB0, qfB1, oB, mB, lB);
        if (kt <= ktA_hi)
            attn_step(kt, qgA, g, r16, Kb, ka, va, P_lds[wave], qfA0, qfA1, oA, mA, lA);
    }

    {
        float inv = (lA > 0.f) ? 1.f / lA : 0.f;
        short* orow = o + (rbase + qgA) * C_ + qoff;
#pragma unroll
        for (int d = 0; d < 4; ++d) {
            short4v ov;
#pragma unroll
            for (int r = 0; r < 4; ++r) ov[r] = f2bf(oA[d][r] * inv);
            *(short4v*)(orow + 16 * d + 4 * g) = ov;
        }
    }
    if (qgB < T_) {
        float inv = (lB > 0.f) ? 1.f / lB : 0.f;
        short* orow = o + (rbase + qgB) * C_ + qoff;
#pragma unroll
        for (int d = 0; d < 4; ++d) {
            short4v ov;
#pragma unroll
            for (int r = 0; r < 4; ++r) ov[r] = f2bf(oB[d][r] * inv);
            *(short4v*)(orow + 16 * d + 4 * g) = ov;
        }
    }
}

// ---------------- per-row NLL: 4 rows per 256-thread block ----------------
__global__ __launch_bounds__(256) void nll_kernel(const float* __restrict__ logits,
                                                  const int* __restrict__ tgt,
                                                  float* __restrict__ nll) {
    int wave = threadIdx.x >> 6, lane = threadIdx.x & 63;
    int row  = blockIdx.x * 4 + wave;       // M_ = 4092*4 exactly
    const float* rp = logits + (size_t)row * V_;
    float v[4];
    float mx = -INFINITY;
#pragma unroll
    for (int i = 0; i < 4; ++i) {
        v[i] = rp[i * 64 + lane];
        mx = fmaxf(mx, v[i]);
    }
#pragma unroll
    for (int o = 32; o > 0; o >>= 1) mx = fmaxf(mx, __shfl_xor(mx, o, 64));
    float s = 0.f;
#pragma unroll
    for (int i = 0; i < 4; ++i) s += expf(v[i] - mx);
#pragma unroll
    for (int o = 32; o > 0; o >>= 1) s += __shfl_xor(s, o, 64);
    if (lane == 0) {
        float lse = mx + logf(s);
        nll[row] = lse - rp[tgt[row]];
    }
}

// ---------------- final deterministic mean reduce ----------------
__global__ __launch_bounds__(256) void loss_kernel(const float* __restrict__ nll,
                                                   float* __restrict__ loss) {
    __shared__ float sm[256];
    float s = 0.f;
    for (int i = threadIdx.x; i < M_; i += 256) s += nll[i];
    sm[threadIdx.x] = s;
    __syncthreads();
    for (int o = 128; o > 0; o >>= 1) {
        if (threadIdx.x < o) sm[threadIdx.x] += sm[threadIdx.x + o];
        __syncthreads();
    }
    if (threadIdx.x == 0) *loss = sm[0] * (1.0f / M_);
}

// ---------------- host launcher ----------------
extern "C" void kernel_launch(void* const* d_in, const int* in_sizes, int n_in,
                              void* d_out, int out_size, void* d_ws, size_t ws_size,
                              hipStream_t stream) {
    const int*   x       = (const int*)d_in[0];
    const int*   targets = (const int*)d_in[1];
    const float* tok_emb = (const float*)d_in[2];
    const float* pos_emb = (const float*)d_in[3];
    const float* Wq      = (const float*)d_in[4];
    const float* Wk      = (const float*)d_in[5];
    const float* Wv      = (const float*)d_in[6];
    const float* Wo      = (const float*)d_in[7];
    const float* bo      = (const float*)d_in[8];
    const float* ln1_g   = (const float*)d_in[9];
    const float* ln1_b   = (const float*)d_in[10];
    const float* ln2_g   = (const float*)d_in[11];
    const float* ln2_b   = (const float*)d_in[12];
    const float* W1      = (const float*)d_in[13];
    const float* b1      = (const float*)d_in[14];
    const float* W2      = (const float*)d_in[15];
    const float* b2      = (const float*)d_in[16];
    const float* lnf_g   = (const float*)d_in[17];
    const float* lnf_b   = (const float*)d_in[18];
    const float* Wf      = (const float*)d_in[19];
    const float* bf      = (const float*)d_in[20];

    float* logits = (float*)d_out;
    float* loss   = logits + (size_t)M_ * V_;

    float* h    = (float*)d_ws;                          // [MP_][C_] fp32
    short* z    = (short*)(h + (size_t)MP_ * C_);        // [MP_][C_] bf16
    short* big  = z + (size_t)MP_ * C_;                  // [MP_][FF_] bf16 (qkv)
    short* ob   = big + (size_t)MP_ * FF_;               // [MP_][C_] bf16
    short* qkvt = ob + (size_t)MP_ * C_;                 // [L][1152][384]
    short* wot  = qkvt + (size_t)L_ * 1152 * 384;        // [L][384][384]
    short* w1t  = wot + (size_t)L_ * 384 * 384;          // [L][1536][384]
    short* w2t  = w1t + (size_t)L_ * 1536 * 384;         // [L][384][1536]
    short* wft  = w2t + (size_t)L_ * 1536 * 384;         // [256][384]
    float* nll  = (float*)(wft + (size_t)256 * 384);     // [M_]

    wconv_kernel<<<10464, 256, 0, stream>>>(Wq, Wk, Wv, Wo, W1, W2, Wf,
                                            qkvt, wot, w1t, w2t, wft);
    embed_kernel<<<(M_ * C_ + 255) / 256, 256, 0, stream>>>(x, tok_emb, pos_emb, h);

    for (int l = 0; l < L_; ++l) {
        ln_kernel<<<M_ / 4, 256, 0, stream>>>(h, ln1_g + l * C_, ln1_b + l * C_, z);
        qkv_kernel<<<MP_ / 64, 512, 0, stream>>>(z, qkvt + (size_t)l * 1152 * 384, big);
        attn_kernel<<<dim3(8, B_ * H_), 256, 0, stream>>>(big, ob);
        wo_kernel<<<MP_ / 64, 512, 0, stream>>>(
            ob, wot + (size_t)l * 384 * 384, bo + l * C_, h,
            ln2_g + l * C_, ln2_b + l * C_, z);
        ffn_kernel<<<MP_ / 64, 512, 0, stream>>>(
            z, w1t + (size_t)l * 1536 * 384, w2t + (size_t)l * 384 * 1536,
            b1 + l * FF_, b2 + l * C_, h);
    }

    ln_kernel<<<M_ / 4, 256, 0, stream>>>(h, lnf_g, lnf_b, z);
    mm_kernel<2, false, true><<<dim3(128, 2), 256, 0, stream>>>(
        z, wft, bf, nullptr, logits, 256, 384);

    nll_kernel<<<M_ / 4, 256, 0, stream>>>(logits, targets, nll);
    loss_kernel<<<1, 256, 0, stream>>>(nll, loss);
}

// Round 22
// 1253.875 us; speedup vs baseline: 1.0524x; 1.0171x over previous
//
#include <hip/hip_runtime.h>
#include <hip/hip_bf16.h>
#include <math.h>

// Problem constants
#define B_  16
#define T_  1023
#define C_  384
#define H_  6
#define DH_ 64
#define L_  6
#define V_  256
#define FF_ 1536
#define M_  (B_*T_)      // 16368 rows
#define MP_ 16384        // padded rows (128-multiple)
#define EPS_ 1e-5f

typedef __attribute__((ext_vector_type(8))) short bf16x8;
typedef __attribute__((ext_vector_type(4))) short short4v;
typedef __attribute__((ext_vector_type(4))) float f32x4;

__device__ inline short f2bf(float x) {   // RNE float->bf16
    union { float f; unsigned u; } c; c.f = x;
    unsigned r = (c.u + 0x7fffu + ((c.u >> 16) & 1u)) >> 16;
    return (short)r;
}

#define GLDS16(g, l) __builtin_amdgcn_global_load_lds(                         \
    (const __attribute__((address_space(1))) void*)(g),                        \
    (__attribute__((address_space(3))) void*)(l), 16, 0, 0)

// hardware transpose read: 4 bf16 per lane (rule #18: waitcnt+sched_barrier after)
#define TRRD(dst, va, IMM) asm volatile("ds_read_b64_tr_b16 %0, %1 offset:" IMM \
    : "=v"(dst) : "v"(va))

// ---------------- embedding: h = tok_emb[x] + pos_emb (fp32) ----------------
__global__ void embed_kernel(const int* __restrict__ x, const float* __restrict__ tok,
                             const float* __restrict__ pos, float* __restrict__ h) {
    int i = blockIdx.x * 256 + threadIdx.x;
    if (i >= M_ * C_) return;
    int bt = i / C_;
    int c  = i - bt * C_;
    int t  = bt % T_;
    h[i] = tok[x[bt] * C_ + c] + pos[t * C_ + c];
}

// ---------------- weight transpose+convert: src fp32 [K][N] -> dst bf16 [N][K] ----
__global__ __launch_bounds__(256) void wconv_kernel(
    const float* __restrict__ Wq, const float* __restrict__ Wk,
    const float* __restrict__ Wv, const float* __restrict__ Wo,
    const float* __restrict__ W1, const float* __restrict__ W2,
    const float* __restrict__ Wf,
    short* __restrict__ qkvt, short* __restrict__ wot, short* __restrict__ w1t,
    short* __restrict__ w2t, short* __restrict__ wft) {
    __shared__ float tile[32][33];
    int t = blockIdx.x;
    const float* src; short* dst; int K, N, tl;
    if (t < 10368) {
        int l = t / 1728, r = t - l * 1728;
        if (r < 432) {                 // Wq/Wk/Wv -> fused qkv^T rows
            int which = r / 144; tl = r - which * 144;
            src = (which == 0 ? Wq : which == 1 ? Wk : Wv) + (size_t)l * 384 * 384;
            dst = qkvt + (size_t)l * 1152 * 384 + (size_t)which * 384 * 384;
            K = 384; N = 384;
        } else if (r < 576) {
            tl = r - 432;
            src = Wo + (size_t)l * 384 * 384; dst = wot + (size_t)l * 384 * 384;
            K = 384; N = 384;
        } else if (r < 1152) {
            tl = r - 576;
            src = W1 + (size_t)l * 384 * 1536; dst = w1t + (size_t)l * 1536 * 384;
            K = 384; N = 1536;
        } else {
            tl = r - 1152;
            src = W2 + (size_t)l * 1536 * 384; dst = w2t + (size_t)l * 384 * 1536;
            K = 1536; N = 384;
        }
    } else {
        tl = t - 10368; src = Wf; dst = wft; K = 384; N = 256;
    }
    int ntx = N >> 5;
    int k0 = (tl / ntx) << 5, n0 = (tl % ntx) << 5;
    int rr = threadIdx.x >> 5, cc = threadIdx.x & 31;
#pragma unroll
    for (int p = 0; p < 4; ++p)
        tile[rr + 8 * p][cc] = src[(size_t)(k0 + rr + 8 * p) * N + n0 + cc];
    __syncthreads();
#pragma unroll
    for (int p = 0; p < 4; ++p)
        dst[(size_t)(n0 + rr + 8 * p) * K + k0 + cc] = f2bf(tile[cc][rr + 8 * p]);
}

// ---------------- LayerNorm: fp32 in -> bf16 out, 4 rows per block ----------------
__global__ __launch_bounds__(256) void ln_kernel(const float* __restrict__ in,
                                                 const float* __restrict__ g,
                                                 const float* __restrict__ b,
                                                 short* __restrict__ out) {
    int wave = threadIdx.x >> 6, lane = threadIdx.x & 63;
    int row  = blockIdx.x * 4 + wave;       // M_ = 4092*4 exactly
    const float* rp = in + (size_t)row * C_;
    float v[6];
    float s = 0.f, s2 = 0.f;
#pragma unroll
    for (int i = 0; i < 6; ++i) {
        v[i] = rp[i * 64 + lane];
        s  += v[i];
        s2 += v[i] * v[i];
    }
#pragma unroll
    for (int o = 32; o > 0; o >>= 1) {
        s  += __shfl_xor(s,  o, 64);
        s2 += __shfl_xor(s2, o, 64);
    }
    float mu  = s * (1.0f / C_);
    float var = s2 * (1.0f / C_) - mu * mu;
    float rs  = rsqrtf(var + EPS_);
    short* op = out + (size_t)row * C_;
#pragma unroll
    for (int i = 0; i < 6; ++i) {
        int c = i * 64 + lane;
        op[c] = f2bf((v[i] - mu) * rs * g[c] + b[c]);
    }
}

// ---------------- bf16 MFMA GEMM (final projection only) ----------------
template<int MODE, bool RELU, bool HB>
__global__ __launch_bounds__(256) void mm_kernel(const short* __restrict__ A,
                                                 const short* __restrict__ Bt,
                                                 const float* __restrict__ bias,
                                                 short* __restrict__ outb,
                                                 float* __restrict__ outf,
                                                 int N, int K) {
    __shared__ short Al[2][8][128][8];   // [dbuf][k-octet][row][8] = 32 KB
    __shared__ short Bl[2][8][128][8];   // 32 KB
    int tid  = threadIdx.x;
    int wave = tid >> 6, lane = tid & 63;
    int kg4 = lane >> 4, r16 = lane & 15;
    int wr = (wave >> 1) * 64, wc = (wave & 1) * 64;
    int row0 = blockIdx.x * 128, col0 = blockIdx.y * 128;

    const short* ga = A  + (size_t)(row0 + (tid & 127)) * K + ((tid >> 7) << 5);
    const short* gb = Bt + (size_t)(col0 + (tid & 127)) * K + ((tid >> 7) << 5);
    short* alds = &Al[0][0][0][0];
    short* blds = &Bl[0][0][0][0];
    int ldst = ((tid >> 7) << 2) * 1024 + (tid & 127) * 8;   // shorts

    f32x4 acc[4][4];
#pragma unroll
    for (int i = 0; i < 4; ++i)
#pragma unroll
        for (int j = 0; j < 4; ++j) { acc[i][j][0]=0.f; acc[i][j][1]=0.f; acc[i][j][2]=0.f; acc[i][j][3]=0.f; }

#define MM_STAGE(BUF)                                                          \
    {                                                                          \
        short* la = alds + (BUF) * 8192 + ldst;                                \
        short* lb = blds + (BUF) * 8192 + ldst;                                \
        GLDS16(ga,      la);        GLDS16(ga + 8,  la + 1024);                \
        GLDS16(ga + 16, la + 2048); GLDS16(ga + 24, la + 3072);                \
        GLDS16(gb,      lb);        GLDS16(gb + 8,  lb + 1024);                \
        GLDS16(gb + 16, lb + 2048); GLDS16(gb + 24, lb + 3072);                \
        ga += 64; gb += 64;                                                    \
    }

#define MM_COMPUTE(BUF)                                                        \
    {                                                                          \
        _Pragma("unroll")                                                      \
        for (int p = 0; p < 2; ++p) {                                          \
            const short* ab = alds + (BUF) * 8192 + (4 * p + kg4) * 1024;      \
            const short* bb = blds + (BUF) * 8192 + (4 * p + kg4) * 1024;      \
            bf16x8 av[4], bv[4];                                               \
            _Pragma("unroll")                                                  \
            for (int i = 0; i < 4; ++i) av[i] = *(const bf16x8*)(ab + (wr + 16*i + r16) * 8); \
            _Pragma("unroll")                                                  \
            for (int j = 0; j < 4; ++j) bv[j] = *(const bf16x8*)(bb + (wc + 16*j + r16) * 8); \
            _Pragma("unroll")                                                  \
            for (int i = 0; i < 4; ++i)                                        \
                _Pragma("unroll")                                              \
                for (int j = 0; j < 4; ++j)                                    \
                    acc[i][j] = __builtin_amdgcn_mfma_f32_16x16x32_bf16(av[i], bv[j], acc[i][j], 0, 0, 0); \
        }                                                                      \
    }

    int NT = K >> 6;
    MM_STAGE(0);
    MM_STAGE(1);
    asm volatile("s_waitcnt vmcnt(8)" ::: "memory");
    __builtin_amdgcn_s_barrier();
    asm volatile("" ::: "memory");

    for (int t = 0; t < NT - 1; ++t) {
        MM_COMPUTE(t & 1);
        __builtin_amdgcn_s_barrier();
        asm volatile("" ::: "memory");
        if (t + 2 < NT) {
            MM_STAGE(t & 1);
            asm volatile("s_waitcnt vmcnt(8)" ::: "memory");
        } else {
            asm volatile("s_waitcnt vmcnt(0)" ::: "memory");
        }
        __builtin_amdgcn_s_barrier();
        asm volatile("" ::: "memory");
    }
    MM_COMPUTE((NT - 1) & 1);
#undef MM_STAGE
#undef MM_COMPUTE

#pragma unroll
    for (int j = 0; j < 4; ++j) {
        int col = col0 + wc + 16 * j + r16;
        float bj = HB ? bias[col] : 0.f;
#pragma unroll
        for (int i = 0; i < 4; ++i) {
#pragma unroll
            for (int rg = 0; rg < 4; ++rg) {
                int row = row0 + wr + 16 * i + 4 * kg4 + rg;
                float v = acc[i][j][rg] + bj;
                if (RELU) v = fmaxf(v, 0.f);
                if (MODE == 0) {
                    outb[(size_t)row * N + col] = f2bf(v);
                } else if (MODE == 1) {
                    outf[(size_t)row * N + col] += v;
                } else {
                    if (row < M_) outf[(size_t)row * N + col] = v;
                }
            }
        }
    }
}

// ---------------- QKV GEMM (ffn-FF1 style): big = z @ qkvt^T ----------------
__global__ __launch_bounds__(512) void qkv_kernel(const short* __restrict__ z,
                                                  const short* __restrict__ wt,
                                                  short* __restrict__ outb) {
    __shared__ short Zl[48 * 64 * 8];   // 48 KB
    int tid  = threadIdx.x;
    int wave = tid >> 6, lane = tid & 63;
    int g = lane >> 4, r16 = lane & 15;
    int r0 = blockIdx.x * 64;

    {
        const short* gz = z + (size_t)(r0 + lane) * C_ + wave * 8;
        short* lz = Zl + (wave * 64 + lane) * 8;
#pragma unroll
        for (int ro = 0; ro < 6; ++ro) { GLDS16(gz, lz); gz += 64; lz += 4096; }
    }

    const short* wbase = wt + (size_t)(16 * wave + r16) * C_ + 8 * g;
    bf16x8 wf[12];
#pragma unroll
    for (int ks = 0; ks < 12; ++ks) wf[ks] = *(const bf16x8*)(wbase + ks * 32);

    asm volatile("s_waitcnt vmcnt(0)" ::: "memory");
    __builtin_amdgcn_s_barrier();
    asm volatile("" ::: "memory");

    for (int c = 0; c < 9; ++c) {
        f32x4 acc[4];
#pragma unroll
        for (int mj = 0; mj < 4; ++mj) { acc[mj][0]=0.f; acc[mj][1]=0.f; acc[mj][2]=0.f; acc[mj][3]=0.f; }
#pragma unroll
        for (int ks = 0; ks < 12; ++ks) {
#pragma unroll
            for (int mj = 0; mj < 4; ++mj) {
                bf16x8 bz = *(const bf16x8*)(Zl + ((4 * ks + g) * 64 + 16 * mj + r16) * 8);
                acc[mj] = __builtin_amdgcn_mfma_f32_16x16x32_bf16(wf[ks], bz, acc[mj], 0, 0, 0);
            }
        }
        if (c + 1 < 9) {
#pragma unroll
            for (int ks = 0; ks < 12; ++ks)
                wf[ks] = *(const bf16x8*)(wbase + (size_t)(c + 1) * 128 * C_ + ks * 32);
        }
#pragma unroll
        for (int mj = 0; mj < 4; ++mj) {
            short4v ov;
#pragma unroll
            for (int rg = 0; rg < 4; ++rg) ov[rg] = f2bf(acc[mj][rg]);
            *(short4v*)(outb + (size_t)(r0 + 16 * mj + r16) * 1152
                        + 128 * c + 16 * wave + 4 * g) = ov;
        }
    }
}

// ---------------- Wo GEMM + residual + fused LN2 -> z (ffn-FF2 style) ---------
__global__ __launch_bounds__(512) void wo_kernel(const short* __restrict__ ob,
                                                 const short* __restrict__ wt,
                                                 const float* __restrict__ bo,
                                                 float* __restrict__ h,
                                                 const float* __restrict__ lng,
                                                 const float* __restrict__ lnb,
                                                 short* __restrict__ zout) {
    __shared__ short Ol[48 * 64 * 8];   // 48 KB (reused as LN scratch at end)
    int tid  = threadIdx.x;
    int wave = tid >> 6, lane = tid & 63;
    int g = lane >> 4, r16 = lane & 15;
    int r0 = blockIdx.x * 64;

    {
        const short* go = ob + (size_t)(r0 + lane) * C_ + wave * 8;
        short* lo = Ol + (wave * 64 + lane) * 8;
#pragma unroll
        for (int ro = 0; ro < 6; ++ro) { GLDS16(go, lo); go += 64; lo += 4096; }
    }

    const short* wbase = wt + (size_t)(48 * wave + r16) * C_ + 8 * g;
    bf16x8 wf[12];
#pragma unroll
    for (int ks2 = 0; ks2 < 4; ++ks2)
#pragma unroll
        for (int j = 0; j < 3; ++j)
            wf[ks2 * 3 + j] = *(const bf16x8*)(wbase + (size_t)(16 * j) * C_ + 32 * ks2);

    asm volatile("s_waitcnt vmcnt(0)" ::: "memory");
    __builtin_amdgcn_s_barrier();
    asm volatile("" ::: "memory");

    f32x4 acc[4][3];
#pragma unroll
    for (int mi = 0; mi < 4; ++mi)
#pragma unroll
        for (int j = 0; j < 3; ++j) { acc[mi][j][0]=0.f; acc[mi][j][1]=0.f; acc[mi][j][2]=0.f; acc[mi][j][3]=0.f; }

    for (int kc = 0; kc < 3; ++kc) {
#pragma unroll
        for (int ks2 = 0; ks2 < 4; ++ks2) {
            bf16x8 pa[4];
#pragma unroll
            for (int mi = 0; mi < 4; ++mi)
                pa[mi] = *(const bf16x8*)(Ol + ((16 * kc + 4 * ks2 + g) * 64 + 16 * mi + r16) * 8);
#pragma unroll
            for (int j = 0; j < 3; ++j)
#pragma unroll
                for (int mi = 0; mi < 4; ++mi)
                    acc[mi][j] = __builtin_amdgcn_mfma_f32_16x16x32_bf16(pa[mi], wf[ks2 * 3 + j], acc[mi][j], 0, 0, 0);
        }
        if (kc + 1 < 3) {
#pragma unroll
            for (int ks2 = 0; ks2 < 4; ++ks2)
#pragma unroll
                for (int j = 0; j < 3; ++j)
                    wf[ks2 * 3 + j] = *(const bf16x8*)(wbase + (size_t)(16 * j) * C_
                                                       + 128 * (kc + 1) + 32 * ks2);
        }
    }
    __syncthreads();               // Ol reads done; reuse as LN scratch

    // ---- epilogue: h_new = h_old + acc + bo (stored); fused LN -> zout ----
    float rsum[4][4], rsq[4][4];
#pragma unroll
    for (int mi = 0; mi < 4; ++mi)
#pragma unroll
        for (int rg = 0; rg < 4; ++rg) { rsum[mi][rg] = 0.f; rsq[mi][rg] = 0.f; }

#pragma unroll
    for (int j = 0; j < 3; ++j) {
        int col = 48 * wave + 16 * j + r16;
        float bj = bo[col];
#pragma unroll
        for (int mi = 0; mi < 4; ++mi) {
#pragma unroll
            for (int rg = 0; rg < 4; ++rg) {
                int row = r0 + 16 * mi + 4 * g + rg;
                float hv = h[(size_t)row * C_ + col] + acc[mi][j][rg] + bj;
                h[(size_t)row * C_ + col] = hv;
                acc[mi][j][rg] = hv;
                rsum[mi][rg] += hv;
                rsq[mi][rg]  += hv * hv;
            }
        }
    }
#pragma unroll
    for (int o = 1; o < 16; o <<= 1) {
#pragma unroll
        for (int mi = 0; mi < 4; ++mi)
#pragma unroll
            for (int rg = 0; rg < 4; ++rg) {
                rsum[mi][rg] += __shfl_xor(rsum[mi][rg], o, 64);
                rsq[mi][rg]  += __shfl_xor(rsq[mi][rg],  o, 64);
            }
    }
    float* St = (float*)Ol;             // [64 rows][16] floats = 4 KB
    if (r16 == 0) {
#pragma unroll
        for (int mi = 0; mi < 4; ++mi)
#pragma unroll
            for (int rg = 0; rg < 4; ++rg) {
                int rr = 16 * mi + 4 * g + rg;
                St[rr * 16 + 2 * wave]     = rsum[mi][rg];
                St[rr * 16 + 2 * wave + 1] = rsq[mi][rg];
            }
    }
    __syncthreads();
    if (tid < 64) {
        float s = 0.f, s2 = 0.f;
#pragma unroll
        for (int w = 0; w < 8; ++w) { s += St[tid * 16 + 2 * w]; s2 += St[tid * 16 + 2 * w + 1]; }
        float mu  = s * (1.0f / C_);
        float var = s2 * (1.0f / C_) - mu * mu;
        St[tid * 16]     = mu;
        St[tid * 16 + 1] = rsqrtf(var + EPS_);
    }
    __syncthreads();
#pragma unroll
    for (int j = 0; j < 3; ++j) {
        int col = 48 * wave + 16 * j + r16;
        float gam = lng[col], bet = lnb[col];
#pragma unroll
        for (int mi = 0; mi < 4; ++mi) {
#pragma unroll
            for (int rg = 0; rg < 4; ++rg) {
                int rr = 16 * mi + 4 * g + rg;
                float mu = St[rr * 16], rs = St[rr * 16 + 1];
                zout[(size_t)(r0 + rr) * C_ + col] = f2bf((acc[mi][j][rg] - mu) * rs * gam + bet);
            }
        }
    }
}

// ---------------- fused FFN v2 (round-11/19 best): h += relu(z@W1+b1)@W2 + b2 ----
__global__ __launch_bounds__(512) void ffn_kernel(const short* __restrict__ z,
                                                  const short* __restrict__ w1t,
                                                  const short* __restrict__ w2t,
                                                  const float* __restrict__ b1,
                                                  const float* __restrict__ b2,
                                                  float* __restrict__ h) {
    __shared__ short Zl[48 * 64 * 8];   // 48 KB: [koct][row][8]
    __shared__ short Pl[16 * 64 * 8];   // 16 KB: [ffoct][row][8]
    int tid  = threadIdx.x;
    int wave = tid >> 6, lane = tid & 63;
    int g = lane >> 4, r16 = lane & 15;
    int r0 = blockIdx.x * 64;

    {
        const short* gz = z + (size_t)(r0 + lane) * C_ + wave * 8;
        short* lz = Zl + (wave * 64 + lane) * 8;
#pragma unroll
        for (int ro = 0; ro < 6; ++ro) {
            GLDS16(gz, lz);
            gz += 64;
            lz += 8 * 64 * 8;
        }
    }

    const short* w1base = w1t + (size_t)(16 * wave + r16) * C_ + 8 * g;
    const short* w2base = w2t + (size_t)(48 * wave + r16) * FF_ + 8 * g;

    bf16x8 w1f[12];
#pragma unroll
    for (int ks = 0; ks < 12; ++ks)
        w1f[ks] = *(const bf16x8*)(w1base + ks * 32);

    asm volatile("s_waitcnt vmcnt(0)" ::: "memory");
    __builtin_amdgcn_s_barrier();
    asm volatile("" ::: "memory");

    f32x4 acc2[4][3];
#pragma unroll
    for (int mi = 0; mi < 4; ++mi)
#pragma unroll
        for (int j = 0; j < 3; ++j) { acc2[mi][j][0]=0.f; acc2[mi][j][1]=0.f; acc2[mi][j][2]=0.f; acc2[mi][j][3]=0.f; }

    for (int c = 0; c < 12; ++c) {
        bf16x8 w2f[12];
#pragma unroll
        for (int ks2 = 0; ks2 < 4; ++ks2)
#pragma unroll
            for (int j = 0; j < 3; ++j)
                w2f[ks2 * 3 + j] = *(const bf16x8*)(w2base + (size_t)(16 * j) * FF_
                                                    + 128 * c + 32 * ks2);

        f32x4 acc1[4];
#pragma unroll
        for (int mj = 0; mj < 4; ++mj) { acc1[mj][0]=0.f; acc1[mj][1]=0.f; acc1[mj][2]=0.f; acc1[mj][3]=0.f; }
#pragma unroll
        for (int ks = 0; ks < 12; ++ks) {
#pragma unroll
            for (int mj = 0; mj < 4; ++mj) {
                bf16x8 bz = *(const bf16x8*)(Zl + ((4 * ks + g) * 64 + 16 * mj + r16) * 8);
                acc1[mj] = __builtin_amdgcn_mfma_f32_16x16x32_bf16(w1f[ks], bz, acc1[mj], 0, 0, 0);
            }
        }
        f32x4 b1v = *(const f32x4*)(b1 + 128 * c + 16 * wave + 4 * g);
        int oct = 2 * wave + (g >> 1);
#pragma unroll
        for (int mj = 0; mj < 4; ++mj) {
            short4v pv;
#pragma unroll
            for (int rg = 0; rg < 4; ++rg)
                pv[rg] = f2bf(fmaxf(acc1[mj][rg] + b1v[rg], 0.f));
            *(short4v*)(Pl + (oct * 64 + 16 * mj + r16) * 8 + (g & 1) * 4) = pv;
        }
        __syncthreads();

        if (c + 1 < 12) {
#pragma unroll
            for (int ks = 0; ks < 12; ++ks)
                w1f[ks] = *(const bf16x8*)(w1base + (size_t)(c + 1) * 128 * C_ + ks * 32);
        }

#pragma unroll
        for (int ks2 = 0; ks2 < 4; ++ks2) {
            bf16x8 pa[4];
#pragma unroll
            for (int mi = 0; mi < 4; ++mi)
                pa[mi] = *(const bf16x8*)(Pl + ((4 * ks2 + g) * 64 + 16 * mi + r16) * 8);
#pragma unroll
            for (int j = 0; j < 3; ++j) {
#pragma unroll
                for (int mi = 0; mi < 4; ++mi)
                    acc2[mi][j] = __builtin_amdgcn_mfma_f32_16x16x32_bf16(pa[mi], w2f[ks2 * 3 + j], acc2[mi][j], 0, 0, 0);
            }
        }
        __syncthreads();
    }

#pragma unroll
    for (int j = 0; j < 3; ++j) {
        int col = 48 * wave + 16 * j + r16;
        float bj = b2[col];
#pragma unroll
        for (int mi = 0; mi < 4; ++mi) {
#pragma unroll
            for (int rg = 0; rg < 4; ++rg) {
                int row = r0 + 16 * mi + 4 * g + rg;
                h[(size_t)row * C_ + col] += acc2[mi][j][rg] + bj;
            }
        }
    }
}

// ---------------- MFMA flash attention v4: paired q-tiles + K/V double-buffer ----
__device__ __forceinline__ void attn_step(int kt, int qg, int g, int r16,
                                          const char* Kb, unsigned ka, unsigned va,
                                          short (*Pw)[40],
                                          bf16x8 qf0, bf16x8 qf1,
                                          f32x4* o_acc, float& m, float& l) {
    f32x4 s0, s1;
    s0[0]=0.f;s0[1]=0.f;s0[2]=0.f;s0[3]=0.f;
    s1[0]=0.f;s1[1]=0.f;s1[2]=0.f;s1[3]=0.f;
    bf16x8 a00 = *(const bf16x8*)(Kb + ka);
    bf16x8 a01 = *(const bf16x8*)(Kb + (ka ^ 64u));
    bf16x8 a10 = *(const bf16x8*)(Kb + ka + 2048u);
    bf16x8 a11 = *(const bf16x8*)(Kb + ((ka + 2048u) ^ 64u));
    s0 = __builtin_amdgcn_mfma_f32_16x16x32_bf16(a00, qf0, s0, 0, 0, 0);
    s0 = __builtin_amdgcn_mfma_f32_16x16x32_bf16(a01, qf1, s0, 0, 0, 0);
    s1 = __builtin_amdgcn_mfma_f32_16x16x32_bf16(a10, qf0, s1, 0, 0, 0);
    s1 = __builtin_amdgcn_mfma_f32_16x16x32_bf16(a11, qf1, s1, 0, 0, 0);

    int kb0 = kt * 32 + 4 * g;
    float sv[8];
#pragma unroll
    for (int r = 0; r < 4; ++r) {
        sv[r]     = (kb0 + r      <= qg) ? s0[r] * 0.125f : -3e38f;
        sv[4 + r] = (kb0 + 16 + r <= qg) ? s1[r] * 0.125f : -3e38f;
    }
    float pmax = sv[0];
#pragma unroll
    for (int i = 1; i < 8; ++i) pmax = fmaxf(pmax, sv[i]);
    pmax = fmaxf(pmax, __shfl_xor(pmax, 16, 64));
    pmax = fmaxf(pmax, __shfl_xor(pmax, 32, 64));
    float mn   = fmaxf(m, pmax);
    float corr = __expf(m - mn);
    float rs = 0.f;
    short pb[8];
#pragma unroll
    for (int i = 0; i < 8; ++i) {
        float p = __expf(sv[i] - mn);
        rs += p;
        pb[i] = f2bf(p);
    }
    rs += __shfl_xor(rs, 16, 64);
    rs += __shfl_xor(rs, 32, 64);
    l = l * corr + rs;
    m = mn;

    short4v t0w, t1w;
    t0w[0]=pb[0]; t0w[1]=pb[1]; t0w[2]=pb[2]; t0w[3]=pb[3];
    t1w[0]=pb[4]; t1w[1]=pb[5]; t1w[2]=pb[6]; t1w[3]=pb[7];
    *(short4v*)&Pw[r16][4 * g]      = t0w;
    *(short4v*)&Pw[r16][16 + 4 * g] = t1w;

    short4v v0, v1, v2, v3, v4, v5, v6, v7;
    TRRD(v0, va, "0");    TRRD(v1, va, "512");
    TRRD(v2, va, "128");  TRRD(v3, va, "640");
    TRRD(v4, va, "256");  TRRD(v5, va, "768");
    TRRD(v6, va, "384");  TRRD(v7, va, "896");

    bf16x8 pB = *(const bf16x8*)&Pw[r16][8 * g];
#pragma unroll
    for (int d = 0; d < 4; ++d) {
        o_acc[d][0] *= corr; o_acc[d][1] *= corr;
        o_acc[d][2] *= corr; o_acc[d][3] *= corr;
    }
    asm volatile("s_waitcnt lgkmcnt(0)" ::: "memory");
    __builtin_amdgcn_sched_barrier(0);

    bf16x8 av0, av1, av2, av3;
#pragma unroll
    for (int i = 0; i < 4; ++i) {
        av0[i] = v0[i]; av0[i + 4] = v1[i];
        av1[i] = v2[i]; av1[i + 4] = v3[i];
        av2[i] = v4[i]; av2[i + 4] = v5[i];
        av3[i] = v6[i]; av3[i + 4] = v7[i];
    }
    o_acc[0] = __builtin_amdgcn_mfma_f32_16x16x32_bf16(av0, pB, o_acc[0], 0, 0, 0);
    o_acc[1] = __builtin_amdgcn_mfma_f32_16x16x32_bf16(av1, pB, o_acc[1], 0, 0, 0);
    o_acc[2] = __builtin_amdgcn_mfma_f32_16x16x32_bf16(av2, pB, o_acc[2], 0, 0, 0);
    o_acc[3] = __builtin_amdgcn_mfma_f32_16x16x32_bf16(av3, pB, o_acc[3], 0, 0, 0);
}

__global__ __launch_bounds__(256) void attn_kernel(const short* __restrict__ qkv,
                                                   short* __restrict__ o) {
    __shared__ short Kl[2][32 * 64];       // 2 x 4 KB (double-buffered)
    __shared__ short Vl[2][32 * 64];       // 2 x 4 KB
    __shared__ short P_lds[4][16][40];     // 5 KB

    int tid  = threadIdx.x;
    int wave = tid >> 6;
    int lane = tid & 63;
    int g    = lane >> 4;
    int r16  = lane & 15;

    int qtA = blockIdx.x;
    int qtB = 15 - qtA;
    int bh = blockIdx.y;
    int b  = bh / H_, hh = bh - b * H_;
    size_t rbase = (size_t)b * T_;
    int qoff = hh * 64;

    int q0A = qtA * 64, q0B = qtB * 64;
    int qgA = q0A + wave * 16 + r16;
    int qgB = q0B + wave * 16 + r16;

    const short* qrA = qkv + (rbase + qgA) * 1152 + qoff;
    const short* qrB = qkv + (rbase + qgB) * 1152 + qoff;
    bf16x8 qfA0 = *(const bf16x8*)(qrA + 8 * g);
    bf16x8 qfA1 = *(const bf16x8*)(qrA + 32 + 8 * g);
    bf16x8 qfB0 = *(const bf16x8*)(qrB + 8 * g);
    bf16x8 qfB1 = *(const bf16x8*)(qrB + 32 + 8 * g);

    int kkey = tid >> 3;
    int koct = (tid & 7) ^ (kkey & 7);
    const short* gk = qkv + (rbase + kkey) * 1152 + qoff + 384 + koct * 8;
    int vkey = 4 * (tid >> 5) + ((tid >> 1) & 3);
    int voct = 2 * ((tid >> 3) & 3) + (tid & 1);
    const short* gv = qkv + (rbase + vkey) * 1152 + qoff + 768 + voct * 8;
    short* lk0 = Kl[0] + tid * 8;
    short* lk1 = Kl[1] + tid * 8;
    short* lv0 = Vl[0] + tid * 8;
    short* lv1 = Vl[1] + tid * 8;

    f32x4 oA[4], oB[4];
#pragma unroll
    for (int d = 0; d < 4; ++d) {
        oA[d][0]=0.f; oA[d][1]=0.f; oA[d][2]=0.f; oA[d][3]=0.f;
        oB[d][0]=0.f; oB[d][1]=0.f; oB[d][2]=0.f; oB[d][3]=0.f;
    }
    float mA = -3e38f, lA = 0.f, mB = -3e38f, lB = 0.f;

    const char* Kb0 = (const char*)Kl[0];
    const char* Kb1 = (const char*)Kl[1];
    unsigned ka = (unsigned)(r16 * 128 + ((g ^ (r16 & 7)) << 4));
    unsigned va0 = (unsigned)(size_t)(__attribute__((address_space(3))) short*)Vl[0]
                 + 1024u * (unsigned)g + 8u * (unsigned)r16;
    unsigned va1 = va0 + 4096u;            // Vl[1] is 4 KB after Vl[0]

    int ktA_hi = (q0A + wave * 16 + 15) >> 5;
    int ktB_hi = (q0B + wave * 16 + 15) >> 5;
    int nkt = 2 * (qtB + 1);

    // prologue: stage tile 0 into buffer 0
    GLDS16(gk, lk0);
    GLDS16(gv, lv0);
    gk += 32 * 1152; gv += 32 * 1152;
    asm volatile("s_waitcnt vmcnt(0)" ::: "memory");
    __builtin_amdgcn_s_barrier();
    asm volatile("" ::: "memory");

    for (int kt = 0; kt < nkt; ++kt) {
        int cur = kt & 1;
        // stage tile kt+1 into the other buffer (hidden under compute below)
        if (kt + 1 < nkt) {
            GLDS16(gk, cur ? lk0 : lk1);
            GLDS16(gv, cur ? lv0 : lv1);
            gk += 32 * 1152; gv += 32 * 1152;
        }
        const char* Kb = cur ? Kb1 : Kb0;
        unsigned va = cur ? va1 : va0;

        if (kt <= ktB_hi)
            attn_step(kt, qgB, g, r16, Kb, ka, va, P_lds[wave], qfB0, qfB1, oB, mB, lB);
        if (kt <= ktA_hi)
            attn_step(kt, qgA, g, r16, Kb, ka, va, P_lds[wave], qfA0, qfA1, oA, mA, lA);

        asm volatile("s_waitcnt vmcnt(0)" ::: "memory");   // stage(kt+1) landed
        __builtin_amdgcn_s_barrier();
        asm volatile("" ::: "memory");
    }

    {
        float inv = (lA > 0.f) ? 1.f / lA : 0.f;
        short* orow = o + (rbase + qgA) * C_ + qoff;
#pragma unroll
        for (int d = 0; d < 4; ++d) {
            short4v ov;
#pragma unroll
            for (int r = 0; r < 4; ++r) ov[r] = f2bf(oA[d][r] * inv);
            *(short4v*)(orow + 16 * d + 4 * g) = ov;
        }
    }
    if (qgB < T_) {
        float inv = (lB > 0.f) ? 1.f / lB : 0.f;
        short* orow = o + (rbase + qgB) * C_ + qoff;
#pragma unroll
        for (int d = 0; d < 4; ++d) {
            short4v ov;
#pragma unroll
            for (int r = 0; r < 4; ++r) ov[r] = f2bf(oB[d][r] * inv);
            *(short4v*)(orow + 16 * d + 4 * g) = ov;
        }
    }
}

// ---------------- per-row NLL: 4 rows per 256-thread block ----------------
__global__ __launch_bounds__(256) void nll_kernel(const float* __restrict__ logits,
                                                  const int* __restrict__ tgt,
                                                  float* __restrict__ nll) {
    int wave = threadIdx.x >> 6, lane = threadIdx.x & 63;
    int row  = blockIdx.x * 4 + wave;       // M_ = 4092*4 exactly
    const float* rp = logits + (size_t)row * V_;
    float v[4];
    float mx = -INFINITY;
#pragma unroll
    for (int i = 0; i < 4; ++i) {
        v[i] = rp[i * 64 + lane];
        mx = fmaxf(mx, v[i]);
    }
#pragma unroll
    for (int o = 32; o > 0; o >>= 1) mx = fmaxf(mx, __shfl_xor(mx, o, 64));
    float s = 0.f;
#pragma unroll
    for (int i = 0; i < 4; ++i) s += expf(v[i] - mx);
#pragma unroll
    for (int o = 32; o > 0; o >>= 1) s += __shfl_xor(s, o, 64);
    if (lane == 0) {
        float lse = mx + logf(s);
        nll[row] = lse - rp[tgt[row]];
    }
}

// ---------------- final deterministic mean reduce ----------------
__global__ __launch_bounds__(256) void loss_kernel(const float* __restrict__ nll,
                                                   float* __restrict__ loss) {
    __shared__ float sm[256];
    float s = 0.f;
    for (int i = threadIdx.x; i < M_; i += 256) s += nll[i];
    sm[threadIdx.x] = s;
    __syncthreads();
    for (int o = 128; o > 0; o >>= 1) {
        if (threadIdx.x < o) sm[threadIdx.x] += sm[threadIdx.x + o];
        __syncthreads();
    }
    if (threadIdx.x == 0) *loss = sm[0] * (1.0f / M_);
}

// ---------------- host launcher ----------------
extern "C" void kernel_launch(void* const* d_in, const int* in_sizes, int n_in,
                              void* d_out, int out_size, void* d_ws, size_t ws_size,
                              hipStream_t stream) {
    const int*   x       = (const int*)d_in[0];
    const int*   targets = (const int*)d_in[1];
    const float* tok_emb = (const float*)d_in[2];
    const float* pos_emb = (const float*)d_in[3];
    const float* Wq      = (const float*)d_in[4];
    const float* Wk      = (const float*)d_in[5];
    const float* Wv      = (const float*)d_in[6];
    const float* Wo      = (const float*)d_in[7];
    const float* bo      = (const float*)d_in[8];
    const float* ln1_g   = (const float*)d_in[9];
    const float* ln1_b   = (const float*)d_in[10];
    const float* ln2_g   = (const float*)d_in[11];
    const float* ln2_b   = (const float*)d_in[12];
    const float* W1      = (const float*)d_in[13];
    const float* b1      = (const float*)d_in[14];
    const float* W2      = (const float*)d_in[15];
    const float* b2      = (const float*)d_in[16];
    const float* lnf_g   = (const float*)d_in[17];
    const float* lnf_b   = (const float*)d_in[18];
    const float* Wf      = (const float*)d_in[19];
    const float* bf      = (const float*)d_in[20];

    float* logits = (float*)d_out;
    float* loss   = logits + (size_t)M_ * V_;

    float* h    = (float*)d_ws;                          // [MP_][C_] fp32
    short* z    = (short*)(h + (size_t)MP_ * C_);        // [MP_][C_] bf16
    short* big  = z + (size_t)MP_ * C_;                  // [MP_][FF_] bf16 (qkv)
    short* ob   = big + (size_t)MP_ * FF_;               // [MP_][C_] bf16
    short* qkvt = ob + (size_t)MP_ * C_;                 // [L][1152][384]
    short* wot  = qkvt + (size_t)L_ * 1152 * 384;        // [L][384][384]
    short* w1t  = wot + (size_t)L_ * 384 * 384;          // [L][1536][384]
    short* w2t  = w1t + (size_t)L_ * 1536 * 384;         // [L][384][1536]
    short* wft  = w2t + (size_t)L_ * 1536 * 384;         // [256][384]
    float* nll  = (float*)(wft + (size_t)256 * 384);     // [M_]

    wconv_kernel<<<10464, 256, 0, stream>>>(Wq, Wk, Wv, Wo, W1, W2, Wf,
                                            qkvt, wot, w1t, w2t, wft);
    embed_kernel<<<(M_ * C_ + 255) / 256, 256, 0, stream>>>(x, tok_emb, pos_emb, h);

    for (int l = 0; l < L_; ++l) {
        ln_kernel<<<M_ / 4, 256, 0, stream>>>(h, ln1_g + l * C_, ln1_b + l * C_, z);
        qkv_kernel<<<MP_ / 64, 512, 0, stream>>>(z, qkvt + (size_t)l * 1152 * 384, big);
        attn_kernel<<<dim3(8, B_ * H_), 256, 0, stream>>>(big, ob);
        wo_kernel<<<MP_ / 64, 512, 0, stream>>>(
            ob, wot + (size_t)l * 384 * 384, bo + l * C_, h,
            ln2_g + l * C_, ln2_b + l * C_, z);
        ffn_kernel<<<MP_ / 64, 512, 0, stream>>>(
            z, w1t + (size_t)l * 1536 * 384, w2t + (size_t)l * 384 * 1536,
            b1 + l * FF_, b2 + l * C_, h);
    }

    ln_kernel<<<M_ / 4, 256, 0, stream>>>(h, lnf_g, lnf_b, z);
    mm_kernel<2, false, true><<<dim3(128, 2), 256, 0, stream>>>(
        z, wft, bf, nullptr, logits, 256, 384);

    nll_kernel<<<M_ / 4, 256, 0, stream>>>(logits, targets, nll);
    loss_kernel<<<1, 256, 0, stream>>>(nll, loss);
}

// Round 23
// 1224.536 us; speedup vs baseline: 1.0776x; 1.0240x over previous
//
#include <hip/hip_runtime.h>
#include <hip/hip_bf16.h>
#include <math.h>

// Problem constants
#define B_  16
#define T_  1023
#define C_  384
#define H_  6
#define DH_ 64
#define L_  6
#define V_  256
#define FF_ 1536
#define M_  (B_*T_)      // 16368 rows
#define MP_ 16384        // padded rows (128-multiple)
#define EPS_ 1e-5f

typedef __attribute__((ext_vector_type(8))) short bf16x8;
typedef __attribute__((ext_vector_type(4))) short short4v;
typedef __attribute__((ext_vector_type(4))) float f32x4;

__device__ inline short f2bf(float x) {   // RNE float->bf16
    union { float f; unsigned u; } c; c.f = x;
    unsigned r = (c.u + 0x7fffu + ((c.u >> 16) & 1u)) >> 16;
    return (short)r;
}

#define GLDS16(g, l) __builtin_amdgcn_global_load_lds(                         \
    (const __attribute__((address_space(1))) void*)(g),                        \
    (__attribute__((address_space(3))) void*)(l), 16, 0, 0)

// hardware transpose read: 4 bf16 per lane (rule #18: waitcnt+sched_barrier after)
#define TRRD(dst, va, IMM) asm volatile("ds_read_b64_tr_b16 %0, %1 offset:" IMM \
    : "=v"(dst) : "v"(va))

// ---------------- embedding: h = tok_emb[x] + pos_emb (fp32) ----------------
__global__ void embed_kernel(const int* __restrict__ x, const float* __restrict__ tok,
                             const float* __restrict__ pos, float* __restrict__ h) {
    int i = blockIdx.x * 256 + threadIdx.x;
    if (i >= M_ * C_) return;
    int bt = i / C_;
    int c  = i - bt * C_;
    int t  = bt % T_;
    h[i] = tok[x[bt] * C_ + c] + pos[t * C_ + c];
}

// ---------------- weight transpose+convert: src fp32 [K][N] -> dst bf16 [N][K] ----
__global__ __launch_bounds__(256) void wconv_kernel(
    const float* __restrict__ Wq, const float* __restrict__ Wk,
    const float* __restrict__ Wv, const float* __restrict__ Wo,
    const float* __restrict__ W1, const float* __restrict__ W2,
    const float* __restrict__ Wf,
    short* __restrict__ qkvt, short* __restrict__ wot, short* __restrict__ w1t,
    short* __restrict__ w2t, short* __restrict__ wft) {
    __shared__ float tile[32][33];
    int t = blockIdx.x;
    const float* src; short* dst; int K, N, tl;
    if (t < 10368) {
        int l = t / 1728, r = t - l * 1728;
        if (r < 432) {                 // Wq/Wk/Wv -> fused qkv^T rows
            int which = r / 144; tl = r - which * 144;
            src = (which == 0 ? Wq : which == 1 ? Wk : Wv) + (size_t)l * 384 * 384;
            dst = qkvt + (size_t)l * 1152 * 384 + (size_t)which * 384 * 384;
            K = 384; N = 384;
        } else if (r < 576) {
            tl = r - 432;
            src = Wo + (size_t)l * 384 * 384; dst = wot + (size_t)l * 384 * 384;
            K = 384; N = 384;
        } else if (r < 1152) {
            tl = r - 576;
            src = W1 + (size_t)l * 384 * 1536; dst = w1t + (size_t)l * 1536 * 384;
            K = 384; N = 1536;
        } else {
            tl = r - 1152;
            src = W2 + (size_t)l * 1536 * 384; dst = w2t + (size_t)l * 384 * 1536;
            K = 1536; N = 384;
        }
    } else {
        tl = t - 10368; src = Wf; dst = wft; K = 384; N = 256;
    }
    int ntx = N >> 5;
    int k0 = (tl / ntx) << 5, n0 = (tl % ntx) << 5;
    int rr = threadIdx.x >> 5, cc = threadIdx.x & 31;
#pragma unroll
    for (int p = 0; p < 4; ++p)
        tile[rr + 8 * p][cc] = src[(size_t)(k0 + rr + 8 * p) * N + n0 + cc];
    __syncthreads();
#pragma unroll
    for (int p = 0; p < 4; ++p)
        dst[(size_t)(n0 + rr + 8 * p) * K + k0 + cc] = f2bf(tile[cc][rr + 8 * p]);
}

// ---------------- LayerNorm: fp32 in -> bf16 out, 4 rows per block ----------------
__global__ __launch_bounds__(256) void ln_kernel(const float* __restrict__ in,
                                                 const float* __restrict__ g,
                                                 const float* __restrict__ b,
                                                 short* __restrict__ out) {
    int wave = threadIdx.x >> 6, lane = threadIdx.x & 63;
    int row  = blockIdx.x * 4 + wave;       // M_ = 4092*4 exactly
    const float* rp = in + (size_t)row * C_;
    float v[6];
    float s = 0.f, s2 = 0.f;
#pragma unroll
    for (int i = 0; i < 6; ++i) {
        v[i] = rp[i * 64 + lane];
        s  += v[i];
        s2 += v[i] * v[i];
    }
#pragma unroll
    for (int o = 32; o > 0; o >>= 1) {
        s  += __shfl_xor(s,  o, 64);
        s2 += __shfl_xor(s2, o, 64);
    }
    float mu  = s * (1.0f / C_);
    float var = s2 * (1.0f / C_) - mu * mu;
    float rs  = rsqrtf(var + EPS_);
    short* op = out + (size_t)row * C_;
#pragma unroll
    for (int i = 0; i < 6; ++i) {
        int c = i * 64 + lane;
        op[c] = f2bf((v[i] - mu) * rs * g[c] + b[c]);
    }
}

// ---------------- bf16 MFMA GEMM (final projection only) ----------------
template<int MODE, bool RELU, bool HB>
__global__ __launch_bounds__(256) void mm_kernel(const short* __restrict__ A,
                                                 const short* __restrict__ Bt,
                                                 const float* __restrict__ bias,
                                                 short* __restrict__ outb,
                                                 float* __restrict__ outf,
                                                 int N, int K) {
    __shared__ short Al[2][8][128][8];   // [dbuf][k-octet][row][8] = 32 KB
    __shared__ short Bl[2][8][128][8];   // 32 KB
    int tid  = threadIdx.x;
    int wave = tid >> 6, lane = tid & 63;
    int kg4 = lane >> 4, r16 = lane & 15;
    int wr = (wave >> 1) * 64, wc = (wave & 1) * 64;
    int row0 = blockIdx.x * 128, col0 = blockIdx.y * 128;

    const short* ga = A  + (size_t)(row0 + (tid & 127)) * K + ((tid >> 7) << 5);
    const short* gb = Bt + (size_t)(col0 + (tid & 127)) * K + ((tid >> 7) << 5);
    short* alds = &Al[0][0][0][0];
    short* blds = &Bl[0][0][0][0];
    int ldst = ((tid >> 7) << 2) * 1024 + (tid & 127) * 8;   // shorts

    f32x4 acc[4][4];
#pragma unroll
    for (int i = 0; i < 4; ++i)
#pragma unroll
        for (int j = 0; j < 4; ++j) { acc[i][j][0]=0.f; acc[i][j][1]=0.f; acc[i][j][2]=0.f; acc[i][j][3]=0.f; }

#define MM_STAGE(BUF)                                                          \
    {                                                                          \
        short* la = alds + (BUF) * 8192 + ldst;                                \
        short* lb = blds + (BUF) * 8192 + ldst;                                \
        GLDS16(ga,      la);        GLDS16(ga + 8,  la + 1024);                \
        GLDS16(ga + 16, la + 2048); GLDS16(ga + 24, la + 3072);                \
        GLDS16(gb,      lb);        GLDS16(gb + 8,  lb + 1024);                \
        GLDS16(gb + 16, lb + 2048); GLDS16(gb + 24, lb + 3072);                \
        ga += 64; gb += 64;                                                    \
    }

#define MM_COMPUTE(BUF)                                                        \
    {                                                                          \
        _Pragma("unroll")                                                      \
        for (int p = 0; p < 2; ++p) {                                          \
            const short* ab = alds + (BUF) * 8192 + (4 * p + kg4) * 1024;      \
            const short* bb = blds + (BUF) * 8192 + (4 * p + kg4) * 1024;      \
            bf16x8 av[4], bv[4];                                               \
            _Pragma("unroll")                                                  \
            for (int i = 0; i < 4; ++i) av[i] = *(const bf16x8*)(ab + (wr + 16*i + r16) * 8); \
            _Pragma("unroll")                                                  \
            for (int j = 0; j < 4; ++j) bv[j] = *(const bf16x8*)(bb + (wc + 16*j + r16) * 8); \
            _Pragma("unroll")                                                  \
            for (int i = 0; i < 4; ++i)                                        \
                _Pragma("unroll")                                              \
                for (int j = 0; j < 4; ++j)                                    \
                    acc[i][j] = __builtin_amdgcn_mfma_f32_16x16x32_bf16(av[i], bv[j], acc[i][j], 0, 0, 0); \
        }                                                                      \
    }

    int NT = K >> 6;
    MM_STAGE(0);
    MM_STAGE(1);
    asm volatile("s_waitcnt vmcnt(8)" ::: "memory");
    __builtin_amdgcn_s_barrier();
    asm volatile("" ::: "memory");

    for (int t = 0; t < NT - 1; ++t) {
        MM_COMPUTE(t & 1);
        __builtin_amdgcn_s_barrier();
        asm volatile("" ::: "memory");
        if (t + 2 < NT) {
            MM_STAGE(t & 1);
            asm volatile("s_waitcnt vmcnt(8)" ::: "memory");
        } else {
            asm volatile("s_waitcnt vmcnt(0)" ::: "memory");
        }
        __builtin_amdgcn_s_barrier();
        asm volatile("" ::: "memory");
    }
    MM_COMPUTE((NT - 1) & 1);
#undef MM_STAGE
#undef MM_COMPUTE

#pragma unroll
    for (int j = 0; j < 4; ++j) {
        int col = col0 + wc + 16 * j + r16;
        float bj = HB ? bias[col] : 0.f;
#pragma unroll
        for (int i = 0; i < 4; ++i) {
#pragma unroll
            for (int rg = 0; rg < 4; ++rg) {
                int row = row0 + wr + 16 * i + 4 * kg4 + rg;
                float v = acc[i][j][rg] + bj;
                if (RELU) v = fmaxf(v, 0.f);
                if (MODE == 0) {
                    outb[(size_t)row * N + col] = f2bf(v);
                } else if (MODE == 1) {
                    outf[(size_t)row * N + col] += v;
                } else {
                    if (row < M_) outf[(size_t)row * N + col] = v;
                }
            }
        }
    }
}

// ---------------- QKV GEMM + fused LN1: big = (LN(h)) @ qkvt^T ----------------
// Block = 64 rows, 512 threads, grid 256. LN1 computed in-kernel: each wave
// LNs 8 rows (h fp32 -> registers -> shuffle reduce -> bf16 into Zl at the
// staging layout [(col>>3)*512 + (row-r0)*8 + (col&7)]). W prefetch issued
// first so its latency hides under LN. No barriers in main loop (Zl RO).
__global__ __launch_bounds__(512) void qkv_kernel(const float* __restrict__ h,
                                                  const float* __restrict__ lng,
                                                  const float* __restrict__ lnb,
                                                  const short* __restrict__ wt,
                                                  short* __restrict__ outb) {
    __shared__ short Zl[48 * 64 * 8];   // 48 KB
    int tid  = threadIdx.x;
    int wave = tid >> 6, lane = tid & 63;
    int g = lane >> 4, r16 = lane & 15;
    int r0 = blockIdx.x * 64;

    // W fragments for chunk 0 (land during LN phase)
    const short* wbase = wt + (size_t)(16 * wave + r16) * C_ + 8 * g;
    bf16x8 wf[12];
#pragma unroll
    for (int ks = 0; ks < 12; ++ks) wf[ks] = *(const bf16x8*)(wbase + ks * 32);

    // gamma/beta for this lane's 6 columns (shared across rows)
    float gv6[6], bv6[6];
#pragma unroll
    for (int i = 0; i < 6; ++i) { gv6[i] = lng[i * 64 + lane]; bv6[i] = lnb[i * 64 + lane]; }

    // fused LN1: wave handles rows r0 + 8*wave .. +7
    for (int rr = 0; rr < 8; ++rr) {
        int lrow = 8 * wave + rr;
        const float* rp = h + (size_t)(r0 + lrow) * C_;
        float v[6];
        float s = 0.f, s2 = 0.f;
#pragma unroll
        for (int i = 0; i < 6; ++i) {
            v[i] = rp[i * 64 + lane];
            s += v[i]; s2 += v[i] * v[i];
        }
#pragma unroll
        for (int o = 32; o > 0; o >>= 1) {
            s  += __shfl_xor(s,  o, 64);
            s2 += __shfl_xor(s2, o, 64);
        }
        float mu = s * (1.0f / C_);
        float rs = rsqrtf(s2 * (1.0f / C_) - mu * mu + EPS_);
#pragma unroll
        for (int i = 0; i < 6; ++i) {
            int col = i * 64 + lane;
            Zl[(col >> 3) * 512 + lrow * 8 + (col & 7)] =
                f2bf((v[i] - mu) * rs * gv6[i] + bv6[i]);
        }
    }
    __syncthreads();

    for (int c = 0; c < 9; ++c) {
        f32x4 acc[4];
#pragma unroll
        for (int mj = 0; mj < 4; ++mj) { acc[mj][0]=0.f; acc[mj][1]=0.f; acc[mj][2]=0.f; acc[mj][3]=0.f; }
#pragma unroll
        for (int ks = 0; ks < 12; ++ks) {
#pragma unroll
            for (int mj = 0; mj < 4; ++mj) {
                bf16x8 bz = *(const bf16x8*)(Zl + ((4 * ks + g) * 64 + 16 * mj + r16) * 8);
                acc[mj] = __builtin_amdgcn_mfma_f32_16x16x32_bf16(wf[ks], bz, acc[mj], 0, 0, 0);
            }
        }
        if (c + 1 < 9) {
#pragma unroll
            for (int ks = 0; ks < 12; ++ks)
                wf[ks] = *(const bf16x8*)(wbase + (size_t)(c + 1) * 128 * C_ + ks * 32);
        }
#pragma unroll
        for (int mj = 0; mj < 4; ++mj) {
            short4v ov;
#pragma unroll
            for (int rg = 0; rg < 4; ++rg) ov[rg] = f2bf(acc[mj][rg]);
            *(short4v*)(outb + (size_t)(r0 + 16 * mj + r16) * 1152
                        + 128 * c + 16 * wave + 4 * g) = ov;
        }
    }
}

// ---------------- Wo GEMM + residual + fused LN2 -> z (ffn-FF2 style) ---------
__global__ __launch_bounds__(512) void wo_kernel(const short* __restrict__ ob,
                                                 const short* __restrict__ wt,
                                                 const float* __restrict__ bo,
                                                 float* __restrict__ h,
                                                 const float* __restrict__ lng,
                                                 const float* __restrict__ lnb,
                                                 short* __restrict__ zout) {
    __shared__ short Ol[48 * 64 * 8];   // 48 KB (reused as LN scratch at end)
    int tid  = threadIdx.x;
    int wave = tid >> 6, lane = tid & 63;
    int g = lane >> 4, r16 = lane & 15;
    int r0 = blockIdx.x * 64;

    {
        const short* go = ob + (size_t)(r0 + lane) * C_ + wave * 8;
        short* lo = Ol + (wave * 64 + lane) * 8;
#pragma unroll
        for (int ro = 0; ro < 6; ++ro) { GLDS16(go, lo); go += 64; lo += 4096; }
    }

    const short* wbase = wt + (size_t)(48 * wave + r16) * C_ + 8 * g;
    bf16x8 wf[12];
#pragma unroll
    for (int ks2 = 0; ks2 < 4; ++ks2)
#pragma unroll
        for (int j = 0; j < 3; ++j)
            wf[ks2 * 3 + j] = *(const bf16x8*)(wbase + (size_t)(16 * j) * C_ + 32 * ks2);

    asm volatile("s_waitcnt vmcnt(0)" ::: "memory");
    __builtin_amdgcn_s_barrier();
    asm volatile("" ::: "memory");

    f32x4 acc[4][3];
#pragma unroll
    for (int mi = 0; mi < 4; ++mi)
#pragma unroll
        for (int j = 0; j < 3; ++j) { acc[mi][j][0]=0.f; acc[mi][j][1]=0.f; acc[mi][j][2]=0.f; acc[mi][j][3]=0.f; }

    for (int kc = 0; kc < 3; ++kc) {
#pragma unroll
        for (int ks2 = 0; ks2 < 4; ++ks2) {
            bf16x8 pa[4];
#pragma unroll
            for (int mi = 0; mi < 4; ++mi)
                pa[mi] = *(const bf16x8*)(Ol + ((16 * kc + 4 * ks2 + g) * 64 + 16 * mi + r16) * 8);
#pragma unroll
            for (int j = 0; j < 3; ++j)
#pragma unroll
                for (int mi = 0; mi < 4; ++mi)
                    acc[mi][j] = __builtin_amdgcn_mfma_f32_16x16x32_bf16(pa[mi], wf[ks2 * 3 + j], acc[mi][j], 0, 0, 0);
        }
        if (kc + 1 < 3) {
#pragma unroll
            for (int ks2 = 0; ks2 < 4; ++ks2)
#pragma unroll
                for (int j = 0; j < 3; ++j)
                    wf[ks2 * 3 + j] = *(const bf16x8*)(wbase + (size_t)(16 * j) * C_
                                                       + 128 * (kc + 1) + 32 * ks2);
        }
    }
    __syncthreads();               // Ol reads done; reuse as LN scratch

    // ---- epilogue: h_new = h_old + acc + bo (stored); fused LN -> zout ----
    float rsum[4][4], rsq[4][4];
#pragma unroll
    for (int mi = 0; mi < 4; ++mi)
#pragma unroll
        for (int rg = 0; rg < 4; ++rg) { rsum[mi][rg] = 0.f; rsq[mi][rg] = 0.f; }

#pragma unroll
    for (int j = 0; j < 3; ++j) {
        int col = 48 * wave + 16 * j + r16;
        float bj = bo[col];
#pragma unroll
        for (int mi = 0; mi < 4; ++mi) {
#pragma unroll
            for (int rg = 0; rg < 4; ++rg) {
                int row = r0 + 16 * mi + 4 * g + rg;
                float hv = h[(size_t)row * C_ + col] + acc[mi][j][rg] + bj;
                h[(size_t)row * C_ + col] = hv;
                acc[mi][j][rg] = hv;
                rsum[mi][rg] += hv;
                rsq[mi][rg]  += hv * hv;
            }
        }
    }
#pragma unroll
    for (int o = 1; o < 16; o <<= 1) {
#pragma unroll
        for (int mi = 0; mi < 4; ++mi)
#pragma unroll
            for (int rg = 0; rg < 4; ++rg) {
                rsum[mi][rg] += __shfl_xor(rsum[mi][rg], o, 64);
                rsq[mi][rg]  += __shfl_xor(rsq[mi][rg],  o, 64);
            }
    }
    float* St = (float*)Ol;             // [64 rows][16] floats = 4 KB
    if (r16 == 0) {
#pragma unroll
        for (int mi = 0; mi < 4; ++mi)
#pragma unroll
            for (int rg = 0; rg < 4; ++rg) {
                int rr = 16 * mi + 4 * g + rg;
                St[rr * 16 + 2 * wave]     = rsum[mi][rg];
                St[rr * 16 + 2 * wave + 1] = rsq[mi][rg];
            }
    }
    __syncthreads();
    if (tid < 64) {
        float s = 0.f, s2 = 0.f;
#pragma unroll
        for (int w = 0; w < 8; ++w) { s += St[tid * 16 + 2 * w]; s2 += St[tid * 16 + 2 * w + 1]; }
        float mu  = s * (1.0f / C_);
        float var = s2 * (1.0f / C_) - mu * mu;
        St[tid * 16]     = mu;
        St[tid * 16 + 1] = rsqrtf(var + EPS_);
    }
    __syncthreads();
#pragma unroll
    for (int j = 0; j < 3; ++j) {
        int col = 48 * wave + 16 * j + r16;
        float gam = lng[col], bet = lnb[col];
#pragma unroll
        for (int mi = 0; mi < 4; ++mi) {
#pragma unroll
            for (int rg = 0; rg < 4; ++rg) {
                int rr = 16 * mi + 4 * g + rg;
                float mu = St[rr * 16], rs = St[rr * 16 + 1];
                zout[(size_t)(r0 + rr) * C_ + col] = f2bf((acc[mi][j][rg] - mu) * rs * gam + bet);
            }
        }
    }
}

// ---------------- fused FFN v2 (round-11/19 best): h += relu(z@W1+b1)@W2 + b2 ----
__global__ __launch_bounds__(512) void ffn_kernel(const short* __restrict__ z,
                                                  const short* __restrict__ w1t,
                                                  const short* __restrict__ w2t,
                                                  const float* __restrict__ b1,
                                                  const float* __restrict__ b2,
                                                  float* __restrict__ h) {
    __shared__ short Zl[48 * 64 * 8];   // 48 KB: [koct][row][8]
    __shared__ short Pl[16 * 64 * 8];   // 16 KB: [ffoct][row][8]
    int tid  = threadIdx.x;
    int wave = tid >> 6, lane = tid & 63;
    int g = lane >> 4, r16 = lane & 15;
    int r0 = blockIdx.x * 64;

    {
        const short* gz = z + (size_t)(r0 + lane) * C_ + wave * 8;
        short* lz = Zl + (wave * 64 + lane) * 8;
#pragma unroll
        for (int ro = 0; ro < 6; ++ro) {
            GLDS16(gz, lz);
            gz += 64;
            lz += 8 * 64 * 8;
        }
    }

    const short* w1base = w1t + (size_t)(16 * wave + r16) * C_ + 8 * g;
    const short* w2base = w2t + (size_t)(48 * wave + r16) * FF_ + 8 * g;

    bf16x8 w1f[12];
#pragma unroll
    for (int ks = 0; ks < 12; ++ks)
        w1f[ks] = *(const bf16x8*)(w1base + ks * 32);

    asm volatile("s_waitcnt vmcnt(0)" ::: "memory");
    __builtin_amdgcn_s_barrier();
    asm volatile("" ::: "memory");

    f32x4 acc2[4][3];
#pragma unroll
    for (int mi = 0; mi < 4; ++mi)
#pragma unroll
        for (int j = 0; j < 3; ++j) { acc2[mi][j][0]=0.f; acc2[mi][j][1]=0.f; acc2[mi][j][2]=0.f; acc2[mi][j][3]=0.f; }

    for (int c = 0; c < 12; ++c) {
        bf16x8 w2f[12];
#pragma unroll
        for (int ks2 = 0; ks2 < 4; ++ks2)
#pragma unroll
            for (int j = 0; j < 3; ++j)
                w2f[ks2 * 3 + j] = *(const bf16x8*)(w2base + (size_t)(16 * j) * FF_
                                                    + 128 * c + 32 * ks2);

        f32x4 acc1[4];
#pragma unroll
        for (int mj = 0; mj < 4; ++mj) { acc1[mj][0]=0.f; acc1[mj][1]=0.f; acc1[mj][2]=0.f; acc1[mj][3]=0.f; }
#pragma unroll
        for (int ks = 0; ks < 12; ++ks) {
#pragma unroll
            for (int mj = 0; mj < 4; ++mj) {
                bf16x8 bz = *(const bf16x8*)(Zl + ((4 * ks + g) * 64 + 16 * mj + r16) * 8);
                acc1[mj] = __builtin_amdgcn_mfma_f32_16x16x32_bf16(w1f[ks], bz, acc1[mj], 0, 0, 0);
            }
        }
        f32x4 b1v = *(const f32x4*)(b1 + 128 * c + 16 * wave + 4 * g);
        int oct = 2 * wave + (g >> 1);
#pragma unroll
        for (int mj = 0; mj < 4; ++mj) {
            short4v pv;
#pragma unroll
            for (int rg = 0; rg < 4; ++rg)
                pv[rg] = f2bf(fmaxf(acc1[mj][rg] + b1v[rg], 0.f));
            *(short4v*)(Pl + (oct * 64 + 16 * mj + r16) * 8 + (g & 1) * 4) = pv;
        }
        __syncthreads();

        if (c + 1 < 12) {
#pragma unroll
            for (int ks = 0; ks < 12; ++ks)
                w1f[ks] = *(const bf16x8*)(w1base + (size_t)(c + 1) * 128 * C_ + ks * 32);
        }

#pragma unroll
        for (int ks2 = 0; ks2 < 4; ++ks2) {
            bf16x8 pa[4];
#pragma unroll
            for (int mi = 0; mi < 4; ++mi)
                pa[mi] = *(const bf16x8*)(Pl + ((4 * ks2 + g) * 64 + 16 * mi + r16) * 8);
#pragma unroll
            for (int j = 0; j < 3; ++j) {
#pragma unroll
                for (int mi = 0; mi < 4; ++mi)
                    acc2[mi][j] = __builtin_amdgcn_mfma_f32_16x16x32_bf16(pa[mi], w2f[ks2 * 3 + j], acc2[mi][j], 0, 0, 0);
            }
        }
        __syncthreads();
    }

#pragma unroll
    for (int j = 0; j < 3; ++j) {
        int col = 48 * wave + 16 * j + r16;
        float bj = b2[col];
#pragma unroll
        for (int mi = 0; mi < 4; ++mi) {
#pragma unroll
            for (int rg = 0; rg < 4; ++rg) {
                int row = r0 + 16 * mi + 4 * g + rg;
                h[(size_t)row * C_ + col] += acc2[mi][j][rg] + bj;
            }
        }
    }
}

// ---------------- MFMA flash attention v4: paired q-tiles + K/V double-buffer ----
__device__ __forceinline__ void attn_step(int kt, int qg, int g, int r16,
                                          const char* Kb, unsigned ka, unsigned va,
                                          short (*Pw)[40],
                                          bf16x8 qf0, bf16x8 qf1,
                                          f32x4* o_acc, float& m, float& l) {
    f32x4 s0, s1;
    s0[0]=0.f;s0[1]=0.f;s0[2]=0.f;s0[3]=0.f;
    s1[0]=0.f;s1[1]=0.f;s1[2]=0.f;s1[3]=0.f;
    bf16x8 a00 = *(const bf16x8*)(Kb + ka);
    bf16x8 a01 = *(const bf16x8*)(Kb + (ka ^ 64u));
    bf16x8 a10 = *(const bf16x8*)(Kb + ka + 2048u);
    bf16x8 a11 = *(const bf16x8*)(Kb + ((ka + 2048u) ^ 64u));
    s0 = __builtin_amdgcn_mfma_f32_16x16x32_bf16(a00, qf0, s0, 0, 0, 0);
    s0 = __builtin_amdgcn_mfma_f32_16x16x32_bf16(a01, qf1, s0, 0, 0, 0);
    s1 = __builtin_amdgcn_mfma_f32_16x16x32_bf16(a10, qf0, s1, 0, 0, 0);
    s1 = __builtin_amdgcn_mfma_f32_16x16x32_bf16(a11, qf1, s1, 0, 0, 0);

    int kb0 = kt * 32 + 4 * g;
    float sv[8];
#pragma unroll
    for (int r = 0; r < 4; ++r) {
        sv[r]     = (kb0 + r      <= qg) ? s0[r] * 0.125f : -3e38f;
        sv[4 + r] = (kb0 + 16 + r <= qg) ? s1[r] * 0.125f : -3e38f;
    }
    float pmax = sv[0];
#pragma unroll
    for (int i = 1; i < 8; ++i) pmax = fmaxf(pmax, sv[i]);
    pmax = fmaxf(pmax, __shfl_xor(pmax, 16, 64));
    pmax = fmaxf(pmax, __shfl_xor(pmax, 32, 64));
    float mn   = fmaxf(m, pmax);
    float corr = __expf(m - mn);
    float rs = 0.f;
    short pb[8];
#pragma unroll
    for (int i = 0; i < 8; ++i) {
        float p = __expf(sv[i] - mn);
        rs += p;
        pb[i] = f2bf(p);
    }
    rs += __shfl_xor(rs, 16, 64);
    rs += __shfl_xor(rs, 32, 64);
    l = l * corr + rs;
    m = mn;

    short4v t0w, t1w;
    t0w[0]=pb[0]; t0w[1]=pb[1]; t0w[2]=pb[2]; t0w[3]=pb[3];
    t1w[0]=pb[4]; t1w[1]=pb[5]; t1w[2]=pb[6]; t1w[3]=pb[7];
    *(short4v*)&Pw[r16][4 * g]      = t0w;
    *(short4v*)&Pw[r16][16 + 4 * g] = t1w;

    short4v v0, v1, v2, v3, v4, v5, v6, v7;
    TRRD(v0, va, "0");    TRRD(v1, va, "512");
    TRRD(v2, va, "128");  TRRD(v3, va, "640");
    TRRD(v4, va, "256");  TRRD(v5, va, "768");
    TRRD(v6, va, "384");  TRRD(v7, va, "896");

    bf16x8 pB = *(const bf16x8*)&Pw[r16][8 * g];
#pragma unroll
    for (int d = 0; d < 4; ++d) {
        o_acc[d][0] *= corr; o_acc[d][1] *= corr;
        o_acc[d][2] *= corr; o_acc[d][3] *= corr;
    }
    asm volatile("s_waitcnt lgkmcnt(0)" ::: "memory");
    __builtin_amdgcn_sched_barrier(0);

    bf16x8 av0, av1, av2, av3;
#pragma unroll
    for (int i = 0; i < 4; ++i) {
        av0[i] = v0[i]; av0[i + 4] = v1[i];
        av1[i] = v2[i]; av1[i + 4] = v3[i];
        av2[i] = v4[i]; av2[i + 4] = v5[i];
        av3[i] = v6[i]; av3[i + 4] = v7[i];
    }
    o_acc[0] = __builtin_amdgcn_mfma_f32_16x16x32_bf16(av0, pB, o_acc[0], 0, 0, 0);
    o_acc[1] = __builtin_amdgcn_mfma_f32_16x16x32_bf16(av1, pB, o_acc[1], 0, 0, 0);
    o_acc[2] = __builtin_amdgcn_mfma_f32_16x16x32_bf16(av2, pB, o_acc[2], 0, 0, 0);
    o_acc[3] = __builtin_amdgcn_mfma_f32_16x16x32_bf16(av3, pB, o_acc[3], 0, 0, 0);
}

__global__ __launch_bounds__(256) void attn_kernel(const short* __restrict__ qkv,
                                                   short* __restrict__ o) {
    __shared__ short Kl[2][32 * 64];       // 2 x 4 KB (double-buffered)
    __shared__ short Vl[2][32 * 64];       // 2 x 4 KB
    __shared__ short P_lds[4][16][40];     // 5 KB

    int tid  = threadIdx.x;
    int wave = tid >> 6;
    int lane = tid & 63;
    int g    = lane >> 4;
    int r16  = lane & 15;

    int qtA = blockIdx.x;
    int qtB = 15 - qtA;
    int bh = blockIdx.y;
    int b  = bh / H_, hh = bh - b * H_;
    size_t rbase = (size_t)b * T_;
    int qoff = hh * 64;

    int q0A = qtA * 64, q0B = qtB * 64;
    int qgA = q0A + wave * 16 + r16;
    int qgB = q0B + wave * 16 + r16;

    const short* qrA = qkv + (rbase + qgA) * 1152 + qoff;
    const short* qrB = qkv + (rbase + qgB) * 1152 + qoff;
    bf16x8 qfA0 = *(const bf16x8*)(qrA + 8 * g);
    bf16x8 qfA1 = *(const bf16x8*)(qrA + 32 + 8 * g);
    bf16x8 qfB0 = *(const bf16x8*)(qrB + 8 * g);
    bf16x8 qfB1 = *(const bf16x8*)(qrB + 32 + 8 * g);

    int kkey = tid >> 3;
    int koct = (tid & 7) ^ (kkey & 7);
    const short* gk = qkv + (rbase + kkey) * 1152 + qoff + 384 + koct * 8;
    int vkey = 4 * (tid >> 5) + ((tid >> 1) & 3);
    int voct = 2 * ((tid >> 3) & 3) + (tid & 1);
    const short* gv = qkv + (rbase + vkey) * 1152 + qoff + 768 + voct * 8;
    short* lk0 = Kl[0] + tid * 8;
    short* lk1 = Kl[1] + tid * 8;
    short* lv0 = Vl[0] + tid * 8;
    short* lv1 = Vl[1] + tid * 8;

    f32x4 oA[4], oB[4];
#pragma unroll
    for (int d = 0; d < 4; ++d) {
        oA[d][0]=0.f; oA[d][1]=0.f; oA[d][2]=0.f; oA[d][3]=0.f;
        oB[d][0]=0.f; oB[d][1]=0.f; oB[d][2]=0.f; oB[d][3]=0.f;
    }
    float mA = -3e38f, lA = 0.f, mB = -3e38f, lB = 0.f;

    const char* Kb0 = (const char*)Kl[0];
    const char* Kb1 = (const char*)Kl[1];
    unsigned ka = (unsigned)(r16 * 128 + ((g ^ (r16 & 7)) << 4));
    unsigned va0 = (unsigned)(size_t)(__attribute__((address_space(3))) short*)Vl[0]
                 + 1024u * (unsigned)g + 8u * (unsigned)r16;
    unsigned va1 = va0 + 4096u;            // Vl[1] is 4 KB after Vl[0]

    int ktA_hi = (q0A + wave * 16 + 15) >> 5;
    int ktB_hi = (q0B + wave * 16 + 15) >> 5;
    int nkt = 2 * (qtB + 1);

    // prologue: stage tile 0 into buffer 0
    GLDS16(gk, lk0);
    GLDS16(gv, lv0);
    gk += 32 * 1152; gv += 32 * 1152;
    asm volatile("s_waitcnt vmcnt(0)" ::: "memory");
    __builtin_amdgcn_s_barrier();
    asm volatile("" ::: "memory");

    for (int kt = 0; kt < nkt; ++kt) {
        int cur = kt & 1;
        // stage tile kt+1 into the other buffer (hidden under compute below)
        if (kt + 1 < nkt) {
            GLDS16(gk, cur ? lk0 : lk1);
            GLDS16(gv, cur ? lv0 : lv1);
            gk += 32 * 1152; gv += 32 * 1152;
        }
        const char* Kb = cur ? Kb1 : Kb0;
        unsigned va = cur ? va1 : va0;

        if (kt <= ktB_hi)
            attn_step(kt, qgB, g, r16, Kb, ka, va, P_lds[wave], qfB0, qfB1, oB, mB, lB);
        if (kt <= ktA_hi)
            attn_step(kt, qgA, g, r16, Kb, ka, va, P_lds[wave], qfA0, qfA1, oA, mA, lA);

        asm volatile("s_waitcnt vmcnt(0)" ::: "memory");   // stage(kt+1) landed
        __builtin_amdgcn_s_barrier();
        asm volatile("" ::: "memory");
    }

    {
        float inv = (lA > 0.f) ? 1.f / lA : 0.f;
        short* orow = o + (rbase + qgA) * C_ + qoff;
#pragma unroll
        for (int d = 0; d < 4; ++d) {
            short4v ov;
#pragma unroll
            for (int r = 0; r < 4; ++r) ov[r] = f2bf(oA[d][r] * inv);
            *(short4v*)(orow + 16 * d + 4 * g) = ov;
        }
    }
    if (qgB < T_) {
        float inv = (lB > 0.f) ? 1.f / lB : 0.f;
        short* orow = o + (rbase + qgB) * C_ + qoff;
#pragma unroll
        for (int d = 0; d < 4; ++d) {
            short4v ov;
#pragma unroll
            for (int r = 0; r < 4; ++r) ov[r] = f2bf(oB[d][r] * inv);
            *(short4v*)(orow + 16 * d + 4 * g) = ov;
        }
    }
}

// ---------------- per-row NLL: 4 rows per 256-thread block ----------------
__global__ __launch_bounds__(256) void nll_kernel(const float* __restrict__ logits,
                                                  const int* __restrict__ tgt,
                                                  float* __restrict__ nll) {
    int wave = threadIdx.x >> 6, lane = threadIdx.x & 63;
    int row  = blockIdx.x * 4 + wave;       // M_ = 4092*4 exactly
    const float* rp = logits + (size_t)row * V_;
    float v[4];
    float mx = -INFINITY;
#pragma unroll
    for (int i = 0; i < 4; ++i) {
        v[i] = rp[i * 64 + lane];
        mx = fmaxf(mx, v[i]);
    }
#pragma unroll
    for (int o = 32; o > 0; o >>= 1) mx = fmaxf(mx, __shfl_xor(mx, o, 64));
    float s = 0.f;
#pragma unroll
    for (int i = 0; i < 4; ++i) s += expf(v[i] - mx);
#pragma unroll
    for (int o = 32; o > 0; o >>= 1) s += __shfl_xor(s, o, 64);
    if (lane == 0) {
        float lse = mx + logf(s);
        nll[row] = lse - rp[tgt[row]];
    }
}

// ---------------- final deterministic mean reduce ----------------
__global__ __launch_bounds__(256) void loss_kernel(const float* __restrict__ nll,
                                                   float* __restrict__ loss) {
    __shared__ float sm[256];
    float s = 0.f;
    for (int i = threadIdx.x; i < M_; i += 256) s += nll[i];
    sm[threadIdx.x] = s;
    __syncthreads();
    for (int o = 128; o > 0; o >>= 1) {
        if (threadIdx.x < o) sm[threadIdx.x] += sm[threadIdx.x + o];
        __syncthreads();
    }
    if (threadIdx.x == 0) *loss = sm[0] * (1.0f / M_);
}

// ---------------- host launcher ----------------
extern "C" void kernel_launch(void* const* d_in, const int* in_sizes, int n_in,
                              void* d_out, int out_size, void* d_ws, size_t ws_size,
                              hipStream_t stream) {
    const int*   x       = (const int*)d_in[0];
    const int*   targets = (const int*)d_in[1];
    const float* tok_emb = (const float*)d_in[2];
    const float* pos_emb = (const float*)d_in[3];
    const float* Wq      = (const float*)d_in[4];
    const float* Wk      = (const float*)d_in[5];
    const float* Wv      = (const float*)d_in[6];
    const float* Wo      = (const float*)d_in[7];
    const float* bo      = (const float*)d_in[8];
    const float* ln1_g   = (const float*)d_in[9];
    const float* ln1_b   = (const float*)d_in[10];
    const float* ln2_g   = (const float*)d_in[11];
    const float* ln2_b   = (const float*)d_in[12];
    const float* W1      = (const float*)d_in[13];
    const float* b1      = (const float*)d_in[14];
    const float* W2      = (const float*)d_in[15];
    const float* b2      = (const float*)d_in[16];
    const float* lnf_g   = (const float*)d_in[17];
    const float* lnf_b   = (const float*)d_in[18];
    const float* Wf      = (const float*)d_in[19];
    const float* bf      = (const float*)d_in[20];

    float* logits = (float*)d_out;
    float* loss   = logits + (size_t)M_ * V_;

    float* h    = (float*)d_ws;                          // [MP_][C_] fp32
    short* z    = (short*)(h + (size_t)MP_ * C_);        // [MP_][C_] bf16
    short* big  = z + (size_t)MP_ * C_;                  // [MP_][FF_] bf16 (qkv)
    short* ob   = big + (size_t)MP_ * FF_;               // [MP_][C_] bf16
    short* qkvt = ob + (size_t)MP_ * C_;                 // [L][1152][384]
    short* wot  = qkvt + (size_t)L_ * 1152 * 384;        // [L][384][384]
    short* w1t  = wot + (size_t)L_ * 384 * 384;          // [L][1536][384]
    short* w2t  = w1t + (size_t)L_ * 1536 * 384;         // [L][384][1536]
    short* wft  = w2t + (size_t)L_ * 1536 * 384;         // [256][384]
    float* nll  = (float*)(wft + (size_t)256 * 384);     // [M_]

    wconv_kernel<<<10464, 256, 0, stream>>>(Wq, Wk, Wv, Wo, W1, W2, Wf,
                                            qkvt, wot, w1t, w2t, wft);
    embed_kernel<<<(M_ * C_ + 255) / 256, 256, 0, stream>>>(x, tok_emb, pos_emb, h);

    for (int l = 0; l < L_; ++l) {
        qkv_kernel<<<MP_ / 64, 512, 0, stream>>>(
            h, ln1_g + l * C_, ln1_b + l * C_,
            qkvt + (size_t)l * 1152 * 384, big);
        attn_kernel<<<dim3(8, B_ * H_), 256, 0, stream>>>(big, ob);
        wo_kernel<<<MP_ / 64, 512, 0, stream>>>(
            ob, wot + (size_t)l * 384 * 384, bo + l * C_, h,
            ln2_g + l * C_, ln2_b + l * C_, z);
        ffn_kernel<<<MP_ / 64, 512, 0, stream>>>(
            z, w1t + (size_t)l * 1536 * 384, w2t + (size_t)l * 384 * 1536,
            b1 + l * FF_, b2 + l * C_, h);
    }

    ln_kernel<<<M_ / 4, 256, 0, stream>>>(h, lnf_g, lnf_b, z);
    mm_kernel<2, false, true><<<dim3(128, 2), 256, 0, stream>>>(
        z, wft, bf, nullptr, logits, 256, 384);

    nll_kernel<<<M_ / 4, 256, 0, stream>>>(logits, targets, nll);
    loss_kernel<<<1, 256, 0, stream>>>(nll, loss);
}

// Round 24
// 1210.770 us; speedup vs baseline: 1.0899x; 1.0114x over previous
//
#include <hip/hip_runtime.h>
#include <hip/hip_bf16.h>
#include <math.h>

// Problem constants
#define B_  16
#define T_  1023
#define C_  384
#define H_  6
#define DH_ 64
#define L_  6
#define V_  256
#define FF_ 1536
#define M_  (B_*T_)      // 16368 rows
#define MP_ 16384        // padded rows (128-multiple)
#define EPS_ 1e-5f

typedef __attribute__((ext_vector_type(8))) short bf16x8;
typedef __attribute__((ext_vector_type(4))) short short4v;
typedef __attribute__((ext_vector_type(4))) float f32x4;

__device__ inline short f2bf(float x) {   // RNE float->bf16
    union { float f; unsigned u; } c; c.f = x;
    unsigned r = (c.u + 0x7fffu + ((c.u >> 16) & 1u)) >> 16;
    return (short)r;
}

#define GLDS16(g, l) __builtin_amdgcn_global_load_lds(                         \
    (const __attribute__((address_space(1))) void*)(g),                        \
    (__attribute__((address_space(3))) void*)(l), 16, 0, 0)

// hardware transpose read: 4 bf16 per lane (rule #18: waitcnt+sched_barrier after)
#define TRRD(dst, va, IMM) asm volatile("ds_read_b64_tr_b16 %0, %1 offset:" IMM \
    : "=v"(dst) : "v"(va))

// ---------------- embedding: h = tok_emb[x] + pos_emb (fp32) ----------------
__global__ void embed_kernel(const int* __restrict__ x, const float* __restrict__ tok,
                             const float* __restrict__ pos, float* __restrict__ h) {
    int i = blockIdx.x * 256 + threadIdx.x;
    if (i >= M_ * C_) return;
    int bt = i / C_;
    int c  = i - bt * C_;
    int t  = bt % T_;
    h[i] = tok[x[bt] * C_ + c] + pos[t * C_ + c];
}

// ---------------- weight transpose+convert: src fp32 [K][N] -> dst bf16 [N][K] ----
__global__ __launch_bounds__(256) void wconv_kernel(
    const float* __restrict__ Wq, const float* __restrict__ Wk,
    const float* __restrict__ Wv, const float* __restrict__ Wo,
    const float* __restrict__ W1, const float* __restrict__ W2,
    const float* __restrict__ Wf,
    short* __restrict__ qkvt, short* __restrict__ wot, short* __restrict__ w1t,
    short* __restrict__ w2t, short* __restrict__ wft) {
    __shared__ float tile[32][33];
    int t = blockIdx.x;
    const float* src; short* dst; int K, N, tl;
    if (t < 10368) {
        int l = t / 1728, r = t - l * 1728;
        if (r < 432) {                 // Wq/Wk/Wv -> fused qkv^T rows
            int which = r / 144; tl = r - which * 144;
            src = (which == 0 ? Wq : which == 1 ? Wk : Wv) + (size_t)l * 384 * 384;
            dst = qkvt + (size_t)l * 1152 * 384 + (size_t)which * 384 * 384;
            K = 384; N = 384;
        } else if (r < 576) {
            tl = r - 432;
            src = Wo + (size_t)l * 384 * 384; dst = wot + (size_t)l * 384 * 384;
            K = 384; N = 384;
        } else if (r < 1152) {
            tl = r - 576;
            src = W1 + (size_t)l * 384 * 1536; dst = w1t + (size_t)l * 1536 * 384;
            K = 384; N = 1536;
        } else {
            tl = r - 1152;
            src = W2 + (size_t)l * 1536 * 384; dst = w2t + (size_t)l * 384 * 1536;
            K = 1536; N = 384;
        }
    } else {
        tl = t - 10368; src = Wf; dst = wft; K = 384; N = 256;
    }
    int ntx = N >> 5;
    int k0 = (tl / ntx) << 5, n0 = (tl % ntx) << 5;
    int rr = threadIdx.x >> 5, cc = threadIdx.x & 31;
#pragma unroll
    for (int p = 0; p < 4; ++p)
        tile[rr + 8 * p][cc] = src[(size_t)(k0 + rr + 8 * p) * N + n0 + cc];
    __syncthreads();
#pragma unroll
    for (int p = 0; p < 4; ++p)
        dst[(size_t)(n0 + rr + 8 * p) * K + k0 + cc] = f2bf(tile[cc][rr + 8 * p]);
}

// ---------------- QKV GEMM + fused LN1: big = (LN(h)) @ qkvt^T ----------------
// Block = 64 rows, 512 threads, grid 256. LN1 computed in-kernel; W prefetch
// issued first so its latency hides under LN. No barriers in main loop.
__global__ __launch_bounds__(512) void qkv_kernel(const float* __restrict__ h,
                                                  const float* __restrict__ lng,
                                                  const float* __restrict__ lnb,
                                                  const short* __restrict__ wt,
                                                  short* __restrict__ outb) {
    __shared__ short Zl[48 * 64 * 8];   // 48 KB
    int tid  = threadIdx.x;
    int wave = tid >> 6, lane = tid & 63;
    int g = lane >> 4, r16 = lane & 15;
    int r0 = blockIdx.x * 64;

    const short* wbase = wt + (size_t)(16 * wave + r16) * C_ + 8 * g;
    bf16x8 wf[12];
#pragma unroll
    for (int ks = 0; ks < 12; ++ks) wf[ks] = *(const bf16x8*)(wbase + ks * 32);

    float gv6[6], bv6[6];
#pragma unroll
    for (int i = 0; i < 6; ++i) { gv6[i] = lng[i * 64 + lane]; bv6[i] = lnb[i * 64 + lane]; }

    for (int rr = 0; rr < 8; ++rr) {
        int lrow = 8 * wave + rr;
        const float* rp = h + (size_t)(r0 + lrow) * C_;
        float v[6];
        float s = 0.f, s2 = 0.f;
#pragma unroll
        for (int i = 0; i < 6; ++i) {
            v[i] = rp[i * 64 + lane];
            s += v[i]; s2 += v[i] * v[i];
        }
#pragma unroll
        for (int o = 32; o > 0; o >>= 1) {
            s  += __shfl_xor(s,  o, 64);
            s2 += __shfl_xor(s2, o, 64);
        }
        float mu = s * (1.0f / C_);
        float rs = rsqrtf(s2 * (1.0f / C_) - mu * mu + EPS_);
#pragma unroll
        for (int i = 0; i < 6; ++i) {
            int col = i * 64 + lane;
            Zl[(col >> 3) * 512 + lrow * 8 + (col & 7)] =
                f2bf((v[i] - mu) * rs * gv6[i] + bv6[i]);
        }
    }
    __syncthreads();

    for (int c = 0; c < 9; ++c) {
        f32x4 acc[4];
#pragma unroll
        for (int mj = 0; mj < 4; ++mj) { acc[mj][0]=0.f; acc[mj][1]=0.f; acc[mj][2]=0.f; acc[mj][3]=0.f; }
#pragma unroll
        for (int ks = 0; ks < 12; ++ks) {
#pragma unroll
            for (int mj = 0; mj < 4; ++mj) {
                bf16x8 bz = *(const bf16x8*)(Zl + ((4 * ks + g) * 64 + 16 * mj + r16) * 8);
                acc[mj] = __builtin_amdgcn_mfma_f32_16x16x32_bf16(wf[ks], bz, acc[mj], 0, 0, 0);
            }
        }
        if (c + 1 < 9) {
#pragma unroll
            for (int ks = 0; ks < 12; ++ks)
                wf[ks] = *(const bf16x8*)(wbase + (size_t)(c + 1) * 128 * C_ + ks * 32);
        }
#pragma unroll
        for (int mj = 0; mj < 4; ++mj) {
            short4v ov;
#pragma unroll
            for (int rg = 0; rg < 4; ++rg) ov[rg] = f2bf(acc[mj][rg]);
            *(short4v*)(outb + (size_t)(r0 + 16 * mj + r16) * 1152
                        + 128 * c + 16 * wave + 4 * g) = ov;
        }
    }
}

// ---------------- Wo GEMM + residual + fused LN2 -> z (ffn-FF2 style) ---------
__global__ __launch_bounds__(512) void wo_kernel(const short* __restrict__ ob,
                                                 const short* __restrict__ wt,
                                                 const float* __restrict__ bo,
                                                 float* __restrict__ h,
                                                 const float* __restrict__ lng,
                                                 const float* __restrict__ lnb,
                                                 short* __restrict__ zout) {
    __shared__ short Ol[48 * 64 * 8];   // 48 KB (reused as LN scratch at end)
    int tid  = threadIdx.x;
    int wave = tid >> 6, lane = tid & 63;
    int g = lane >> 4, r16 = lane & 15;
    int r0 = blockIdx.x * 64;

    {
        const short* go = ob + (size_t)(r0 + lane) * C_ + wave * 8;
        short* lo = Ol + (wave * 64 + lane) * 8;
#pragma unroll
        for (int ro = 0; ro < 6; ++ro) { GLDS16(go, lo); go += 64; lo += 4096; }
    }

    const short* wbase = wt + (size_t)(48 * wave + r16) * C_ + 8 * g;
    bf16x8 wf[12];
#pragma unroll
    for (int ks2 = 0; ks2 < 4; ++ks2)
#pragma unroll
        for (int j = 0; j < 3; ++j)
            wf[ks2 * 3 + j] = *(const bf16x8*)(wbase + (size_t)(16 * j) * C_ + 32 * ks2);

    asm volatile("s_waitcnt vmcnt(0)" ::: "memory");
    __builtin_amdgcn_s_barrier();
    asm volatile("" ::: "memory");

    f32x4 acc[4][3];
#pragma unroll
    for (int mi = 0; mi < 4; ++mi)
#pragma unroll
        for (int j = 0; j < 3; ++j) { acc[mi][j][0]=0.f; acc[mi][j][1]=0.f; acc[mi][j][2]=0.f; acc[mi][j][3]=0.f; }

    for (int kc = 0; kc < 3; ++kc) {
#pragma unroll
        for (int ks2 = 0; ks2 < 4; ++ks2) {
            bf16x8 pa[4];
#pragma unroll
            for (int mi = 0; mi < 4; ++mi)
                pa[mi] = *(const bf16x8*)(Ol + ((16 * kc + 4 * ks2 + g) * 64 + 16 * mi + r16) * 8);
#pragma unroll
            for (int j = 0; j < 3; ++j)
#pragma unroll
                for (int mi = 0; mi < 4; ++mi)
                    acc[mi][j] = __builtin_amdgcn_mfma_f32_16x16x32_bf16(pa[mi], wf[ks2 * 3 + j], acc[mi][j], 0, 0, 0);
        }
        if (kc + 1 < 3) {
#pragma unroll
            for (int ks2 = 0; ks2 < 4; ++ks2)
#pragma unroll
                for (int j = 0; j < 3; ++j)
                    wf[ks2 * 3 + j] = *(const bf16x8*)(wbase + (size_t)(16 * j) * C_
                                                       + 128 * (kc + 1) + 32 * ks2);
        }
    }
    __syncthreads();               // Ol reads done; reuse as LN scratch

    float rsum[4][4], rsq[4][4];
#pragma unroll
    for (int mi = 0; mi < 4; ++mi)
#pragma unroll
        for (int rg = 0; rg < 4; ++rg) { rsum[mi][rg] = 0.f; rsq[mi][rg] = 0.f; }

#pragma unroll
    for (int j = 0; j < 3; ++j) {
        int col = 48 * wave + 16 * j + r16;
        float bj = bo[col];
#pragma unroll
        for (int mi = 0; mi < 4; ++mi) {
#pragma unroll
            for (int rg = 0; rg < 4; ++rg) {
                int row = r0 + 16 * mi + 4 * g + rg;
                float hv = h[(size_t)row * C_ + col] + acc[mi][j][rg] + bj;
                h[(size_t)row * C_ + col] = hv;
                acc[mi][j][rg] = hv;
                rsum[mi][rg] += hv;
                rsq[mi][rg]  += hv * hv;
            }
        }
    }
#pragma unroll
    for (int o = 1; o < 16; o <<= 1) {
#pragma unroll
        for (int mi = 0; mi < 4; ++mi)
#pragma unroll
            for (int rg = 0; rg < 4; ++rg) {
                rsum[mi][rg] += __shfl_xor(rsum[mi][rg], o, 64);
                rsq[mi][rg]  += __shfl_xor(rsq[mi][rg],  o, 64);
            }
    }
    float* St = (float*)Ol;             // [64 rows][16] floats = 4 KB
    if (r16 == 0) {
#pragma unroll
        for (int mi = 0; mi < 4; ++mi)
#pragma unroll
            for (int rg = 0; rg < 4; ++rg) {
                int rr = 16 * mi + 4 * g + rg;
                St[rr * 16 + 2 * wave]     = rsum[mi][rg];
                St[rr * 16 + 2 * wave + 1] = rsq[mi][rg];
            }
    }
    __syncthreads();
    if (tid < 64) {
        float s = 0.f, s2 = 0.f;
#pragma unroll
        for (int w = 0; w < 8; ++w) { s += St[tid * 16 + 2 * w]; s2 += St[tid * 16 + 2 * w + 1]; }
        float mu  = s * (1.0f / C_);
        float var = s2 * (1.0f / C_) - mu * mu;
        St[tid * 16]     = mu;
        St[tid * 16 + 1] = rsqrtf(var + EPS_);
    }
    __syncthreads();
#pragma unroll
    for (int j = 0; j < 3; ++j) {
        int col = 48 * wave + 16 * j + r16;
        float gam = lng[col], bet = lnb[col];
#pragma unroll
        for (int mi = 0; mi < 4; ++mi) {
#pragma unroll
            for (int rg = 0; rg < 4; ++rg) {
                int rr = 16 * mi + 4 * g + rg;
                float mu = St[rr * 16], rs = St[rr * 16 + 1];
                zout[(size_t)(r0 + rr) * C_ + col] = f2bf((acc[mi][j][rg] - mu) * rs * gam + bet);
            }
        }
    }
}

// ---------------- fused FFN v2 (round-11/19 best): h += relu(z@W1+b1)@W2 + b2 ----
__global__ __launch_bounds__(512) void ffn_kernel(const short* __restrict__ z,
                                                  const short* __restrict__ w1t,
                                                  const short* __restrict__ w2t,
                                                  const float* __restrict__ b1,
                                                  const float* __restrict__ b2,
                                                  float* __restrict__ h) {
    __shared__ short Zl[48 * 64 * 8];   // 48 KB: [koct][row][8]
    __shared__ short Pl[16 * 64 * 8];   // 16 KB: [ffoct][row][8]
    int tid  = threadIdx.x;
    int wave = tid >> 6, lane = tid & 63;
    int g = lane >> 4, r16 = lane & 15;
    int r0 = blockIdx.x * 64;

    {
        const short* gz = z + (size_t)(r0 + lane) * C_ + wave * 8;
        short* lz = Zl + (wave * 64 + lane) * 8;
#pragma unroll
        for (int ro = 0; ro < 6; ++ro) {
            GLDS16(gz, lz);
            gz += 64;
            lz += 8 * 64 * 8;
        }
    }

    const short* w1base = w1t + (size_t)(16 * wave + r16) * C_ + 8 * g;
    const short* w2base = w2t + (size_t)(48 * wave + r16) * FF_ + 8 * g;

    bf16x8 w1f[12];
#pragma unroll
    for (int ks = 0; ks < 12; ++ks)
        w1f[ks] = *(const bf16x8*)(w1base + ks * 32);

    asm volatile("s_waitcnt vmcnt(0)" ::: "memory");
    __builtin_amdgcn_s_barrier();
    asm volatile("" ::: "memory");

    f32x4 acc2[4][3];
#pragma unroll
    for (int mi = 0; mi < 4; ++mi)
#pragma unroll
        for (int j = 0; j < 3; ++j) { acc2[mi][j][0]=0.f; acc2[mi][j][1]=0.f; acc2[mi][j][2]=0.f; acc2[mi][j][3]=0.f; }

    for (int c = 0; c < 12; ++c) {
        bf16x8 w2f[12];
#pragma unroll
        for (int ks2 = 0; ks2 < 4; ++ks2)
#pragma unroll
            for (int j = 0; j < 3; ++j)
                w2f[ks2 * 3 + j] = *(const bf16x8*)(w2base + (size_t)(16 * j) * FF_
                                                    + 128 * c + 32 * ks2);

        f32x4 acc1[4];
#pragma unroll
        for (int mj = 0; mj < 4; ++mj) { acc1[mj][0]=0.f; acc1[mj][1]=0.f; acc1[mj][2]=0.f; acc1[mj][3]=0.f; }
#pragma unroll
        for (int ks = 0; ks < 12; ++ks) {
#pragma unroll
            for (int mj = 0; mj < 4; ++mj) {
                bf16x8 bz = *(const bf16x8*)(Zl + ((4 * ks + g) * 64 + 16 * mj + r16) * 8);
                acc1[mj] = __builtin_amdgcn_mfma_f32_16x16x32_bf16(w1f[ks], bz, acc1[mj], 0, 0, 0);
            }
        }
        f32x4 b1v = *(const f32x4*)(b1 + 128 * c + 16 * wave + 4 * g);
        int oct = 2 * wave + (g >> 1);
#pragma unroll
        for (int mj = 0; mj < 4; ++mj) {
            short4v pv;
#pragma unroll
            for (int rg = 0; rg < 4; ++rg)
                pv[rg] = f2bf(fmaxf(acc1[mj][rg] + b1v[rg], 0.f));
            *(short4v*)(Pl + (oct * 64 + 16 * mj + r16) * 8 + (g & 1) * 4) = pv;
        }
        __syncthreads();

        if (c + 1 < 12) {
#pragma unroll
            for (int ks = 0; ks < 12; ++ks)
                w1f[ks] = *(const bf16x8*)(w1base + (size_t)(c + 1) * 128 * C_ + ks * 32);
        }

#pragma unroll
        for (int ks2 = 0; ks2 < 4; ++ks2) {
            bf16x8 pa[4];
#pragma unroll
            for (int mi = 0; mi < 4; ++mi)
                pa[mi] = *(const bf16x8*)(Pl + ((4 * ks2 + g) * 64 + 16 * mi + r16) * 8);
#pragma unroll
            for (int j = 0; j < 3; ++j) {
#pragma unroll
                for (int mi = 0; mi < 4; ++mi)
                    acc2[mi][j] = __builtin_amdgcn_mfma_f32_16x16x32_bf16(pa[mi], w2f[ks2 * 3 + j], acc2[mi][j], 0, 0, 0);
            }
        }
        __syncthreads();
    }

#pragma unroll
    for (int j = 0; j < 3; ++j) {
        int col = 48 * wave + 16 * j + r16;
        float bj = b2[col];
#pragma unroll
        for (int mi = 0; mi < 4; ++mi) {
#pragma unroll
            for (int rg = 0; rg < 4; ++rg) {
                int row = r0 + 16 * mi + 4 * g + rg;
                h[(size_t)row * C_ + col] += acc2[mi][j][rg] + bj;
            }
        }
    }
}

// ---------------- final: lnf + projection + NLL fused ----------------
// Block = 64 rows, 512 threads, grid 256. LN prologue (lnf) -> Zl; 2 chunks
// of 128 cols (N=256); guarded fp32 stores to logits + staging into padded
// LDS Lg; in-kernel NLL reduction (wave = 8 rows, lane = 4 cols).
__global__ __launch_bounds__(512) void final_kernel(const float* __restrict__ h,
                                                    const float* __restrict__ lng,
                                                    const float* __restrict__ lnb,
                                                    const short* __restrict__ wt,
                                                    const float* __restrict__ bf,
                                                    const int* __restrict__ tgt,
                                                    float* __restrict__ logits,
                                                    float* __restrict__ nll) {
    __shared__ short Zl[48 * 64 * 8];   // 48 KB
    __shared__ float Lg[64][260];       // 65 KB (pad 260: 2-way bank aliasing)
    int tid  = threadIdx.x;
    int wave = tid >> 6, lane = tid & 63;
    int g = lane >> 4, r16 = lane & 15;
    int r0 = blockIdx.x * 64;

    const short* wbase = wt + (size_t)(16 * wave + r16) * C_ + 8 * g;
    bf16x8 wf[12];
#pragma unroll
    for (int ks = 0; ks < 12; ++ks) wf[ks] = *(const bf16x8*)(wbase + ks * 32);

    float gv6[6], bv6[6];
#pragma unroll
    for (int i = 0; i < 6; ++i) { gv6[i] = lng[i * 64 + lane]; bv6[i] = lnb[i * 64 + lane]; }

    for (int rr = 0; rr < 8; ++rr) {
        int lrow = 8 * wave + rr;
        const float* rp = h + (size_t)(r0 + lrow) * C_;
        float v[6];
        float s = 0.f, s2 = 0.f;
#pragma unroll
        for (int i = 0; i < 6; ++i) {
            v[i] = rp[i * 64 + lane];
            s += v[i]; s2 += v[i] * v[i];
        }
#pragma unroll
        for (int o = 32; o > 0; o >>= 1) {
            s  += __shfl_xor(s,  o, 64);
            s2 += __shfl_xor(s2, o, 64);
        }
        float mu = s * (1.0f / C_);
        float rs = rsqrtf(s2 * (1.0f / C_) - mu * mu + EPS_);
#pragma unroll
        for (int i = 0; i < 6; ++i) {
            int col = i * 64 + lane;
            Zl[(col >> 3) * 512 + lrow * 8 + (col & 7)] =
                f2bf((v[i] - mu) * rs * gv6[i] + bv6[i]);
        }
    }
    __syncthreads();

    for (int c = 0; c < 2; ++c) {
        f32x4 acc[4];
#pragma unroll
        for (int mj = 0; mj < 4; ++mj) { acc[mj][0]=0.f; acc[mj][1]=0.f; acc[mj][2]=0.f; acc[mj][3]=0.f; }
#pragma unroll
        for (int ks = 0; ks < 12; ++ks) {
#pragma unroll
            for (int mj = 0; mj < 4; ++mj) {
                bf16x8 bz = *(const bf16x8*)(Zl + ((4 * ks + g) * 64 + 16 * mj + r16) * 8);
                acc[mj] = __builtin_amdgcn_mfma_f32_16x16x32_bf16(wf[ks], bz, acc[mj], 0, 0, 0);
            }
        }
        if (c + 1 < 2) {
#pragma unroll
            for (int ks = 0; ks < 12; ++ks)
                wf[ks] = *(const bf16x8*)(wbase + (size_t)128 * C_ + ks * 32);
        }
        int colb = 128 * c + 16 * wave + 4 * g;
        f32x4 bv4 = *(const f32x4*)(bf + colb);
#pragma unroll
        for (int mj = 0; mj < 4; ++mj) {
            int lrow = 16 * mj + r16;
            int row  = r0 + lrow;
            f32x4 ov;
#pragma unroll
            for (int rg = 0; rg < 4; ++rg) {
                ov[rg] = acc[mj][rg] + bv4[rg];
                Lg[lrow][colb + rg] = ov[rg];
            }
            if (row < M_) *(f32x4*)(logits + (size_t)row * V_ + colb) = ov;
        }
    }
    __syncthreads();

    // ---- NLL: wave handles rows 8*wave..+7 ----
    for (int rr = 0; rr < 8; ++rr) {
        int lrow = 8 * wave + rr;
        int row  = r0 + lrow;
        float v[4];
        float mx = -INFINITY;
#pragma unroll
        for (int i = 0; i < 4; ++i) {
            v[i] = Lg[lrow][i * 64 + lane];
            mx = fmaxf(mx, v[i]);
        }
#pragma unroll
        for (int o = 32; o > 0; o >>= 1) mx = fmaxf(mx, __shfl_xor(mx, o, 64));
        float s = 0.f;
#pragma unroll
        for (int i = 0; i < 4; ++i) s += expf(v[i] - mx);
#pragma unroll
        for (int o = 32; o > 0; o >>= 1) s += __shfl_xor(s, o, 64);
        if (lane == 0 && row < M_) {
            float lse = mx + logf(s);
            nll[row] = lse - Lg[lrow][tgt[row]];
        }
    }
}

// ---------------- MFMA flash attention v4: paired q-tiles + K/V double-buffer ----
__device__ __forceinline__ void attn_step(int kt, int qg, int g, int r16,
                                          const char* Kb, unsigned ka, unsigned va,
                                          short (*Pw)[40],
                                          bf16x8 qf0, bf16x8 qf1,
                                          f32x4* o_acc, float& m, float& l) {
    f32x4 s0, s1;
    s0[0]=0.f;s0[1]=0.f;s0[2]=0.f;s0[3]=0.f;
    s1[0]=0.f;s1[1]=0.f;s1[2]=0.f;s1[3]=0.f;
    bf16x8 a00 = *(const bf16x8*)(Kb + ka);
    bf16x8 a01 = *(const bf16x8*)(Kb + (ka ^ 64u));
    bf16x8 a10 = *(const bf16x8*)(Kb + ka + 2048u);
    bf16x8 a11 = *(const bf16x8*)(Kb + ((ka + 2048u) ^ 64u));
    s0 = __builtin_amdgcn_mfma_f32_16x16x32_bf16(a00, qf0, s0, 0, 0, 0);
    s0 = __builtin_amdgcn_mfma_f32_16x16x32_bf16(a01, qf1, s0, 0, 0, 0);
    s1 = __builtin_amdgcn_mfma_f32_16x16x32_bf16(a10, qf0, s1, 0, 0, 0);
    s1 = __builtin_amdgcn_mfma_f32_16x16x32_bf16(a11, qf1, s1, 0, 0, 0);

    int kb0 = kt * 32 + 4 * g;
    float sv[8];
#pragma unroll
    for (int r = 0; r < 4; ++r) {
        sv[r]     = (kb0 + r      <= qg) ? s0[r] * 0.125f : -3e38f;
        sv[4 + r] = (kb0 + 16 + r <= qg) ? s1[r] * 0.125f : -3e38f;
    }
    float pmax = sv[0];
#pragma unroll
    for (int i = 1; i < 8; ++i) pmax = fmaxf(pmax, sv[i]);
    pmax = fmaxf(pmax, __shfl_xor(pmax, 16, 64));
    pmax = fmaxf(pmax, __shfl_xor(pmax, 32, 64));
    float mn   = fmaxf(m, pmax);
    float corr = __expf(m - mn);
    float rs = 0.f;
    short pb[8];
#pragma unroll
    for (int i = 0; i < 8; ++i) {
        float p = __expf(sv[i] - mn);
        rs += p;
        pb[i] = f2bf(p);
    }
    rs += __shfl_xor(rs, 16, 64);
    rs += __shfl_xor(rs, 32, 64);
    l = l * corr + rs;
    m = mn;

    short4v t0w, t1w;
    t0w[0]=pb[0]; t0w[1]=pb[1]; t0w[2]=pb[2]; t0w[3]=pb[3];
    t1w[0]=pb[4]; t1w[1]=pb[5]; t1w[2]=pb[6]; t1w[3]=pb[7];
    *(short4v*)&Pw[r16][4 * g]      = t0w;
    *(short4v*)&Pw[r16][16 + 4 * g] = t1w;

    short4v v0, v1, v2, v3, v4, v5, v6, v7;
    TRRD(v0, va, "0");    TRRD(v1, va, "512");
    TRRD(v2, va, "128");  TRRD(v3, va, "640");
    TRRD(v4, va, "256");  TRRD(v5, va, "768");
    TRRD(v6, va, "384");  TRRD(v7, va, "896");

    bf16x8 pB = *(const bf16x8*)&Pw[r16][8 * g];
#pragma unroll
    for (int d = 0; d < 4; ++d) {
        o_acc[d][0] *= corr; o_acc[d][1] *= corr;
        o_acc[d][2] *= corr; o_acc[d][3] *= corr;
    }
    asm volatile("s_waitcnt lgkmcnt(0)" ::: "memory");
    __builtin_amdgcn_sched_barrier(0);

    bf16x8 av0, av1, av2, av3;
#pragma unroll
    for (int i = 0; i < 4; ++i) {
        av0[i] = v0[i]; av0[i + 4] = v1[i];
        av1[i] = v2[i]; av1[i + 4] = v3[i];
        av2[i] = v4[i]; av2[i + 4] = v5[i];
        av3[i] = v6[i]; av3[i + 4] = v7[i];
    }
    o_acc[0] = __builtin_amdgcn_mfma_f32_16x16x32_bf16(av0, pB, o_acc[0], 0, 0, 0);
    o_acc[1] = __builtin_amdgcn_mfma_f32_16x16x32_bf16(av1, pB, o_acc[1], 0, 0, 0);
    o_acc[2] = __builtin_amdgcn_mfma_f32_16x16x32_bf16(av2, pB, o_acc[2], 0, 0, 0);
    o_acc[3] = __builtin_amdgcn_mfma_f32_16x16x32_bf16(av3, pB, o_acc[3], 0, 0, 0);
}

__global__ __launch_bounds__(256) void attn_kernel(const short* __restrict__ qkv,
                                                   short* __restrict__ o) {
    __shared__ short Kl[2][32 * 64];       // 2 x 4 KB (double-buffered)
    __shared__ short Vl[2][32 * 64];       // 2 x 4 KB
    __shared__ short P_lds[4][16][40];     // 5 KB

    int tid  = threadIdx.x;
    int wave = tid >> 6;
    int lane = tid & 63;
    int g    = lane >> 4;
    int r16  = lane & 15;

    int qtA = blockIdx.x;
    int qtB = 15 - qtA;
    int bh = blockIdx.y;
    int b  = bh / H_, hh = bh - b * H_;
    size_t rbase = (size_t)b * T_;
    int qoff = hh * 64;

    int q0A = qtA * 64, q0B = qtB * 64;
    int qgA = q0A + wave * 16 + r16;
    int qgB = q0B + wave * 16 + r16;

    const short* qrA = qkv + (rbase + qgA) * 1152 + qoff;
    const short* qrB = qkv + (rbase + qgB) * 1152 + qoff;
    bf16x8 qfA0 = *(const bf16x8*)(qrA + 8 * g);
    bf16x8 qfA1 = *(const bf16x8*)(qrA + 32 + 8 * g);
    bf16x8 qfB0 = *(const bf16x8*)(qrB + 8 * g);
    bf16x8 qfB1 = *(const bf16x8*)(qrB + 32 + 8 * g);

    int kkey = tid >> 3;
    int koct = (tid & 7) ^ (kkey & 7);
    const short* gk = qkv + (rbase + kkey) * 1152 + qoff + 384 + koct * 8;
    int vkey = 4 * (tid >> 5) + ((tid >> 1) & 3);
    int voct = 2 * ((tid >> 3) & 3) + (tid & 1);
    const short* gv = qkv + (rbase + vkey) * 1152 + qoff + 768 + voct * 8;
    short* lk0 = Kl[0] + tid * 8;
    short* lk1 = Kl[1] + tid * 8;
    short* lv0 = Vl[0] + tid * 8;
    short* lv1 = Vl[1] + tid * 8;

    f32x4 oA[4], oB[4];
#pragma unroll
    for (int d = 0; d < 4; ++d) {
        oA[d][0]=0.f; oA[d][1]=0.f; oA[d][2]=0.f; oA[d][3]=0.f;
        oB[d][0]=0.f; oB[d][1]=0.f; oB[d][2]=0.f; oB[d][3]=0.f;
    }
    float mA = -3e38f, lA = 0.f, mB = -3e38f, lB = 0.f;

    const char* Kb0 = (const char*)Kl[0];
    const char* Kb1 = (const char*)Kl[1];
    unsigned ka = (unsigned)(r16 * 128 + ((g ^ (r16 & 7)) << 4));
    unsigned va0 = (unsigned)(size_t)(__attribute__((address_space(3))) short*)Vl[0]
                 + 1024u * (unsigned)g + 8u * (unsigned)r16;
    unsigned va1 = va0 + 4096u;            // Vl[1] is 4 KB after Vl[0]

    int ktA_hi = (q0A + wave * 16 + 15) >> 5;
    int ktB_hi = (q0B + wave * 16 + 15) >> 5;
    int nkt = 2 * (qtB + 1);

    // prologue: stage tile 0 into buffer 0
    GLDS16(gk, lk0);
    GLDS16(gv, lv0);
    gk += 32 * 1152; gv += 32 * 1152;
    asm volatile("s_waitcnt vmcnt(0)" ::: "memory");
    __builtin_amdgcn_s_barrier();
    asm volatile("" ::: "memory");

    for (int kt = 0; kt < nkt; ++kt) {
        int cur = kt & 1;
        // stage tile kt+1 into the other buffer (hidden under compute below)
        if (kt + 1 < nkt) {
            GLDS16(gk, cur ? lk0 : lk1);
            GLDS16(gv, cur ? lv0 : lv1);
            gk += 32 * 1152; gv += 32 * 1152;
        }
        const char* Kb = cur ? Kb1 : Kb0;
        unsigned va = cur ? va1 : va0;

        if (kt <= ktB_hi)
            attn_step(kt, qgB, g, r16, Kb, ka, va, P_lds[wave], qfB0, qfB1, oB, mB, lB);
        if (kt <= ktA_hi)
            attn_step(kt, qgA, g, r16, Kb, ka, va, P_lds[wave], qfA0, qfA1, oA, mA, lA);

        asm volatile("s_waitcnt vmcnt(0)" ::: "memory");   // stage(kt+1) landed
        __builtin_amdgcn_s_barrier();
        asm volatile("" ::: "memory");
    }

    {
        float inv = (lA > 0.f) ? 1.f / lA : 0.f;
        short* orow = o + (rbase + qgA) * C_ + qoff;
#pragma unroll
        for (int d = 0; d < 4; ++d) {
            short4v ov;
#pragma unroll
            for (int r = 0; r < 4; ++r) ov[r] = f2bf(oA[d][r] * inv);
            *(short4v*)(orow + 16 * d + 4 * g) = ov;
        }
    }
    if (qgB < T_) {
        float inv = (lB > 0.f) ? 1.f / lB : 0.f;
        short* orow = o + (rbase + qgB) * C_ + qoff;
#pragma unroll
        for (int d = 0; d < 4; ++d) {
            short4v ov;
#pragma unroll
            for (int r = 0; r < 4; ++r) ov[r] = f2bf(oB[d][r] * inv);
            *(short4v*)(orow + 16 * d + 4 * g) = ov;
        }
    }
}

// ---------------- final deterministic mean reduce ----------------
__global__ __launch_bounds__(256) void loss_kernel(const float* __restrict__ nll,
                                                   float* __restrict__ loss) {
    __shared__ float sm[256];
    float s = 0.f;
    for (int i = threadIdx.x; i < M_; i += 256) s += nll[i];
    sm[threadIdx.x] = s;
    __syncthreads();
    for (int o = 128; o > 0; o >>= 1) {
        if (threadIdx.x < o) sm[threadIdx.x] += sm[threadIdx.x + o];
        __syncthreads();
    }
    if (threadIdx.x == 0) *loss = sm[0] * (1.0f / M_);
}

// ---------------- host launcher ----------------
extern "C" void kernel_launch(void* const* d_in, const int* in_sizes, int n_in,
                              void* d_out, int out_size, void* d_ws, size_t ws_size,
                              hipStream_t stream) {
    const int*   x       = (const int*)d_in[0];
    const int*   targets = (const int*)d_in[1];
    const float* tok_emb = (const float*)d_in[2];
    const float* pos_emb = (const float*)d_in[3];
    const float* Wq      = (const float*)d_in[4];
    const float* Wk      = (const float*)d_in[5];
    const float* Wv      = (const float*)d_in[6];
    const float* Wo      = (const float*)d_in[7];
    const float* bo      = (const float*)d_in[8];
    const float* ln1_g   = (const float*)d_in[9];
    const float* ln1_b   = (const float*)d_in[10];
    const float* ln2_g   = (const float*)d_in[11];
    const float* ln2_b   = (const float*)d_in[12];
    const float* W1      = (const float*)d_in[13];
    const float* b1      = (const float*)d_in[14];
    const float* W2      = (const float*)d_in[15];
    const float* b2      = (const float*)d_in[16];
    const float* lnf_g   = (const float*)d_in[17];
    const float* lnf_b   = (const float*)d_in[18];
    const float* Wf      = (const float*)d_in[19];
    const float* bf      = (const float*)d_in[20];

    float* logits = (float*)d_out;
    float* loss   = logits + (size_t)M_ * V_;

    float* h    = (float*)d_ws;                          // [MP_][C_] fp32
    short* z    = (short*)(h + (size_t)MP_ * C_);        // [MP_][C_] bf16
    short* big  = z + (size_t)MP_ * C_;                  // [MP_][FF_] bf16 (qkv)
    short* ob   = big + (size_t)MP_ * FF_;               // [MP_][C_] bf16
    short* qkvt = ob + (size_t)MP_ * C_;                 // [L][1152][384]
    short* wot  = qkvt + (size_t)L_ * 1152 * 384;        // [L][384][384]
    short* w1t  = wot + (size_t)L_ * 384 * 384;          // [L][1536][384]
    short* w2t  = w1t + (size_t)L_ * 1536 * 384;         // [L][384][1536]
    short* wft  = w2t + (size_t)L_ * 1536 * 384;         // [256][384]
    float* nll  = (float*)(wft + (size_t)256 * 384);     // [M_]

    wconv_kernel<<<10464, 256, 0, stream>>>(Wq, Wk, Wv, Wo, W1, W2, Wf,
                                            qkvt, wot, w1t, w2t, wft);
    embed_kernel<<<(M_ * C_ + 255) / 256, 256, 0, stream>>>(x, tok_emb, pos_emb, h);

    for (int l = 0; l < L_; ++l) {
        qkv_kernel<<<MP_ / 64, 512, 0, stream>>>(
            h, ln1_g + l * C_, ln1_b + l * C_,
            qkvt + (size_t)l * 1152 * 384, big);
        attn_kernel<<<dim3(8, B_ * H_), 256, 0, stream>>>(big, ob);
        wo_kernel<<<MP_ / 64, 512, 0, stream>>>(
            ob, wot + (size_t)l * 384 * 384, bo + l * C_, h,
            ln2_g + l * C_, ln2_b + l * C_, z);
        ffn_kernel<<<MP_ / 64, 512, 0, stream>>>(
            z, w1t + (size_t)l * 1536 * 384, w2t + (size_t)l * 384 * 1536,
            b1 + l * FF_, b2 + l * C_, h);
    }

    final_kernel<<<MP_ / 64, 512, 0, stream>>>(
        h, lnf_g, lnf_b, wft, bf, targets, logits, nll);
    loss_kernel<<<1, 256, 0, stream>>>(nll, loss);
}

// Round 25
// 1132.320 us; speedup vs baseline: 1.1654x; 1.0693x over previous
//
#include <hip/hip_runtime.h>
#include <hip/hip_bf16.h>
#include <math.h>

// Problem constants
#define B_  16
#define T_  1023
#define C_  384
#define H_  6
#define DH_ 64
#define L_  6
#define V_  256
#define FF_ 1536
#define M_  (B_*T_)      // 16368 rows
#define MP_ 16384        // padded rows (128-multiple)
#define EPS_ 1e-5f

typedef __attribute__((ext_vector_type(8))) short bf16x8;
typedef __attribute__((ext_vector_type(4))) short short4v;
typedef __attribute__((ext_vector_type(4))) float f32x4;

__device__ inline short f2bf(float x) {   // RNE float->bf16
    union { float f; unsigned u; } c; c.f = x;
    unsigned r = (c.u + 0x7fffu + ((c.u >> 16) & 1u)) >> 16;
    return (short)r;
}

#define GLDS16(g, l) __builtin_amdgcn_global_load_lds(                         \
    (const __attribute__((address_space(1))) void*)(g),                        \
    (__attribute__((address_space(3))) void*)(l), 16, 0, 0)

// hardware transpose read: 4 bf16 per lane (rule #18: waitcnt+sched_barrier after)
#define TRRD(dst, va, IMM) asm volatile("ds_read_b64_tr_b16 %0, %1 offset:" IMM \
    : "=v"(dst) : "v"(va))

// ---------------- embedding: h = tok_emb[x] + pos_emb (fp32) ----------------
__global__ void embed_kernel(const int* __restrict__ x, const float* __restrict__ tok,
                             const float* __restrict__ pos, float* __restrict__ h) {
    int i = blockIdx.x * 256 + threadIdx.x;
    if (i >= M_ * C_) return;
    int bt = i / C_;
    int c  = i - bt * C_;
    int t  = bt % T_;
    h[i] = tok[x[bt] * C_ + c] + pos[t * C_ + c];
}

// ---------------- weight transpose+convert: src fp32 [K][N] -> dst bf16 [N][K] ----
__global__ __launch_bounds__(256) void wconv_kernel(
    const float* __restrict__ Wq, const float* __restrict__ Wk,
    const float* __restrict__ Wv, const float* __restrict__ Wo,
    const float* __restrict__ W1, const float* __restrict__ W2,
    const float* __restrict__ Wf,
    short* __restrict__ qkvt, short* __restrict__ wot, short* __restrict__ w1t,
    short* __restrict__ w2t, short* __restrict__ wft) {
    __shared__ float tile[32][33];
    int t = blockIdx.x;
    const float* src; short* dst; int K, N, tl;
    if (t < 10368) {
        int l = t / 1728, r = t - l * 1728;
        if (r < 432) {                 // Wq/Wk/Wv -> fused qkv^T rows
            int which = r / 144; tl = r - which * 144;
            src = (which == 0 ? Wq : which == 1 ? Wk : Wv) + (size_t)l * 384 * 384;
            dst = qkvt + (size_t)l * 1152 * 384 + (size_t)which * 384 * 384;
            K = 384; N = 384;
        } else if (r < 576) {
            tl = r - 432;
            src = Wo + (size_t)l * 384 * 384; dst = wot + (size_t)l * 384 * 384;
            K = 384; N = 384;
        } else if (r < 1152) {
            tl = r - 576;
            src = W1 + (size_t)l * 384 * 1536; dst = w1t + (size_t)l * 1536 * 384;
            K = 384; N = 1536;
        } else {
            tl = r - 1152;
            src = W2 + (size_t)l * 1536 * 384; dst = w2t + (size_t)l * 384 * 1536;
            K = 1536; N = 384;
        }
    } else {
        tl = t - 10368; src = Wf; dst = wft; K = 384; N = 256;
    }
    int ntx = N >> 5;
    int k0 = (tl / ntx) << 5, n0 = (tl % ntx) << 5;
    int rr = threadIdx.x >> 5, cc = threadIdx.x & 31;
#pragma unroll
    for (int p = 0; p < 4; ++p)
        tile[rr + 8 * p][cc] = src[(size_t)(k0 + rr + 8 * p) * N + n0 + cc];
    __syncthreads();
#pragma unroll
    for (int p = 0; p < 4; ++p)
        dst[(size_t)(n0 + rr + 8 * p) * K + k0 + cc] = f2bf(tile[cc][rr + 8 * p]);
}

// ---------------- QKV GEMM + fused LN1: big = (LN(h)) @ qkvt^T ----------------
__global__ __launch_bounds__(512) void qkv_kernel(const float* __restrict__ h,
                                                  const float* __restrict__ lng,
                                                  const float* __restrict__ lnb,
                                                  const short* __restrict__ wt,
                                                  short* __restrict__ outb) {
    __shared__ short Zl[48 * 64 * 8];   // 48 KB
    int tid  = threadIdx.x;
    int wave = tid >> 6, lane = tid & 63;
    int g = lane >> 4, r16 = lane & 15;
    int r0 = blockIdx.x * 64;

    const short* wbase = wt + (size_t)(16 * wave + r16) * C_ + 8 * g;
    bf16x8 wf[12];
#pragma unroll
    for (int ks = 0; ks < 12; ++ks) wf[ks] = *(const bf16x8*)(wbase + ks * 32);

    float gv6[6], bv6[6];
#pragma unroll
    for (int i = 0; i < 6; ++i) { gv6[i] = lng[i * 64 + lane]; bv6[i] = lnb[i * 64 + lane]; }

    for (int rr = 0; rr < 8; ++rr) {
        int lrow = 8 * wave + rr;
        const float* rp = h + (size_t)(r0 + lrow) * C_;
        float v[6];
        float s = 0.f, s2 = 0.f;
#pragma unroll
        for (int i = 0; i < 6; ++i) {
            v[i] = rp[i * 64 + lane];
            s += v[i]; s2 += v[i] * v[i];
        }
#pragma unroll
        for (int o = 32; o > 0; o >>= 1) {
            s  += __shfl_xor(s,  o, 64);
            s2 += __shfl_xor(s2, o, 64);
        }
        float mu = s * (1.0f / C_);
        float rs = rsqrtf(s2 * (1.0f / C_) - mu * mu + EPS_);
#pragma unroll
        for (int i = 0; i < 6; ++i) {
            int col = i * 64 + lane;
            Zl[(col >> 3) * 512 + lrow * 8 + (col & 7)] =
                f2bf((v[i] - mu) * rs * gv6[i] + bv6[i]);
        }
    }
    __syncthreads();

    for (int c = 0; c < 9; ++c) {
        f32x4 acc[4];
#pragma unroll
        for (int mj = 0; mj < 4; ++mj) { acc[mj][0]=0.f; acc[mj][1]=0.f; acc[mj][2]=0.f; acc[mj][3]=0.f; }
#pragma unroll
        for (int ks = 0; ks < 12; ++ks) {
#pragma unroll
            for (int mj = 0; mj < 4; ++mj) {
                bf16x8 bz = *(const bf16x8*)(Zl + ((4 * ks + g) * 64 + 16 * mj + r16) * 8);
                acc[mj] = __builtin_amdgcn_mfma_f32_16x16x32_bf16(wf[ks], bz, acc[mj], 0, 0, 0);
            }
        }
        if (c + 1 < 9) {
#pragma unroll
            for (int ks = 0; ks < 12; ++ks)
                wf[ks] = *(const bf16x8*)(wbase + (size_t)(c + 1) * 128 * C_ + ks * 32);
        }
#pragma unroll
        for (int mj = 0; mj < 4; ++mj) {
            short4v ov;
#pragma unroll
            for (int rg = 0; rg < 4; ++rg) ov[rg] = f2bf(acc[mj][rg]);
            *(short4v*)(outb + (size_t)(r0 + 16 * mj + r16) * 1152
                        + 128 * c + 16 * wave + 4 * g) = ov;
        }
    }
}

// ---------------- merged Wo+FFN: h += ob@Wo^T+bo; z=LN2(h) in LDS;
// ----------------                h += relu(z@W1+b1)@W2 + b2 ----------------
// Block = 64 rows, 512 threads, grid 256. z never touches HBM: the wo
// epilogue writes LN'd values directly into Zl (qkv's verified LN-write
// layout), then falls through into ffn v2's main loop.
__global__ __launch_bounds__(512) void wo_ffn_kernel(const short* __restrict__ ob,
                                                     const short* __restrict__ wot_,
                                                     const float* __restrict__ bo,
                                                     float* __restrict__ h,
                                                     const float* __restrict__ lng,
                                                     const float* __restrict__ lnb,
                                                     const short* __restrict__ w1t,
                                                     const short* __restrict__ w2t,
                                                     const float* __restrict__ b1,
                                                     const float* __restrict__ b2) {
    __shared__ short Ol[48 * 64 * 8];   // 48 KB (ob tile; reused as LN scratch)
    __shared__ short Zl[48 * 64 * 8];   // 48 KB (z tile, LDS-only)
    __shared__ short Pl[16 * 64 * 8];   // 16 KB (ffn P tile)
    int tid  = threadIdx.x;
    int wave = tid >> 6, lane = tid & 63;
    int g = lane >> 4, r16 = lane & 15;
    int r0 = blockIdx.x * 64;

    // ---- phase 1: wo GEMM ----
    {
        const short* go = ob + (size_t)(r0 + lane) * C_ + wave * 8;
        short* lo = Ol + (wave * 64 + lane) * 8;
#pragma unroll
        for (int ro = 0; ro < 6; ++ro) { GLDS16(go, lo); go += 64; lo += 4096; }
    }

    const short* wbase = wot_ + (size_t)(48 * wave + r16) * C_ + 8 * g;
    bf16x8 wf[12];
#pragma unroll
    for (int ks2 = 0; ks2 < 4; ++ks2)
#pragma unroll
        for (int j = 0; j < 3; ++j)
            wf[ks2 * 3 + j] = *(const bf16x8*)(wbase + (size_t)(16 * j) * C_ + 32 * ks2);

    asm volatile("s_waitcnt vmcnt(0)" ::: "memory");
    __builtin_amdgcn_s_barrier();
    asm volatile("" ::: "memory");

    f32x4 acc[4][3];
#pragma unroll
    for (int mi = 0; mi < 4; ++mi)
#pragma unroll
        for (int j = 0; j < 3; ++j) { acc[mi][j][0]=0.f; acc[mi][j][1]=0.f; acc[mi][j][2]=0.f; acc[mi][j][3]=0.f; }

    for (int kc = 0; kc < 3; ++kc) {
#pragma unroll
        for (int ks2 = 0; ks2 < 4; ++ks2) {
            bf16x8 pa[4];
#pragma unroll
            for (int mi = 0; mi < 4; ++mi)
                pa[mi] = *(const bf16x8*)(Ol + ((16 * kc + 4 * ks2 + g) * 64 + 16 * mi + r16) * 8);
#pragma unroll
            for (int j = 0; j < 3; ++j)
#pragma unroll
                for (int mi = 0; mi < 4; ++mi)
                    acc[mi][j] = __builtin_amdgcn_mfma_f32_16x16x32_bf16(pa[mi], wf[ks2 * 3 + j], acc[mi][j], 0, 0, 0);
        }
        if (kc + 1 < 3) {
#pragma unroll
            for (int ks2 = 0; ks2 < 4; ++ks2)
#pragma unroll
                for (int j = 0; j < 3; ++j)
                    wf[ks2 * 3 + j] = *(const bf16x8*)(wbase + (size_t)(16 * j) * C_
                                                       + 128 * (kc + 1) + 32 * ks2);
        }
    }
    __syncthreads();               // Ol reads done; reuse as LN scratch

    // W1 chunk-0 prefetch: lands under the LN epilogue below
    const short* w1base = w1t + (size_t)(16 * wave + r16) * C_ + 8 * g;
    const short* w2base = w2t + (size_t)(48 * wave + r16) * FF_ + 8 * g;
    bf16x8 w1f[12];
#pragma unroll
    for (int ks = 0; ks < 12; ++ks)
        w1f[ks] = *(const bf16x8*)(w1base + ks * 32);

    // ---- phase 2: residual + LN2, z -> Zl (LDS only) ----
    float rsum[4][4], rsq[4][4];
#pragma unroll
    for (int mi = 0; mi < 4; ++mi)
#pragma unroll
        for (int rg = 0; rg < 4; ++rg) { rsum[mi][rg] = 0.f; rsq[mi][rg] = 0.f; }

#pragma unroll
    for (int j = 0; j < 3; ++j) {
        int col = 48 * wave + 16 * j + r16;
        float bj = bo[col];
#pragma unroll
        for (int mi = 0; mi < 4; ++mi) {
#pragma unroll
            for (int rg = 0; rg < 4; ++rg) {
                int row = r0 + 16 * mi + 4 * g + rg;
                float hv = h[(size_t)row * C_ + col] + acc[mi][j][rg] + bj;
                h[(size_t)row * C_ + col] = hv;
                acc[mi][j][rg] = hv;
                rsum[mi][rg] += hv;
                rsq[mi][rg]  += hv * hv;
            }
        }
    }
#pragma unroll
    for (int o = 1; o < 16; o <<= 1) {
#pragma unroll
        for (int mi = 0; mi < 4; ++mi)
#pragma unroll
            for (int rg = 0; rg < 4; ++rg) {
                rsum[mi][rg] += __shfl_xor(rsum[mi][rg], o, 64);
                rsq[mi][rg]  += __shfl_xor(rsq[mi][rg],  o, 64);
            }
    }
    float* St = (float*)Ol;             // [64 rows][16] floats = 4 KB
    if (r16 == 0) {
#pragma unroll
        for (int mi = 0; mi < 4; ++mi)
#pragma unroll
            for (int rg = 0; rg < 4; ++rg) {
                int rr = 16 * mi + 4 * g + rg;
                St[rr * 16 + 2 * wave]     = rsum[mi][rg];
                St[rr * 16 + 2 * wave + 1] = rsq[mi][rg];
            }
    }
    __syncthreads();
    if (tid < 64) {
        float s = 0.f, s2 = 0.f;
#pragma unroll
        for (int w = 0; w < 8; ++w) { s += St[tid * 16 + 2 * w]; s2 += St[tid * 16 + 2 * w + 1]; }
        float mu  = s * (1.0f / C_);
        float var = s2 * (1.0f / C_) - mu * mu;
        St[tid * 16]     = mu;
        St[tid * 16 + 1] = rsqrtf(var + EPS_);
    }
    __syncthreads();
#pragma unroll
    for (int j = 0; j < 3; ++j) {
        int col = 48 * wave + 16 * j + r16;
        float gam = lng[col], bet = lnb[col];
#pragma unroll
        for (int mi = 0; mi < 4; ++mi) {
#pragma unroll
            for (int rg = 0; rg < 4; ++rg) {
                int rr = 16 * mi + 4 * g + rg;
                float mu = St[rr * 16], rs = St[rr * 16 + 1];
                Zl[(col >> 3) * 512 + rr * 8 + (col & 7)] =
                    f2bf((acc[mi][j][rg] - mu) * rs * gam + bet);
            }
        }
    }
    __syncthreads();               // Zl complete

    // ---- phase 3: ffn v2 main loop (Zl already populated) ----
    f32x4 acc2[4][3];
#pragma unroll
    for (int mi = 0; mi < 4; ++mi)
#pragma unroll
        for (int j = 0; j < 3; ++j) { acc2[mi][j][0]=0.f; acc2[mi][j][1]=0.f; acc2[mi][j][2]=0.f; acc2[mi][j][3]=0.f; }

    for (int c = 0; c < 12; ++c) {
        bf16x8 w2f[12];
#pragma unroll
        for (int ks2 = 0; ks2 < 4; ++ks2)
#pragma unroll
            for (int j = 0; j < 3; ++j)
                w2f[ks2 * 3 + j] = *(const bf16x8*)(w2base + (size_t)(16 * j) * FF_
                                                    + 128 * c + 32 * ks2);

        f32x4 acc1[4];
#pragma unroll
        for (int mj = 0; mj < 4; ++mj) { acc1[mj][0]=0.f; acc1[mj][1]=0.f; acc1[mj][2]=0.f; acc1[mj][3]=0.f; }
#pragma unroll
        for (int ks = 0; ks < 12; ++ks) {
#pragma unroll
            for (int mj = 0; mj < 4; ++mj) {
                bf16x8 bz = *(const bf16x8*)(Zl + ((4 * ks + g) * 64 + 16 * mj + r16) * 8);
                acc1[mj] = __builtin_amdgcn_mfma_f32_16x16x32_bf16(w1f[ks], bz, acc1[mj], 0, 0, 0);
            }
        }
        f32x4 b1v = *(const f32x4*)(b1 + 128 * c + 16 * wave + 4 * g);
        int oct = 2 * wave + (g >> 1);
#pragma unroll
        for (int mj = 0; mj < 4; ++mj) {
            short4v pv;
#pragma unroll
            for (int rg = 0; rg < 4; ++rg)
                pv[rg] = f2bf(fmaxf(acc1[mj][rg] + b1v[rg], 0.f));
            *(short4v*)(Pl + (oct * 64 + 16 * mj + r16) * 8 + (g & 1) * 4) = pv;
        }
        __syncthreads();

        if (c + 1 < 12) {
#pragma unroll
            for (int ks = 0; ks < 12; ++ks)
                w1f[ks] = *(const bf16x8*)(w1base + (size_t)(c + 1) * 128 * C_ + ks * 32);
        }

#pragma unroll
        for (int ks2 = 0; ks2 < 4; ++ks2) {
            bf16x8 pa[4];
#pragma unroll
            for (int mi = 0; mi < 4; ++mi)
                pa[mi] = *(const bf16x8*)(Pl + ((4 * ks2 + g) * 64 + 16 * mi + r16) * 8);
#pragma unroll
            for (int j = 0; j < 3; ++j) {
#pragma unroll
                for (int mi = 0; mi < 4; ++mi)
                    acc2[mi][j] = __builtin_amdgcn_mfma_f32_16x16x32_bf16(pa[mi], w2f[ks2 * 3 + j], acc2[mi][j], 0, 0, 0);
            }
        }
        __syncthreads();
    }

#pragma unroll
    for (int j = 0; j < 3; ++j) {
        int col = 48 * wave + 16 * j + r16;
        float bj = b2[col];
#pragma unroll
        for (int mi = 0; mi < 4; ++mi) {
#pragma unroll
            for (int rg = 0; rg < 4; ++rg) {
                int row = r0 + 16 * mi + 4 * g + rg;
                h[(size_t)row * C_ + col] += acc2[mi][j][rg] + bj;
            }
        }
    }
}

// ---------------- final: lnf + projection + NLL fused ----------------
__global__ __launch_bounds__(512) void final_kernel(const float* __restrict__ h,
                                                    const float* __restrict__ lng,
                                                    const float* __restrict__ lnb,
                                                    const short* __restrict__ wt,
                                                    const float* __restrict__ bf,
                                                    const int* __restrict__ tgt,
                                                    float* __restrict__ logits,
                                                    float* __restrict__ nll) {
    __shared__ short Zl[48 * 64 * 8];   // 48 KB
    __shared__ float Lg[64][260];       // 65 KB (pad 260: 2-way bank aliasing)
    int tid  = threadIdx.x;
    int wave = tid >> 6, lane = tid & 63;
    int g = lane >> 4, r16 = lane & 15;
    int r0 = blockIdx.x * 64;

    const short* wbase = wt + (size_t)(16 * wave + r16) * C_ + 8 * g;
    bf16x8 wf[12];
#pragma unroll
    for (int ks = 0; ks < 12; ++ks) wf[ks] = *(const bf16x8*)(wbase + ks * 32);

    float gv6[6], bv6[6];
#pragma unroll
    for (int i = 0; i < 6; ++i) { gv6[i] = lng[i * 64 + lane]; bv6[i] = lnb[i * 64 + lane]; }

    for (int rr = 0; rr < 8; ++rr) {
        int lrow = 8 * wave + rr;
        const float* rp = h + (size_t)(r0 + lrow) * C_;
        float v[6];
        float s = 0.f, s2 = 0.f;
#pragma unroll
        for (int i = 0; i < 6; ++i) {
            v[i] = rp[i * 64 + lane];
            s += v[i]; s2 += v[i] * v[i];
        }
#pragma unroll
        for (int o = 32; o > 0; o >>= 1) {
            s  += __shfl_xor(s,  o, 64);
            s2 += __shfl_xor(s2, o, 64);
        }
        float mu = s * (1.0f / C_);
        float rs = rsqrtf(s2 * (1.0f / C_) - mu * mu + EPS_);
#pragma unroll
        for (int i = 0; i < 6; ++i) {
            int col = i * 64 + lane;
            Zl[(col >> 3) * 512 + lrow * 8 + (col & 7)] =
                f2bf((v[i] - mu) * rs * gv6[i] + bv6[i]);
        }
    }
    __syncthreads();

    for (int c = 0; c < 2; ++c) {
        f32x4 acc[4];
#pragma unroll
        for (int mj = 0; mj < 4; ++mj) { acc[mj][0]=0.f; acc[mj][1]=0.f; acc[mj][2]=0.f; acc[mj][3]=0.f; }
#pragma unroll
        for (int ks = 0; ks < 12; ++ks) {
#pragma unroll
            for (int mj = 0; mj < 4; ++mj) {
                bf16x8 bz = *(const bf16x8*)(Zl + ((4 * ks + g) * 64 + 16 * mj + r16) * 8);
                acc[mj] = __builtin_amdgcn_mfma_f32_16x16x32_bf16(wf[ks], bz, acc[mj], 0, 0, 0);
            }
        }
        if (c + 1 < 2) {
#pragma unroll
            for (int ks = 0; ks < 12; ++ks)
                wf[ks] = *(const bf16x8*)(wbase + (size_t)128 * C_ + ks * 32);
        }
        int colb = 128 * c + 16 * wave + 4 * g;
        f32x4 bv4 = *(const f32x4*)(bf + colb);
#pragma unroll
        for (int mj = 0; mj < 4; ++mj) {
            int lrow = 16 * mj + r16;
            int row  = r0 + lrow;
            f32x4 ov;
#pragma unroll
            for (int rg = 0; rg < 4; ++rg) {
                ov[rg] = acc[mj][rg] + bv4[rg];
                Lg[lrow][colb + rg] = ov[rg];
            }
            if (row < M_) *(f32x4*)(logits + (size_t)row * V_ + colb) = ov;
        }
    }
    __syncthreads();

    for (int rr = 0; rr < 8; ++rr) {
        int lrow = 8 * wave + rr;
        int row  = r0 + lrow;
        float v[4];
        float mx = -INFINITY;
#pragma unroll
        for (int i = 0; i < 4; ++i) {
            v[i] = Lg[lrow][i * 64 + lane];
            mx = fmaxf(mx, v[i]);
        }
#pragma unroll
        for (int o = 32; o > 0; o >>= 1) mx = fmaxf(mx, __shfl_xor(mx, o, 64));
        float s = 0.f;
#pragma unroll
        for (int i = 0; i < 4; ++i) s += expf(v[i] - mx);
#pragma unroll
        for (int o = 32; o > 0; o >>= 1) s += __shfl_xor(s, o, 64);
        if (lane == 0 && row < M_) {
            float lse = mx + logf(s);
            nll[row] = lse - Lg[lrow][tgt[row]];
        }
    }
}

// ---------------- MFMA flash attention v4: paired q-tiles + K/V double-buffer ----
__device__ __forceinline__ void attn_step(int kt, int qg, int g, int r16,
                                          const char* Kb, unsigned ka, unsigned va,
                                          short (*Pw)[40],
                                          bf16x8 qf0, bf16x8 qf1,
                                          f32x4* o_acc, float& m, float& l) {
    f32x4 s0, s1;
    s0[0]=0.f;s0[1]=0.f;s0[2]=0.f;s0[3]=0.f;
    s1[0]=0.f;s1[1]=0.f;s1[2]=0.f;s1[3]=0.f;
    bf16x8 a00 = *(const bf16x8*)(Kb + ka);
    bf16x8 a01 = *(const bf16x8*)(Kb + (ka ^ 64u));
    bf16x8 a10 = *(const bf16x8*)(Kb + ka + 2048u);
    bf16x8 a11 = *(const bf16x8*)(Kb + ((ka + 2048u) ^ 64u));
    s0 = __builtin_amdgcn_mfma_f32_16x16x32_bf16(a00, qf0, s0, 0, 0, 0);
    s0 = __builtin_amdgcn_mfma_f32_16x16x32_bf16(a01, qf1, s0, 0, 0, 0);
    s1 = __builtin_amdgcn_mfma_f32_16x16x32_bf16(a10, qf0, s1, 0, 0, 0);
    s1 = __builtin_amdgcn_mfma_f32_16x16x32_bf16(a11, qf1, s1, 0, 0, 0);

    int kb0 = kt * 32 + 4 * g;
    float sv[8];
#pragma unroll
    for (int r = 0; r < 4; ++r) {
        sv[r]     = (kb0 + r      <= qg) ? s0[r] * 0.125f : -3e38f;
        sv[4 + r] = (kb0 + 16 + r <= qg) ? s1[r] * 0.125f : -3e38f;
    }
    float pmax = sv[0];
#pragma unroll
    for (int i = 1; i < 8; ++i) pmax = fmaxf(pmax, sv[i]);
    pmax = fmaxf(pmax, __shfl_xor(pmax, 16, 64));
    pmax = fmaxf(pmax, __shfl_xor(pmax, 32, 64));
    float mn   = fmaxf(m, pmax);
    float corr = __expf(m - mn);
    float rs = 0.f;
    short pb[8];
#pragma unroll
    for (int i = 0; i < 8; ++i) {
        float p = __expf(sv[i] - mn);
        rs += p;
        pb[i] = f2bf(p);
    }
    rs += __shfl_xor(rs, 16, 64);
    rs += __shfl_xor(rs, 32, 64);
    l = l * corr + rs;
    m = mn;

    short4v t0w, t1w;
    t0w[0]=pb[0]; t0w[1]=pb[1]; t0w[2]=pb[2]; t0w[3]=pb[3];
    t1w[0]=pb[4]; t1w[1]=pb[5]; t1w[2]=pb[6]; t1w[3]=pb[7];
    *(short4v*)&Pw[r16][4 * g]      = t0w;
    *(short4v*)&Pw[r16][16 + 4 * g] = t1w;

    short4v v0, v1, v2, v3, v4, v5, v6, v7;
    TRRD(v0, va, "0");    TRRD(v1, va, "512");
    TRRD(v2, va, "128");  TRRD(v3, va, "640");
    TRRD(v4, va, "256");  TRRD(v5, va, "768");
    TRRD(v6, va, "384");  TRRD(v7, va, "896");

    bf16x8 pB = *(const bf16x8*)&Pw[r16][8 * g];
#pragma unroll
    for (int d = 0; d < 4; ++d) {
        o_acc[d][0] *= corr; o_acc[d][1] *= corr;
        o_acc[d][2] *= corr; o_acc[d][3] *= corr;
    }
    asm volatile("s_waitcnt lgkmcnt(0)" ::: "memory");
    __builtin_amdgcn_sched_barrier(0);

    bf16x8 av0, av1, av2, av3;
#pragma unroll
    for (int i = 0; i < 4; ++i) {
        av0[i] = v0[i]; av0[i + 4] = v1[i];
        av1[i] = v2[i]; av1[i + 4] = v3[i];
        av2[i] = v4[i]; av2[i + 4] = v5[i];
        av3[i] = v6[i]; av3[i + 4] = v7[i];
    }
    o_acc[0] = __builtin_amdgcn_mfma_f32_16x16x32_bf16(av0, pB, o_acc[0], 0, 0, 0);
    o_acc[1] = __builtin_amdgcn_mfma_f32_16x16x32_bf16(av1, pB, o_acc[1], 0, 0, 0);
    o_acc[2] = __builtin_amdgcn_mfma_f32_16x16x32_bf16(av2, pB, o_acc[2], 0, 0, 0);
    o_acc[3] = __builtin_amdgcn_mfma_f32_16x16x32_bf16(av3, pB, o_acc[3], 0, 0, 0);
}

__global__ __launch_bounds__(256) void attn_kernel(const short* __restrict__ qkv,
                                                   short* __restrict__ o) {
    __shared__ short Kl[2][32 * 64];       // 2 x 4 KB (double-buffered)
    __shared__ short Vl[2][32 * 64];       // 2 x 4 KB
    __shared__ short P_lds[4][16][40];     // 5 KB

    int tid  = threadIdx.x;
    int wave = tid >> 6;
    int lane = tid & 63;
    int g    = lane >> 4;
    int r16  = lane & 15;

    int qtA = blockIdx.x;
    int qtB = 15 - qtA;
    int bh = blockIdx.y;
    int b  = bh / H_, hh = bh - b * H_;
    size_t rbase = (size_t)b * T_;
    int qoff = hh * 64;

    int q0A = qtA * 64, q0B = qtB * 64;
    int qgA = q0A + wave * 16 + r16;
    int qgB = q0B + wave * 16 + r16;

    const short* qrA = qkv + (rbase + qgA) * 1152 + qoff;
    const short* qrB = qkv + (rbase + qgB) * 1152 + qoff;
    bf16x8 qfA0 = *(const bf16x8*)(qrA + 8 * g);
    bf16x8 qfA1 = *(const bf16x8*)(qrA + 32 + 8 * g);
    bf16x8 qfB0 = *(const bf16x8*)(qrB + 8 * g);
    bf16x8 qfB1 = *(const bf16x8*)(qrB + 32 + 8 * g);

    int kkey = tid >> 3;
    int koct = (tid & 7) ^ (kkey & 7);
    const short* gk = qkv + (rbase + kkey) * 1152 + qoff + 384 + koct * 8;
    int vkey = 4 * (tid >> 5) + ((tid >> 1) & 3);
    int voct = 2 * ((tid >> 3) & 3) + (tid & 1);
    const short* gv = qkv + (rbase + vkey) * 1152 + qoff + 768 + voct * 8;
    short* lk0 = Kl[0] + tid * 8;
    short* lk1 = Kl[1] + tid * 8;
    short* lv0 = Vl[0] + tid * 8;
    short* lv1 = Vl[1] + tid * 8;

    f32x4 oA[4], oB[4];
#pragma unroll
    for (int d = 0; d < 4; ++d) {
        oA[d][0]=0.f; oA[d][1]=0.f; oA[d][2]=0.f; oA[d][3]=0.f;
        oB[d][0]=0.f; oB[d][1]=0.f; oB[d][2]=0.f; oB[d][3]=0.f;
    }
    float mA = -3e38f, lA = 0.f, mB = -3e38f, lB = 0.f;

    const char* Kb0 = (const char*)Kl[0];
    const char* Kb1 = (const char*)Kl[1];
    unsigned ka = (unsigned)(r16 * 128 + ((g ^ (r16 & 7)) << 4));
    unsigned va0 = (unsigned)(size_t)(__attribute__((address_space(3))) short*)Vl[0]
                 + 1024u * (unsigned)g + 8u * (unsigned)r16;
    unsigned va1 = va0 + 4096u;            // Vl[1] is 4 KB after Vl[0]

    int ktA_hi = (q0A + wave * 16 + 15) >> 5;
    int ktB_hi = (q0B + wave * 16 + 15) >> 5;
    int nkt = 2 * (qtB + 1);

    // prologue: stage tile 0 into buffer 0
    GLDS16(gk, lk0);
    GLDS16(gv, lv0);
    gk += 32 * 1152; gv += 32 * 1152;
    asm volatile("s_waitcnt vmcnt(0)" ::: "memory");
    __builtin_amdgcn_s_barrier();
    asm volatile("" ::: "memory");

    for (int kt = 0; kt < nkt; ++kt) {
        int cur = kt & 1;
        if (kt + 1 < nkt) {
            GLDS16(gk, cur ? lk0 : lk1);
            GLDS16(gv, cur ? lv0 : lv1);
            gk += 32 * 1152; gv += 32 * 1152;
        }
        const char* Kb = cur ? Kb1 : Kb0;
        unsigned va = cur ? va1 : va0;

        if (kt <= ktB_hi)
            attn_step(kt, qgB, g, r16, Kb, ka, va, P_lds[wave], qfB0, qfB1, oB, mB, lB);
        if (kt <= ktA_hi)
            attn_step(kt, qgA, g, r16, Kb, ka, va, P_lds[wave], qfA0, qfA1, oA, mA, lA);

        asm volatile("s_waitcnt vmcnt(0)" ::: "memory");   // stage(kt+1) landed
        __builtin_amdgcn_s_barrier();
        asm volatile("" ::: "memory");
    }

    {
        float inv = (lA > 0.f) ? 1.f / lA : 0.f;
        short* orow = o + (rbase + qgA) * C_ + qoff;
#pragma unroll
        for (int d = 0; d < 4; ++d) {
            short4v ov;
#pragma unroll
            for (int r = 0; r < 4; ++r) ov[r] = f2bf(oA[d][r] * inv);
            *(short4v*)(orow + 16 * d + 4 * g) = ov;
        }
    }
    if (qgB < T_) {
        float inv = (lB > 0.f) ? 1.f / lB : 0.f;
        short* orow = o + (rbase + qgB) * C_ + qoff;
#pragma unroll
        for (int d = 0; d < 4; ++d) {
            short4v ov;
#pragma unroll
            for (int r = 0; r < 4; ++r) ov[r] = f2bf(oB[d][r] * inv);
            *(short4v*)(orow + 16 * d + 4 * g) = ov;
        }
    }
}

// ---------------- final deterministic mean reduce ----------------
__global__ __launch_bounds__(256) void loss_kernel(const float* __restrict__ nll,
                                                   float* __restrict__ loss) {
    __shared__ float sm[256];
    float s = 0.f;
    for (int i = threadIdx.x; i < M_; i += 256) s += nll[i];
    sm[threadIdx.x] = s;
    __syncthreads();
    for (int o = 128; o > 0; o >>= 1) {
        if (threadIdx.x < o) sm[threadIdx.x] += sm[threadIdx.x + o];
        __syncthreads();
    }
    if (threadIdx.x == 0) *loss = sm[0] * (1.0f / M_);
}

// ---------------- host launcher ----------------
extern "C" void kernel_launch(void* const* d_in, const int* in_sizes, int n_in,
                              void* d_out, int out_size, void* d_ws, size_t ws_size,
                              hipStream_t stream) {
    const int*   x       = (const int*)d_in[0];
    const int*   targets = (const int*)d_in[1];
    const float* tok_emb = (const float*)d_in[2];
    const float* pos_emb = (const float*)d_in[3];
    const float* Wq      = (const float*)d_in[4];
    const float* Wk      = (const float*)d_in[5];
    const float* Wv      = (const float*)d_in[6];
    const float* Wo      = (const float*)d_in[7];
    const float* bo      = (const float*)d_in[8];
    const float* ln1_g   = (const float*)d_in[9];
    const float* ln1_b   = (const float*)d_in[10];
    const float* ln2_g   = (const float*)d_in[11];
    const float* ln2_b   = (const float*)d_in[12];
    const float* W1      = (const float*)d_in[13];
    const float* b1      = (const float*)d_in[14];
    const float* W2      = (const float*)d_in[15];
    const float* b2      = (const float*)d_in[16];
    const float* lnf_g   = (const float*)d_in[17];
    const float* lnf_b   = (const float*)d_in[18];
    const float* Wf      = (const float*)d_in[19];
    const float* bf      = (const float*)d_in[20];

    float* logits = (float*)d_out;
    float* loss   = logits + (size_t)M_ * V_;

    float* h    = (float*)d_ws;                          // [MP_][C_] fp32
    short* z    = (short*)(h + (size_t)MP_ * C_);        // [MP_][C_] bf16 (unused now)
    short* big  = z + (size_t)MP_ * C_;                  // [MP_][FF_] bf16 (qkv)
    short* ob   = big + (size_t)MP_ * FF_;               // [MP_][C_] bf16
    short* qkvt = ob + (size_t)MP_ * C_;                 // [L][1152][384]
    short* wot  = qkvt + (size_t)L_ * 1152 * 384;        // [L][384][384]
    short* w1t  = wot + (size_t)L_ * 384 * 384;          // [L][1536][384]
    short* w2t  = w1t + (size_t)L_ * 1536 * 384;         // [L][384][1536]
    short* wft  = w2t + (size_t)L_ * 1536 * 384;         // [256][384]
    float* nll  = (float*)(wft + (size_t)256 * 384);     // [M_]

    wconv_kernel<<<10464, 256, 0, stream>>>(Wq, Wk, Wv, Wo, W1, W2, Wf,
                                            qkvt, wot, w1t, w2t, wft);
    embed_kernel<<<(M_ * C_ + 255) / 256, 256, 0, stream>>>(x, tok_emb, pos_emb, h);

    for (int l = 0; l < L_; ++l) {
        qkv_kernel<<<MP_ / 64, 512, 0, stream>>>(
            h, ln1_g + l * C_, ln1_b + l * C_,
            qkvt + (size_t)l * 1152 * 384, big);
        attn_kernel<<<dim3(8, B_ * H_), 256, 0, stream>>>(big, ob);
        wo_ffn_kernel<<<MP_ / 64, 512, 0, stream>>>(
            ob, wot + (size_t)l * 384 * 384, bo + l * C_, h,
            ln2_g + l * C_, ln2_b + l * C_,
            w1t + (size_t)l * 1536 * 384, w2t + (size_t)l * 384 * 1536,
            b1 + l * FF_, b2 + l * C_);
        ffn_dummy:;
    }

    final_kernel<<<MP_ / 64, 512, 0, stream>>>(
        h, lnf_g, lnf_b, wft, bf, targets, logits, nll);
    loss_kernel<<<1, 256, 0, stream>>>(nll, loss);
}